// Round 6
// baseline (471.184 us; speedup 1.0000x reference)
//
#include <hip/hip_runtime.h>
#include <hip/hip_fp16.h>

#define N_NODES_C 100000
#define N_EDGES_C 1200000

// ---------- degree histogram (int) over row ----------
__global__ void hist_kernel(const int* __restrict__ ei, int* __restrict__ cnt, int nedges) {
    int e = blockIdx.x * blockDim.x + threadIdx.x;
    if (e >= nedges) return;
    atomicAdd(cnt + ei[e], 1);
}

// ---------- exclusive scan stage 1 + fused deg_inv_sqrt ----------
__global__ __launch_bounds__(256) void scan1(const int* __restrict__ cnt, int* __restrict__ rowptr,
                                             int* __restrict__ blocksum, float* __restrict__ dis,
                                             int n) {
    __shared__ int s[256];
    int base = blockIdx.x * 1024 + threadIdx.x * 4;
    int v[4];
    int sum = 0;
#pragma unroll
    for (int i = 0; i < 4; ++i) {
        int idx = base + i;
        v[i] = (idx < n) ? cnt[idx] : 0;
        sum += v[i];
        if (idx < n) {
            float d = (float)v[i];
            dis[idx] = (d > 0.f) ? (1.0f / sqrtf(fmaxf(d, 1.f))) : 0.f;
        }
    }
    s[threadIdx.x] = sum;
    __syncthreads();
    for (int off = 1; off < 256; off <<= 1) {
        int val = s[threadIdx.x];
        int add = (threadIdx.x >= off) ? s[threadIdx.x - off] : 0;
        __syncthreads();
        s[threadIdx.x] = val + add;
        __syncthreads();
    }
    int run = (threadIdx.x > 0) ? s[threadIdx.x - 1] : 0;
#pragma unroll
    for (int i = 0; i < 4; ++i) {
        int idx = base + i;
        if (idx < n) rowptr[idx] = run;
        run += v[i];
    }
    if (threadIdx.x == 255) blocksum[blockIdx.x] = s[255];
}

// ---------- scan stage 2: serial scan of block sums (~98) ----------
__global__ void scan2(int* __restrict__ blocksum, int nb) {
    if (threadIdx.x == 0 && blockIdx.x == 0) {
        int acc = 0;
        for (int i = 0; i < nb; ++i) {
            int t = blocksum[i];
            blocksum[i] = acc;
            acc += t;
        }
    }
}

// ---------- scan stage 3: add block offsets, copy to `next`, cap rowptr ----------
__global__ void scan3(int* __restrict__ rowptr, int* __restrict__ next,
                      const int* __restrict__ blocksum, int n, int nedges) {
    int i = blockIdx.x * blockDim.x + threadIdx.x;
    if (i < n) {
        int v = rowptr[i] + blocksum[i >> 10];
        rowptr[i] = v;
        next[i] = v;
    }
    if (i == n) rowptr[n] = nedges;
}

// ---------- bucket-scatter edges into CSR with fused norm weight ----------
__global__ void edge_scatter(const int* __restrict__ ei, const float* __restrict__ dis,
                             int* __restrict__ next, int2* __restrict__ colw, int nedges) {
    int e = blockIdx.x * blockDim.x + threadIdx.x;
    if (e >= nedges) return;
    int r = ei[e];
    int c = ei[nedges + e];
    float w = -dis[r] * dis[c];
    int pos = atomicAdd(next + r, 1);
    colw[pos] = make_int2(c, __float_as_int(w));
}

// ---------- fold Chebyshev recurrence into layer-1 weights: [3][64][64] k-major ----------
__global__ void fold_w(const float* __restrict__ W, float* __restrict__ Wp, int total) {
    int i = blockIdx.x * blockDim.x + threadIdx.x;
    if (i >= total) return;
    float w0 = W[i], w1 = W[total + i], w2 = W[2 * total + i];
    Wp[i] = w0 - w2;
    Wp[total + i] = w1;
    Wp[2 * total + i] = 2.0f * w2;
}

// ---------- layer-2 weights concatenated: Wcat[k][0:32]=W0-W2, [32:64]=W1, [64:96]=2W2 ----------
__global__ void fold_wcat(const float* __restrict__ W, float* __restrict__ Wcat) {
    int i = blockIdx.x * blockDim.x + threadIdx.x;
    if (i >= 64 * 96) return;
    int k = i / 96;
    int c = i % 96;
    float v;
    if (c < 32) v = W[k * 32 + c] - W[2 * 2048 + k * 32 + c];
    else if (c < 64) v = W[2048 + k * 32 + (c - 32)];
    else v = 2.0f * W[2 * 2048 + k * 32 + (c - 64)];
    Wcat[i] = v;
}

// ---------- fp32 -> fp16 feature conversion (4 elems/thread) ----------
__global__ void f2h_kernel(const float* __restrict__ in, __half* __restrict__ out, int n4) {
    int i = blockIdx.x * blockDim.x + threadIdx.x;
    if (i >= n4) return;
    float4 v = ((const float4*)in)[i];
    __half2 tmp[2];
    tmp[0] = __floats2half2_rn(v.x, v.y);
    tmp[1] = __floats2half2_rn(v.z, v.w);
    ((float2*)out)[i] = *(float2*)tmp;
}

// ---------- prop64: out[r] = sum_e w_e * t[col_e]; fp16 64ch rows, 8 lanes/edge ----------
__global__ __launch_bounds__(256) void prop_gather_h(const __half* __restrict__ t,
                                                     const int* __restrict__ rowptr,
                                                     const int2* __restrict__ colw,
                                                     __half* __restrict__ out, int nnodes) {
    int node = blockIdx.x * 4 + (threadIdx.x >> 6);
    if (node >= nnodes) return;
    int lane = threadIdx.x & 63;
    int g = lane >> 3;    // edge group 0..7
    int gl = lane & 7;    // channel octet: channels gl*8 .. gl*8+7
    int s = rowptr[node];
    int e = rowptr[node + 1];
    float acc[8] = {0.f, 0.f, 0.f, 0.f, 0.f, 0.f, 0.f, 0.f};
    for (int base = s; base < e; base += 64) {
        int m = e - base;
        if (m > 64) m = 64;
        int2 cw = (lane < m) ? colw[base + lane] : make_int2(0, 0);
        int iters = (m + 7) >> 3;
        for (int it = 0; it < iters; ++it) {
            int j = (it << 3) | g;
            int c = __shfl(cw.x, j);
            float w = __int_as_float(__shfl(cw.y, j));
            if (j < m) {
                float4 raw = ((const float4*)(t + (size_t)c * 64))[gl];   // half8 = 16B
                const __half2* hp = (const __half2*)&raw;
                float2 f0 = __half22float2(hp[0]);
                float2 f1 = __half22float2(hp[1]);
                float2 f2 = __half22float2(hp[2]);
                float2 f3 = __half22float2(hp[3]);
                acc[0] += w * f0.x; acc[1] += w * f0.y;
                acc[2] += w * f1.x; acc[3] += w * f1.y;
                acc[4] += w * f2.x; acc[5] += w * f2.y;
                acc[6] += w * f3.x; acc[7] += w * f3.y;
            }
        }
    }
#pragma unroll
    for (int i = 0; i < 8; ++i) {
        acc[i] += __shfl_xor(acc[i], 8);
        acc[i] += __shfl_xor(acc[i], 16);
        acc[i] += __shfl_xor(acc[i], 32);
    }
    if (g == 0) {
        __half2 tmp[4];
        tmp[0] = __floats2half2_rn(acc[0], acc[1]);
        tmp[1] = __floats2half2_rn(acc[2], acc[3]);
        tmp[2] = __floats2half2_rn(acc[4], acc[5]);
        tmp[3] = __floats2half2_rn(acc[6], acc[7]);
        ((float4*)(out + (size_t)node * 64))[gl] = *(float4*)tmp;
    }
}

// ---------- prop32: 32-ch fp16 gather + per-node add-input; fp16 or fp32 output ----------
// F32OUT=false: out_h[n] = add_h[n] + prop(t)[n]     (Q = G1 + prop(G2))
// F32OUT=true:  out_f[n] = add_f[n] + prop(t)[n]     (out = P0 + prop(Q))
template <bool F32OUT>
__global__ __launch_bounds__(256) void prop_gather32(const __half* __restrict__ t,
                                                     const int* __restrict__ rowptr,
                                                     const int2* __restrict__ colw,
                                                     const void* __restrict__ addin,
                                                     void* __restrict__ outv, int nnodes) {
    int node = blockIdx.x * 4 + (threadIdx.x >> 6);
    if (node >= nnodes) return;
    int lane = threadIdx.x & 63;
    int g = lane >> 2;    // edge group 0..15
    int gl = lane & 3;    // channel octet: channels gl*8 .. gl*8+7
    int s = rowptr[node];
    int e = rowptr[node + 1];
    float acc[8] = {0.f, 0.f, 0.f, 0.f, 0.f, 0.f, 0.f, 0.f};
    for (int base = s; base < e; base += 64) {
        int m = e - base;
        if (m > 64) m = 64;
        int2 cw = (lane < m) ? colw[base + lane] : make_int2(0, 0);
        int iters = (m + 15) >> 4;
        for (int it = 0; it < iters; ++it) {
            int j = (it << 4) | g;
            int c = __shfl(cw.x, j);
            float w = __int_as_float(__shfl(cw.y, j));
            if (j < m) {
                float4 raw = ((const float4*)(t + (size_t)c * 32))[gl];   // half8 = 16B
                const __half2* hp = (const __half2*)&raw;
                float2 f0 = __half22float2(hp[0]);
                float2 f1 = __half22float2(hp[1]);
                float2 f2 = __half22float2(hp[2]);
                float2 f3 = __half22float2(hp[3]);
                acc[0] += w * f0.x; acc[1] += w * f0.y;
                acc[2] += w * f1.x; acc[3] += w * f1.y;
                acc[4] += w * f2.x; acc[5] += w * f2.y;
                acc[6] += w * f3.x; acc[7] += w * f3.y;
            }
        }
    }
#pragma unroll
    for (int i = 0; i < 8; ++i) {
        acc[i] += __shfl_xor(acc[i], 4);
        acc[i] += __shfl_xor(acc[i], 8);
        acc[i] += __shfl_xor(acc[i], 16);
        acc[i] += __shfl_xor(acc[i], 32);
    }
    if (g == 0) {
        if (F32OUT) {
            const float* add = (const float*)addin;
            float* out = (float*)outv;
            float4 a0 = ((const float4*)(add + (size_t)node * 32))[gl * 2 + 0];
            float4 a1 = ((const float4*)(add + (size_t)node * 32))[gl * 2 + 1];
            a0.x += acc[0]; a0.y += acc[1]; a0.z += acc[2]; a0.w += acc[3];
            a1.x += acc[4]; a1.y += acc[5]; a1.z += acc[6]; a1.w += acc[7];
            ((float4*)(out + (size_t)node * 32))[gl * 2 + 0] = a0;
            ((float4*)(out + (size_t)node * 32))[gl * 2 + 1] = a1;
        } else {
            const __half* add = (const __half*)addin;
            __half* out = (__half*)outv;
            float4 raw = ((const float4*)(add + (size_t)node * 32))[gl];
            const __half2* hp = (const __half2*)&raw;
            float2 f0 = __half22float2(hp[0]);
            float2 f1 = __half22float2(hp[1]);
            float2 f2 = __half22float2(hp[2]);
            float2 f3 = __half22float2(hp[3]);
            __half2 tmp[4];
            tmp[0] = __floats2half2_rn(acc[0] + f0.x, acc[1] + f0.y);
            tmp[1] = __floats2half2_rn(acc[2] + f1.x, acc[3] + f1.y);
            tmp[2] = __floats2half2_rn(acc[4] + f2.x, acc[5] + f2.y);
            tmp[3] = __floats2half2_rn(acc[6] + f3.x, acc[7] + f3.y);
            ((float4*)(out + (size_t)node * 32))[gl] = *(float4*)tmp;
        }
    }
}

// ---------- layer-1 register-tiled GEMM: Hh = relu([A0|A1|A2] @ Wp + bias), fp16 out ----------
__global__ __launch_bounds__(256) void cheb_gemm_h(const __half* __restrict__ A0,
                                                   const __half* __restrict__ A1,
                                                   const __half* __restrict__ A2,
                                                   const float* __restrict__ Wp,
                                                   const float* __restrict__ bias,
                                                   __half* __restrict__ outh, int nnodes) {
    constexpr int OUTC = 64;
    constexpr int NODES = 64;
    constexpr int NG = 16;
    constexpr int S = NODES + 5;
    constexpr int F8 = NODES * 8 / 256;
    __shared__ float sA[64 * S];

    const int tid = threadIdx.x;
    const int ng = tid % NG;
    const int cg = tid / NG;
    const int node0 = blockIdx.x * NODES;
    const int n_base = node0 + ng * 4;

    float4 bv = *(const float4*)(bias + cg * 4);
    float acc[4][4];
#pragma unroll
    for (int j = 0; j < 4; ++j) {
        acc[j][0] = bv.x; acc[j][1] = bv.y; acc[j][2] = bv.z; acc[j][3] = bv.w;
    }

    const __half* Aptr[3] = {A0, A1, A2};
    for (int term = 0; term < 3; ++term) {
        const __half* A = Aptr[term];
        __syncthreads();
#pragma unroll
        for (int i = 0; i < F8; ++i) {
            int f = tid + i * 256;
            int n = f >> 3;
            int kc = f & 7;
            int gn = node0 + n;
            float4 raw = make_float4(0.f, 0.f, 0.f, 0.f);
            if (gn < nnodes) raw = ((const float4*)(A + (size_t)gn * 64))[kc];
            const __half2* hp = (const __half2*)&raw;
            float2 f0 = __half22float2(hp[0]);
            float2 f1 = __half22float2(hp[1]);
            float2 f2 = __half22float2(hp[2]);
            float2 f3 = __half22float2(hp[3]);
            sA[(kc * 8 + 0) * S + n] = f0.x;
            sA[(kc * 8 + 1) * S + n] = f0.y;
            sA[(kc * 8 + 2) * S + n] = f1.x;
            sA[(kc * 8 + 3) * S + n] = f1.y;
            sA[(kc * 8 + 4) * S + n] = f2.x;
            sA[(kc * 8 + 5) * S + n] = f2.y;
            sA[(kc * 8 + 6) * S + n] = f3.x;
            sA[(kc * 8 + 7) * S + n] = f3.y;
        }
        __syncthreads();
        const float* Wt = Wp + term * 64 * OUTC;
#pragma unroll 8
        for (int k = 0; k < 64; ++k) {
            float4 a = *(const float4*)(sA + k * S + ng * 4);
            float4 b = *(const float4*)(Wt + k * OUTC + cg * 4);
            acc[0][0] += a.x * b.x; acc[0][1] += a.x * b.y; acc[0][2] += a.x * b.z; acc[0][3] += a.x * b.w;
            acc[1][0] += a.y * b.x; acc[1][1] += a.y * b.y; acc[1][2] += a.y * b.z; acc[1][3] += a.y * b.w;
            acc[2][0] += a.z * b.x; acc[2][1] += a.z * b.y; acc[2][2] += a.z * b.z; acc[2][3] += a.z * b.w;
            acc[3][0] += a.w * b.x; acc[3][1] += a.w * b.y; acc[3][2] += a.w * b.z; acc[3][3] += a.w * b.w;
        }
    }
#pragma unroll
    for (int j = 0; j < 4; ++j) {
        int n = n_base + j;
        if (n >= nnodes) continue;
        float4 o = make_float4(fmaxf(acc[j][0], 0.f), fmaxf(acc[j][1], 0.f),
                               fmaxf(acc[j][2], 0.f), fmaxf(acc[j][3], 0.f));
        __half2 tmp[2];
        tmp[0] = __floats2half2_rn(o.x, o.y);
        tmp[1] = __floats2half2_rn(o.z, o.w);
        ((float2*)(outh + (size_t)n * OUTC))[cg] = *(float2*)tmp;
    }
}

// ---------- layer-2 fan-out GEMM: [P0|G1|G2] = Hh @ Wcat (+b2 on P0 cols) ----------
// Wcat k-major [64][96]; P0 fp32 [N,32]; G1,G2 fp16 [N,32]. 4 nodes x 6 ch per thread.
__global__ __launch_bounds__(256) void gemm96(const __half* __restrict__ Hh,
                                              const float* __restrict__ Wcat,
                                              const float* __restrict__ b2,
                                              float* __restrict__ P0,
                                              __half* __restrict__ G1,
                                              __half* __restrict__ G2, int nnodes) {
    constexpr int NODES = 64;
    constexpr int NG = 16;     // 16 node-groups x 4 nodes
    constexpr int S = NODES + 5;
    __shared__ float sA[64 * S];

    const int tid = threadIdx.x;
    const int ng = tid % NG;
    const int cg = tid / NG;   // 16 channel-groups x 6 ch
    const int c0 = cg * 6;
    const int node0 = blockIdx.x * NODES;
    const int n_base = node0 + ng * 4;

    float acc[4][6];
#pragma unroll
    for (int cc = 0; cc < 6; ++cc) {
        int c = c0 + cc;
        float b = (c < 32) ? b2[c] : 0.f;
#pragma unroll
        for (int j = 0; j < 4; ++j) acc[j][cc] = b;
    }

    // stage Hh tile k-major
#pragma unroll
    for (int i = 0; i < 2; ++i) {
        int f = tid + i * 256;
        int n = f >> 3;
        int kc = f & 7;
        int gn = node0 + n;
        float4 raw = make_float4(0.f, 0.f, 0.f, 0.f);
        if (gn < nnodes) raw = ((const float4*)(Hh + (size_t)gn * 64))[kc];
        const __half2* hp = (const __half2*)&raw;
        float2 f0 = __half22float2(hp[0]);
        float2 f1 = __half22float2(hp[1]);
        float2 f2 = __half22float2(hp[2]);
        float2 f3 = __half22float2(hp[3]);
        sA[(kc * 8 + 0) * S + n] = f0.x;
        sA[(kc * 8 + 1) * S + n] = f0.y;
        sA[(kc * 8 + 2) * S + n] = f1.x;
        sA[(kc * 8 + 3) * S + n] = f1.y;
        sA[(kc * 8 + 4) * S + n] = f2.x;
        sA[(kc * 8 + 5) * S + n] = f2.y;
        sA[(kc * 8 + 6) * S + n] = f3.x;
        sA[(kc * 8 + 7) * S + n] = f3.y;
    }
    __syncthreads();
#pragma unroll 8
    for (int k = 0; k < 64; ++k) {
        float4 a = *(const float4*)(sA + k * S + ng * 4);
        const float2* wp = (const float2*)(Wcat + k * 96 + c0);   // c0 even -> 8B aligned
        float2 w01 = wp[0], w23 = wp[1], w45 = wp[2];
        float w[6] = {w01.x, w01.y, w23.x, w23.y, w45.x, w45.y};
        float av[4] = {a.x, a.y, a.z, a.w};
#pragma unroll
        for (int j = 0; j < 4; ++j)
#pragma unroll
            for (int cc = 0; cc < 6; ++cc) acc[j][cc] += av[j] * w[cc];
    }
#pragma unroll
    for (int j = 0; j < 4; ++j) {
        int n = n_base + j;
        if (n >= nnodes) continue;
#pragma unroll
        for (int cc = 0; cc < 6; ++cc) {
            int c = c0 + cc;
            float v = acc[j][cc];
            if (c < 32) P0[(size_t)n * 32 + c] = v;
            else if (c < 64) G1[(size_t)n * 32 + (c - 32)] = __float2half(v);
            else G2[(size_t)n * 32 + (c - 64)] = __float2half(v);
        }
    }
}

extern "C" void kernel_launch(void* const* d_in, const int* in_sizes, int n_in,
                              void* d_out, int out_size, void* d_ws, size_t ws_size,
                              hipStream_t stream) {
    const float* x  = (const float*)d_in[0];
    const int*   ei = (const int*)d_in[1];
    const float* W1 = (const float*)d_in[2];
    const float* b1 = (const float*)d_in[3];
    const float* W2 = (const float*)d_in[4];
    const float* b2 = (const float*)d_in[5];
    float* out = (float*)d_out;

    const int NN = N_NODES_C;
    const int NE = N_EDGES_C;
    const size_t HFEAT_BYTES = (size_t)NN * 64 * sizeof(__half);
    const size_t H32_BYTES = (size_t)NN * 32 * sizeof(__half);

    char* ws = (char*)d_ws;
    size_t off = 0;
    auto alloc = [&](size_t bytes) -> void* {
        void* p = ws + off;
        off += (bytes + 255) & ~(size_t)255;
        return p;
    };
    int*    cnt      = (int*)alloc((size_t)NN * 4);
    int*    rowptr   = (int*)alloc((size_t)(NN + 1) * 4);
    int*    next     = (int*)alloc((size_t)NN * 4);
    float*  dis      = (float*)alloc((size_t)NN * 4);
    int*    blocksum = (int*)alloc(1024);
    int2*   colw     = (int2*)alloc((size_t)NE * 8);
    __half* xh       = (__half*)alloc(HFEAT_BYTES);
    __half* T1h      = (__half*)alloc(HFEAT_BYTES);   // layer1: T1; layer2: G1
    __half* T2h      = (__half*)alloc(HFEAT_BYTES);   // layer1: T2; layer2: G2
    __half* Hh       = (__half*)alloc(HFEAT_BYTES);
    __half* Qh       = (__half*)alloc(H32_BYTES);
    float*  P0       = (float*)alloc((size_t)NN * 32 * 4);
    float*  W1p      = (float*)alloc((size_t)3 * 64 * 64 * 4);
    float*  Wcat     = (float*)alloc((size_t)64 * 96 * 4);

    const int EB = (NE + 255) / 256;
    const int SCAN_BLOCKS = (NN + 1023) / 1024;
    const int PROPB = (NN + 3) / 4;
    const int CONVB = (NN * 64 / 4 + 255) / 256;

    // ---- CSR build + normalization + weight prep + x->fp16 ----
    hipMemsetAsync(cnt, 0, (size_t)NN * 4, stream);
    hist_kernel<<<EB, 256, 0, stream>>>(ei, cnt, NE);
    scan1<<<SCAN_BLOCKS, 256, 0, stream>>>(cnt, rowptr, blocksum, dis, NN);
    scan2<<<1, 64, 0, stream>>>(blocksum, SCAN_BLOCKS);
    scan3<<<(NN + 256) / 256, 256, 0, stream>>>(rowptr, next, blocksum, NN, NE);
    edge_scatter<<<EB, 256, 0, stream>>>(ei, dis, next, colw, NE);
    fold_w<<<(64 * 64 + 255) / 256, 256, 0, stream>>>(W1, W1p, 64 * 64);
    fold_wcat<<<(64 * 96 + 255) / 256, 256, 0, stream>>>(W2, Wcat);
    f2h_kernel<<<CONVB, 256, 0, stream>>>(x, xh, NN * 64 / 4);

    // ---- layer 1: Hh = relu(x@(W0-W2) + T1@W1 + T2@(2W2) + b1), T2 = prop(T1) ----
    prop_gather_h<<<PROPB, 256, 0, stream>>>(xh, rowptr, colw, T1h, NN);
    prop_gather_h<<<PROPB, 256, 0, stream>>>(T1h, rowptr, colw, T2h, NN);
    cheb_gemm_h<<<(NN + 63) / 64, 256, 0, stream>>>(xh, T1h, T2h, W1p, b1, Hh, NN);

    // ---- layer 2 (factored): out = P0 + prop(G1 + prop(G2)) ----
    gemm96<<<(NN + 63) / 64, 256, 0, stream>>>(Hh, Wcat, b2, P0, T1h, T2h, NN);
    prop_gather32<false><<<PROPB, 256, 0, stream>>>(T2h, rowptr, colw, T1h, Qh, NN);
    prop_gather32<true><<<PROPB, 256, 0, stream>>>(Qh, rowptr, colw, P0, out, NN);
}

// Round 7
// 459.144 us; speedup vs baseline: 1.0262x; 1.0262x over previous
//
#include <hip/hip_runtime.h>
#include <hip/hip_fp16.h>

#define N_NODES_C 100000
#define N_EDGES_C 1200000

// ---------- degree histogram (int) over row ----------
__global__ void hist_kernel(const int* __restrict__ ei, int* __restrict__ cnt, int nedges) {
    int e = blockIdx.x * blockDim.x + threadIdx.x;
    if (e >= nedges) return;
    atomicAdd(cnt + ei[e], 1);
}

// ---------- exclusive scan stage 1 + fused deg_inv_sqrt ----------
__global__ __launch_bounds__(256) void scan1(const int* __restrict__ cnt, int* __restrict__ rowptr,
                                             int* __restrict__ blocksum, float* __restrict__ dis,
                                             int n) {
    __shared__ int s[256];
    int base = blockIdx.x * 1024 + threadIdx.x * 4;
    int v[4];
    int sum = 0;
#pragma unroll
    for (int i = 0; i < 4; ++i) {
        int idx = base + i;
        v[i] = (idx < n) ? cnt[idx] : 0;
        sum += v[i];
        if (idx < n) {
            float d = (float)v[i];
            dis[idx] = (d > 0.f) ? (1.0f / sqrtf(fmaxf(d, 1.f))) : 0.f;
        }
    }
    s[threadIdx.x] = sum;
    __syncthreads();
    for (int off = 1; off < 256; off <<= 1) {
        int val = s[threadIdx.x];
        int add = (threadIdx.x >= off) ? s[threadIdx.x - off] : 0;
        __syncthreads();
        s[threadIdx.x] = val + add;
        __syncthreads();
    }
    int run = (threadIdx.x > 0) ? s[threadIdx.x - 1] : 0;
#pragma unroll
    for (int i = 0; i < 4; ++i) {
        int idx = base + i;
        if (idx < n) rowptr[idx] = run;
        run += v[i];
    }
    if (threadIdx.x == 255) blocksum[blockIdx.x] = s[255];
}

// ---------- scan stage 2: serial scan of block sums (~98) ----------
__global__ void scan2(int* __restrict__ blocksum, int nb) {
    if (threadIdx.x == 0 && blockIdx.x == 0) {
        int acc = 0;
        for (int i = 0; i < nb; ++i) {
            int t = blocksum[i];
            blocksum[i] = acc;
            acc += t;
        }
    }
}

// ---------- scan stage 3: add block offsets, copy to `next`, cap rowptr ----------
__global__ void scan3(int* __restrict__ rowptr, int* __restrict__ next,
                      const int* __restrict__ blocksum, int n, int nedges) {
    int i = blockIdx.x * blockDim.x + threadIdx.x;
    if (i < n) {
        int v = rowptr[i] + blocksum[i >> 10];
        rowptr[i] = v;
        next[i] = v;
    }
    if (i == n) rowptr[n] = nedges;
}

// ---------- bucket-scatter edges into CSR with fused norm weight ----------
__global__ void edge_scatter(const int* __restrict__ ei, const float* __restrict__ dis,
                             int* __restrict__ next, int2* __restrict__ colw, int nedges) {
    int e = blockIdx.x * blockDim.x + threadIdx.x;
    if (e >= nedges) return;
    int r = ei[e];
    int c = ei[nedges + e];
    float w = -dis[r] * dis[c];
    int pos = atomicAdd(next + r, 1);
    colw[pos] = make_int2(c, __float_as_int(w));
}

// ---------- fold Chebyshev recurrence into layer-1 weights: [3][64][64] k-major ----------
__global__ void fold_w(const float* __restrict__ W, float* __restrict__ Wp, int total) {
    int i = blockIdx.x * blockDim.x + threadIdx.x;
    if (i >= total) return;
    float w0 = W[i], w1 = W[total + i], w2 = W[2 * total + i];
    Wp[i] = w0 - w2;
    Wp[total + i] = w1;
    Wp[2 * total + i] = 2.0f * w2;
}

// ---------- layer-2 weights concatenated: Wcat[k][0:32]=W0-W2, [32:64]=W1, [64:96]=2W2 ----------
__global__ void fold_wcat(const float* __restrict__ W, float* __restrict__ Wcat) {
    int i = blockIdx.x * blockDim.x + threadIdx.x;
    if (i >= 64 * 96) return;
    int k = i / 96;
    int c = i % 96;
    float v;
    if (c < 32) v = W[k * 32 + c] - W[2 * 2048 + k * 32 + c];
    else if (c < 64) v = W[2048 + k * 32 + (c - 32)];
    else v = 2.0f * W[2 * 2048 + k * 32 + (c - 64)];
    Wcat[i] = v;
}

// ---------- fp32 -> fp16 feature conversion (4 elems/thread) ----------
__global__ void f2h_kernel(const float* __restrict__ in, __half* __restrict__ out, int n4) {
    int i = blockIdx.x * blockDim.x + threadIdx.x;
    if (i >= n4) return;
    float4 v = ((const float4*)in)[i];
    __half2 tmp[2];
    tmp[0] = __floats2half2_rn(v.x, v.y);
    tmp[1] = __floats2half2_rn(v.z, v.w);
    ((float2*)out)[i] = *(float2*)tmp;
}

// ---------- prop64: out[r] = sum_e w_e * t[col_e]; fp16 64ch rows, 8 lanes/edge ----------
// NOTE: no j<m guard — tail lanes hold (0,0) sentinel: gather row 0 (L1-hot) with w=0.
__global__ __launch_bounds__(256) void prop_gather_h(const __half* __restrict__ t,
                                                     const int* __restrict__ rowptr,
                                                     const int2* __restrict__ colw,
                                                     __half* __restrict__ out, int nnodes) {
    int node = blockIdx.x * 4 + (threadIdx.x >> 6);
    if (node >= nnodes) return;
    int lane = threadIdx.x & 63;
    int g = lane >> 3;    // edge group 0..7
    int gl = lane & 7;    // channel octet: channels gl*8 .. gl*8+7
    int s = rowptr[node];
    int e = rowptr[node + 1];
    float acc[8] = {0.f, 0.f, 0.f, 0.f, 0.f, 0.f, 0.f, 0.f};
    for (int base = s; base < e; base += 64) {
        int m = e - base;
        if (m > 64) m = 64;
        int2 cw = (lane < m) ? colw[base + lane] : make_int2(0, 0);
        int iters = (m + 7) >> 3;
        for (int it = 0; it < iters; ++it) {
            int j = (it << 3) | g;                  // j>=m lanes hold (0,0) -> w=0, safe
            int c = __shfl(cw.x, j);
            float w = __int_as_float(__shfl(cw.y, j));
            float4 raw = ((const float4*)(t + (size_t)c * 64))[gl];   // half8 = 16B
            const __half2* hp = (const __half2*)&raw;
            float2 f0 = __half22float2(hp[0]);
            float2 f1 = __half22float2(hp[1]);
            float2 f2 = __half22float2(hp[2]);
            float2 f3 = __half22float2(hp[3]);
            acc[0] += w * f0.x; acc[1] += w * f0.y;
            acc[2] += w * f1.x; acc[3] += w * f1.y;
            acc[4] += w * f2.x; acc[5] += w * f2.y;
            acc[6] += w * f3.x; acc[7] += w * f3.y;
        }
    }
#pragma unroll
    for (int i = 0; i < 8; ++i) {
        acc[i] += __shfl_xor(acc[i], 8);
        acc[i] += __shfl_xor(acc[i], 16);
        acc[i] += __shfl_xor(acc[i], 32);
    }
    if (g == 0) {
        __half2 tmp[4];
        tmp[0] = __floats2half2_rn(acc[0], acc[1]);
        tmp[1] = __floats2half2_rn(acc[2], acc[3]);
        tmp[2] = __floats2half2_rn(acc[4], acc[5]);
        tmp[3] = __floats2half2_rn(acc[6], acc[7]);
        ((float4*)(out + (size_t)node * 64))[gl] = *(float4*)tmp;
    }
}

// ---------- prop32: 32-ch fp16 gather + per-node add-input; fp16 or fp32 output ----------
// F32OUT=false: out_h[n] = add_h[n] + prop(t)[n]     (Q = G1 + prop(G2))
// F32OUT=true:  out_f[n] = add_f[n] + prop(t)[n]     (out = P0 + prop(Q))
template <bool F32OUT>
__global__ __launch_bounds__(256) void prop_gather32(const __half* __restrict__ t,
                                                     const int* __restrict__ rowptr,
                                                     const int2* __restrict__ colw,
                                                     const void* __restrict__ addin,
                                                     void* __restrict__ outv, int nnodes) {
    int node = blockIdx.x * 4 + (threadIdx.x >> 6);
    if (node >= nnodes) return;
    int lane = threadIdx.x & 63;
    int g = lane >> 2;    // edge group 0..15
    int gl = lane & 3;    // channel octet: channels gl*8 .. gl*8+7
    int s = rowptr[node];
    int e = rowptr[node + 1];
    float acc[8] = {0.f, 0.f, 0.f, 0.f, 0.f, 0.f, 0.f, 0.f};
    for (int base = s; base < e; base += 64) {
        int m = e - base;
        if (m > 64) m = 64;
        int2 cw = (lane < m) ? colw[base + lane] : make_int2(0, 0);
        int iters = (m + 15) >> 4;
        for (int it = 0; it < iters; ++it) {
            int j = (it << 4) | g;                  // sentinel (0,0) for j>=m: w=0, safe
            int c = __shfl(cw.x, j);
            float w = __int_as_float(__shfl(cw.y, j));
            float4 raw = ((const float4*)(t + (size_t)c * 32))[gl];   // half8 = 16B
            const __half2* hp = (const __half2*)&raw;
            float2 f0 = __half22float2(hp[0]);
            float2 f1 = __half22float2(hp[1]);
            float2 f2 = __half22float2(hp[2]);
            float2 f3 = __half22float2(hp[3]);
            acc[0] += w * f0.x; acc[1] += w * f0.y;
            acc[2] += w * f1.x; acc[3] += w * f1.y;
            acc[4] += w * f2.x; acc[5] += w * f2.y;
            acc[6] += w * f3.x; acc[7] += w * f3.y;
        }
    }
#pragma unroll
    for (int i = 0; i < 8; ++i) {
        acc[i] += __shfl_xor(acc[i], 4);
        acc[i] += __shfl_xor(acc[i], 8);
        acc[i] += __shfl_xor(acc[i], 16);
        acc[i] += __shfl_xor(acc[i], 32);
    }
    if (g == 0) {
        if (F32OUT) {
            const float* add = (const float*)addin;
            float* out = (float*)outv;
            float4 a0 = ((const float4*)(add + (size_t)node * 32))[gl * 2 + 0];
            float4 a1 = ((const float4*)(add + (size_t)node * 32))[gl * 2 + 1];
            a0.x += acc[0]; a0.y += acc[1]; a0.z += acc[2]; a0.w += acc[3];
            a1.x += acc[4]; a1.y += acc[5]; a1.z += acc[6]; a1.w += acc[7];
            ((float4*)(out + (size_t)node * 32))[gl * 2 + 0] = a0;
            ((float4*)(out + (size_t)node * 32))[gl * 2 + 1] = a1;
        } else {
            const __half* add = (const __half*)addin;
            __half* out = (__half*)outv;
            float4 raw = ((const float4*)(add + (size_t)node * 32))[gl];
            const __half2* hp = (const __half2*)&raw;
            float2 f0 = __half22float2(hp[0]);
            float2 f1 = __half22float2(hp[1]);
            float2 f2 = __half22float2(hp[2]);
            float2 f3 = __half22float2(hp[3]);
            __half2 tmp[4];
            tmp[0] = __floats2half2_rn(acc[0] + f0.x, acc[1] + f0.y);
            tmp[1] = __floats2half2_rn(acc[2] + f1.x, acc[3] + f1.y);
            tmp[2] = __floats2half2_rn(acc[4] + f2.x, acc[5] + f2.y);
            tmp[3] = __floats2half2_rn(acc[6] + f3.x, acc[7] + f3.y);
            ((float4*)(out + (size_t)node * 32))[gl] = *(float4*)tmp;
        }
    }
}

// ---------- layer-1 register-tiled GEMM: Hh = relu([A0|A1|A2] @ Wp + bias), fp16 out ----------
__global__ __launch_bounds__(256) void cheb_gemm_h(const __half* __restrict__ A0,
                                                   const __half* __restrict__ A1,
                                                   const __half* __restrict__ A2,
                                                   const float* __restrict__ Wp,
                                                   const float* __restrict__ bias,
                                                   __half* __restrict__ outh, int nnodes) {
    constexpr int OUTC = 64;
    constexpr int NODES = 64;
    constexpr int NG = 16;
    constexpr int S = NODES + 5;
    constexpr int F8 = NODES * 8 / 256;
    __shared__ float sA[64 * S];

    const int tid = threadIdx.x;
    const int ng = tid % NG;
    const int cg = tid / NG;
    const int node0 = blockIdx.x * NODES;
    const int n_base = node0 + ng * 4;

    float4 bv = *(const float4*)(bias + cg * 4);
    float acc[4][4];
#pragma unroll
    for (int j = 0; j < 4; ++j) {
        acc[j][0] = bv.x; acc[j][1] = bv.y; acc[j][2] = bv.z; acc[j][3] = bv.w;
    }

    const __half* Aptr[3] = {A0, A1, A2};
    for (int term = 0; term < 3; ++term) {
        const __half* A = Aptr[term];
        __syncthreads();
#pragma unroll
        for (int i = 0; i < F8; ++i) {
            int f = tid + i * 256;
            int n = f >> 3;
            int kc = f & 7;
            int gn = node0 + n;
            float4 raw = make_float4(0.f, 0.f, 0.f, 0.f);
            if (gn < nnodes) raw = ((const float4*)(A + (size_t)gn * 64))[kc];
            const __half2* hp = (const __half2*)&raw;
            float2 f0 = __half22float2(hp[0]);
            float2 f1 = __half22float2(hp[1]);
            float2 f2 = __half22float2(hp[2]);
            float2 f3 = __half22float2(hp[3]);
            sA[(kc * 8 + 0) * S + n] = f0.x;
            sA[(kc * 8 + 1) * S + n] = f0.y;
            sA[(kc * 8 + 2) * S + n] = f1.x;
            sA[(kc * 8 + 3) * S + n] = f1.y;
            sA[(kc * 8 + 4) * S + n] = f2.x;
            sA[(kc * 8 + 5) * S + n] = f2.y;
            sA[(kc * 8 + 6) * S + n] = f3.x;
            sA[(kc * 8 + 7) * S + n] = f3.y;
        }
        __syncthreads();
        const float* Wt = Wp + term * 64 * OUTC;
#pragma unroll 8
        for (int k = 0; k < 64; ++k) {
            float4 a = *(const float4*)(sA + k * S + ng * 4);
            float4 b = *(const float4*)(Wt + k * OUTC + cg * 4);
            acc[0][0] += a.x * b.x; acc[0][1] += a.x * b.y; acc[0][2] += a.x * b.z; acc[0][3] += a.x * b.w;
            acc[1][0] += a.y * b.x; acc[1][1] += a.y * b.y; acc[1][2] += a.y * b.z; acc[1][3] += a.y * b.w;
            acc[2][0] += a.z * b.x; acc[2][1] += a.z * b.y; acc[2][2] += a.z * b.z; acc[2][3] += a.z * b.w;
            acc[3][0] += a.w * b.x; acc[3][1] += a.w * b.y; acc[3][2] += a.w * b.z; acc[3][3] += a.w * b.w;
        }
    }
#pragma unroll
    for (int j = 0; j < 4; ++j) {
        int n = n_base + j;
        if (n >= nnodes) continue;
        float4 o = make_float4(fmaxf(acc[j][0], 0.f), fmaxf(acc[j][1], 0.f),
                               fmaxf(acc[j][2], 0.f), fmaxf(acc[j][3], 0.f));
        __half2 tmp[2];
        tmp[0] = __floats2half2_rn(o.x, o.y);
        tmp[1] = __floats2half2_rn(o.z, o.w);
        ((float2*)(outh + (size_t)n * OUTC))[cg] = *(float2*)tmp;
    }
}

// ---------- layer-2 fan-out GEMM: [P0|G1|G2] = Hh @ Wcat (+b2 on P0 cols) ----------
// Channel-pair mapping: thread cg owns channels {2cg,2cg+1} of EACH segment ->
// all stores are aligned float2 (P0) / half2 (G1,G2); weight reads are float2.
__global__ __launch_bounds__(256) void gemm96(const __half* __restrict__ Hh,
                                              const float* __restrict__ Wcat,
                                              const float* __restrict__ b2,
                                              float* __restrict__ P0,
                                              __half* __restrict__ G1,
                                              __half* __restrict__ G2, int nnodes) {
    constexpr int NODES = 64;
    constexpr int NG = 16;     // 16 node-groups x 4 nodes
    constexpr int S = NODES + 5;
    __shared__ float sA[64 * S];

    const int tid = threadIdx.x;
    const int ng = tid % NG;
    const int cg = tid / NG;   // 16 channel-pair groups
    const int c0 = cg * 2;     // pair base within each 32-col segment
    const int node0 = blockIdx.x * NODES;
    const int n_base = node0 + ng * 4;

    float2 bp = *(const float2*)(b2 + c0);
    float acc[4][6];           // [node][seg0.x, seg0.y, seg1.x, seg1.y, seg2.x, seg2.y]
#pragma unroll
    for (int j = 0; j < 4; ++j) {
        acc[j][0] = bp.x; acc[j][1] = bp.y;
        acc[j][2] = 0.f;  acc[j][3] = 0.f;
        acc[j][4] = 0.f;  acc[j][5] = 0.f;
    }

    // stage Hh tile k-major
#pragma unroll
    for (int i = 0; i < 2; ++i) {
        int f = tid + i * 256;
        int n = f >> 3;
        int kc = f & 7;
        int gn = node0 + n;
        float4 raw = make_float4(0.f, 0.f, 0.f, 0.f);
        if (gn < nnodes) raw = ((const float4*)(Hh + (size_t)gn * 64))[kc];
        const __half2* hp = (const __half2*)&raw;
        float2 f0 = __half22float2(hp[0]);
        float2 f1 = __half22float2(hp[1]);
        float2 f2 = __half22float2(hp[2]);
        float2 f3 = __half22float2(hp[3]);
        sA[(kc * 8 + 0) * S + n] = f0.x;
        sA[(kc * 8 + 1) * S + n] = f0.y;
        sA[(kc * 8 + 2) * S + n] = f1.x;
        sA[(kc * 8 + 3) * S + n] = f1.y;
        sA[(kc * 8 + 4) * S + n] = f2.x;
        sA[(kc * 8 + 5) * S + n] = f2.y;
        sA[(kc * 8 + 6) * S + n] = f3.x;
        sA[(kc * 8 + 7) * S + n] = f3.y;
    }
    __syncthreads();
#pragma unroll 8
    for (int k = 0; k < 64; ++k) {
        float4 a = *(const float4*)(sA + k * S + ng * 4);
        float2 w0 = *(const float2*)(Wcat + k * 96 + c0);
        float2 w1 = *(const float2*)(Wcat + k * 96 + 32 + c0);
        float2 w2 = *(const float2*)(Wcat + k * 96 + 64 + c0);
        float av[4] = {a.x, a.y, a.z, a.w};
#pragma unroll
        for (int j = 0; j < 4; ++j) {
            acc[j][0] += av[j] * w0.x; acc[j][1] += av[j] * w0.y;
            acc[j][2] += av[j] * w1.x; acc[j][3] += av[j] * w1.y;
            acc[j][4] += av[j] * w2.x; acc[j][5] += av[j] * w2.y;
        }
    }
#pragma unroll
    for (int j = 0; j < 4; ++j) {
        int n = n_base + j;
        if (n >= nnodes) continue;
        *(float2*)(P0 + (size_t)n * 32 + c0) = make_float2(acc[j][0], acc[j][1]);
        *(__half2*)(G1 + (size_t)n * 32 + c0) = __floats2half2_rn(acc[j][2], acc[j][3]);
        *(__half2*)(G2 + (size_t)n * 32 + c0) = __floats2half2_rn(acc[j][4], acc[j][5]);
    }
}

extern "C" void kernel_launch(void* const* d_in, const int* in_sizes, int n_in,
                              void* d_out, int out_size, void* d_ws, size_t ws_size,
                              hipStream_t stream) {
    const float* x  = (const float*)d_in[0];
    const int*   ei = (const int*)d_in[1];
    const float* W1 = (const float*)d_in[2];
    const float* b1 = (const float*)d_in[3];
    const float* W2 = (const float*)d_in[4];
    const float* b2 = (const float*)d_in[5];
    float* out = (float*)d_out;

    const int NN = N_NODES_C;
    const int NE = N_EDGES_C;
    const size_t HFEAT_BYTES = (size_t)NN * 64 * sizeof(__half);
    const size_t H32_BYTES = (size_t)NN * 32 * sizeof(__half);

    char* ws = (char*)d_ws;
    size_t off = 0;
    auto alloc = [&](size_t bytes) -> void* {
        void* p = ws + off;
        off += (bytes + 255) & ~(size_t)255;
        return p;
    };
    int*    cnt      = (int*)alloc((size_t)NN * 4);
    int*    rowptr   = (int*)alloc((size_t)(NN + 1) * 4);
    int*    next     = (int*)alloc((size_t)NN * 4);
    float*  dis      = (float*)alloc((size_t)NN * 4);
    int*    blocksum = (int*)alloc(1024);
    int2*   colw     = (int2*)alloc((size_t)NE * 8);
    __half* xh       = (__half*)alloc(HFEAT_BYTES);
    __half* T1h      = (__half*)alloc(HFEAT_BYTES);   // layer1: T1; layer2: G1
    __half* T2h      = (__half*)alloc(HFEAT_BYTES);   // layer1: T2; layer2: G2
    __half* Hh       = (__half*)alloc(HFEAT_BYTES);
    __half* Qh       = (__half*)alloc(H32_BYTES);
    float*  P0       = (float*)alloc((size_t)NN * 32 * 4);
    float*  W1p      = (float*)alloc((size_t)3 * 64 * 64 * 4);
    float*  Wcat     = (float*)alloc((size_t)64 * 96 * 4);

    const int EB = (NE + 255) / 256;
    const int SCAN_BLOCKS = (NN + 1023) / 1024;
    const int PROPB = (NN + 3) / 4;
    const int CONVB = (NN * 64 / 4 + 255) / 256;

    // ---- CSR build + normalization + weight prep + x->fp16 ----
    hipMemsetAsync(cnt, 0, (size_t)NN * 4, stream);
    hist_kernel<<<EB, 256, 0, stream>>>(ei, cnt, NE);
    scan1<<<SCAN_BLOCKS, 256, 0, stream>>>(cnt, rowptr, blocksum, dis, NN);
    scan2<<<1, 64, 0, stream>>>(blocksum, SCAN_BLOCKS);
    scan3<<<(NN + 256) / 256, 256, 0, stream>>>(rowptr, next, blocksum, NN, NE);
    edge_scatter<<<EB, 256, 0, stream>>>(ei, dis, next, colw, NE);
    fold_w<<<(64 * 64 + 255) / 256, 256, 0, stream>>>(W1, W1p, 64 * 64);
    fold_wcat<<<(64 * 96 + 255) / 256, 256, 0, stream>>>(W2, Wcat);
    f2h_kernel<<<CONVB, 256, 0, stream>>>(x, xh, NN * 64 / 4);

    // ---- layer 1: Hh = relu(x@(W0-W2) + T1@W1 + T2@(2W2) + b1), T2 = prop(T1) ----
    prop_gather_h<<<PROPB, 256, 0, stream>>>(xh, rowptr, colw, T1h, NN);
    prop_gather_h<<<PROPB, 256, 0, stream>>>(T1h, rowptr, colw, T2h, NN);
    cheb_gemm_h<<<(NN + 63) / 64, 256, 0, stream>>>(xh, T1h, T2h, W1p, b1, Hh, NN);

    // ---- layer 2 (factored): out = P0 + prop(G1 + prop(G2)) ----
    gemm96<<<(NN + 63) / 64, 256, 0, stream>>>(Hh, Wcat, b2, P0, T1h, T2h, NN);
    prop_gather32<false><<<PROPB, 256, 0, stream>>>(T2h, rowptr, colw, T1h, Qh, NN);
    prop_gather32<true><<<PROPB, 256, 0, stream>>>(Qh, rowptr, colw, P0, out, NN);
}

// Round 8
// 432.160 us; speedup vs baseline: 1.0903x; 1.0624x over previous
//
#include <hip/hip_runtime.h>
#include <hip/hip_fp16.h>

#define N_NODES_C 100000
#define N_EDGES_C 1200000
#define NBUK ((N_NODES_C + 255) >> 8)   // 391 buckets of 256 nodes
#define CHUNK 4096                       // edges per bin_stage block

// ---------- degree histogram (int) over row ----------
__global__ void hist_kernel(const int* __restrict__ ei, int* __restrict__ cnt, int nedges) {
    int e = blockIdx.x * blockDim.x + threadIdx.x;
    if (e >= nedges) return;
    atomicAdd(cnt + ei[e], 1);
}

// ---------- exclusive scan stage 1 + fused deg_inv_sqrt ----------
__global__ __launch_bounds__(256) void scan1(const int* __restrict__ cnt, int* __restrict__ rowptr,
                                             int* __restrict__ blocksum, float* __restrict__ dis,
                                             int n) {
    __shared__ int s[256];
    int base = blockIdx.x * 1024 + threadIdx.x * 4;
    int v[4];
    int sum = 0;
#pragma unroll
    for (int i = 0; i < 4; ++i) {
        int idx = base + i;
        v[i] = (idx < n) ? cnt[idx] : 0;
        sum += v[i];
        if (idx < n) {
            float d = (float)v[i];
            dis[idx] = (d > 0.f) ? (1.0f / sqrtf(fmaxf(d, 1.f))) : 0.f;
        }
    }
    s[threadIdx.x] = sum;
    __syncthreads();
    for (int off = 1; off < 256; off <<= 1) {
        int val = s[threadIdx.x];
        int add = (threadIdx.x >= off) ? s[threadIdx.x - off] : 0;
        __syncthreads();
        s[threadIdx.x] = val + add;
        __syncthreads();
    }
    int run = (threadIdx.x > 0) ? s[threadIdx.x - 1] : 0;
#pragma unroll
    for (int i = 0; i < 4; ++i) {
        int idx = base + i;
        if (idx < n) rowptr[idx] = run;
        run += v[i];
    }
    if (threadIdx.x == 255) blocksum[blockIdx.x] = s[255];
}

// ---------- scan stage 2: serial scan of block sums (~98) ----------
__global__ void scan2(int* __restrict__ blocksum, int nb) {
    if (threadIdx.x == 0 && blockIdx.x == 0) {
        int acc = 0;
        for (int i = 0; i < nb; ++i) {
            int t = blocksum[i];
            blocksum[i] = acc;
            acc += t;
        }
    }
}

// ---------- scan stage 3: finalize rowptr, init per-bucket alloc cursors ----------
__global__ void scan3(int* __restrict__ rowptr, int* __restrict__ bucket_next,
                      const int* __restrict__ blocksum, int n, int nedges) {
    int i = blockIdx.x * blockDim.x + threadIdx.x;
    if (i < n) {
        int v = rowptr[i] + blocksum[i >> 10];
        rowptr[i] = v;
        if ((i & 255) == 0) bucket_next[i >> 8] = v;   // bucket base = rowptr[b*256]
    }
    if (i == n) rowptr[n] = nedges;
}

// ---------- phase B: LDS-binned staging of (r,c) grouped by 256-node bucket ----------
__global__ __launch_bounds__(256) void bin_stage(const int* __restrict__ ei,
                                                 int* __restrict__ bucket_next,
                                                 int2* __restrict__ staged, int nedges) {
    __shared__ int cnt[NBUK];
    __shared__ int ofs[NBUK];
    __shared__ int run[NBUK];
    __shared__ int gbase[NBUK];
    __shared__ int ssum[256];
    __shared__ int2 sedge[CHUNK];
    const int tid = threadIdx.x;
    const int base = blockIdx.x * CHUNK;
    const int nloc = min(CHUNK, nedges - base);

    for (int i = tid; i < NBUK; i += 256) { cnt[i] = 0; run[i] = 0; }
    __syncthreads();

    int r[16], c[16];
#pragma unroll
    for (int k = 0; k < 16; ++k) {
        int loc = tid + k * 256;
        bool ok = loc < nloc;
        int idx = base + loc;
        r[k] = ok ? ei[idx] : -1;
        c[k] = ok ? ei[nedges + idx] : 0;
        if (ok) atomicAdd(&cnt[r[k] >> 8], 1);
    }
    __syncthreads();

    // exclusive scan of cnt[NBUK] -> ofs (2 elems/thread + Hillis-Steele over 256)
    int a0 = (2 * tid < NBUK) ? cnt[2 * tid] : 0;
    int a1 = (2 * tid + 1 < NBUK) ? cnt[2 * tid + 1] : 0;
    ssum[tid] = a0 + a1;
    __syncthreads();
    for (int off = 1; off < 256; off <<= 1) {
        int v = ssum[tid];
        int add = (tid >= off) ? ssum[tid - off] : 0;
        __syncthreads();
        ssum[tid] = v + add;
        __syncthreads();
    }
    int excl = (tid > 0) ? ssum[tid - 1] : 0;
    if (2 * tid < NBUK) ofs[2 * tid] = excl;
    if (2 * tid + 1 < NBUK) ofs[2 * tid + 1] = excl + a0;
    __syncthreads();

    // place edges into LDS grouped by bucket
#pragma unroll
    for (int k = 0; k < 16; ++k) {
        if (r[k] >= 0) {
            int b = r[k] >> 8;
            int p = atomicAdd(&run[b], 1);
            sedge[ofs[b] + p] = make_int2(r[k], c[k]);
        }
    }
    __syncthreads();

    // allocate global runs (one atomic per non-empty bucket)
    for (int b = tid; b < NBUK; b += 256) {
        int n = cnt[b];
        gbase[b] = n ? atomicAdd(&bucket_next[b], n) : 0;
    }
    __syncthreads();

    // coalesced copy-out: consecutive i are bucket-grouped runs
    for (int i = tid; i < nloc; i += 256) {
        int2 e = sedge[i];
        int b = e.x >> 8;
        staged[gbase[b] + (i - ofs[b])] = e;
    }
}

// ---------- phase C: per-bucket exact CSR placement + norm weight ----------
__global__ __launch_bounds__(256) void bin_place(const int2* __restrict__ staged,
                                                 const int* __restrict__ rowptr,
                                                 const float* __restrict__ dis,
                                                 int2* __restrict__ colw, int nnodes) {
    __shared__ int rp[256];
    __shared__ int nx[256];
    __shared__ float dl[256];
    const int b = blockIdx.x;
    const int n0 = b << 8;
    const int nend = min(n0 + 256, nnodes);
    const int nloc = nend - n0;
    const int tid = threadIdx.x;
    if (tid < nloc) {
        rp[tid] = rowptr[n0 + tid];
        dl[tid] = dis[n0 + tid];
    }
    nx[tid] = 0;
    __syncthreads();
    const int ebase = rowptr[n0];
    const int ecount = rowptr[nend] - ebase;
    for (int i = tid; i < ecount; i += 256) {
        int2 e = staged[ebase + i];
        int rrel = e.x - n0;
        int p = atomicAdd(&nx[rrel], 1);
        float w = -dl[rrel] * dis[e.y];
        colw[rp[rrel] + p] = make_int2(e.y, __float_as_int(w));
    }
}

// ---------- fold Chebyshev recurrence into layer-1 weights: [3][64][64] k-major ----------
__global__ void fold_w(const float* __restrict__ W, float* __restrict__ Wp, int total) {
    int i = blockIdx.x * blockDim.x + threadIdx.x;
    if (i >= total) return;
    float w0 = W[i], w1 = W[total + i], w2 = W[2 * total + i];
    Wp[i] = w0 - w2;
    Wp[total + i] = w1;
    Wp[2 * total + i] = 2.0f * w2;
}

// ---------- layer-2 weights concatenated: Wcat[k][0:32]=W0-W2, [32:64]=W1, [64:96]=2W2 ----------
__global__ void fold_wcat(const float* __restrict__ W, float* __restrict__ Wcat) {
    int i = blockIdx.x * blockDim.x + threadIdx.x;
    if (i >= 64 * 96) return;
    int k = i / 96;
    int c = i % 96;
    float v;
    if (c < 32) v = W[k * 32 + c] - W[2 * 2048 + k * 32 + c];
    else if (c < 64) v = W[2048 + k * 32 + (c - 32)];
    else v = 2.0f * W[2 * 2048 + k * 32 + (c - 64)];
    Wcat[i] = v;
}

// ---------- fp32 -> fp16 feature conversion (4 elems/thread) ----------
__global__ void f2h_kernel(const float* __restrict__ in, __half* __restrict__ out, int n4) {
    int i = blockIdx.x * blockDim.x + threadIdx.x;
    if (i >= n4) return;
    float4 v = ((const float4*)in)[i];
    __half2 tmp[2];
    tmp[0] = __floats2half2_rn(v.x, v.y);
    tmp[1] = __floats2half2_rn(v.z, v.w);
    ((float2*)out)[i] = *(float2*)tmp;
}

// ---------- prop64: 8 lanes/edge, chunk loop unrolled x2 (2 gathers in flight) ----------
__global__ __launch_bounds__(256) void prop_gather_h(const __half* __restrict__ t,
                                                     const int* __restrict__ rowptr,
                                                     const int2* __restrict__ colw,
                                                     __half* __restrict__ out, int nnodes) {
    int node = blockIdx.x * 4 + (threadIdx.x >> 6);
    if (node >= nnodes) return;
    int lane = threadIdx.x & 63;
    int g = lane >> 3;    // edge group 0..7
    int gl = lane & 7;    // channel octet
    int s = rowptr[node];
    int e = rowptr[node + 1];
    float acc[8] = {0.f, 0.f, 0.f, 0.f, 0.f, 0.f, 0.f, 0.f};
    for (int base = s; base < e; base += 64) {
        int m = e - base;
        if (m > 64) m = 64;
        int2 cw = (lane < m) ? colw[base + lane] : make_int2(0, 0);
        int iters = (m + 7) >> 3;
        for (int it = 0; it < iters; it += 2) {
            int j0 = (it << 3) | g;
            int j1 = j0 + 8;                        // sentinel (0,0) if >= m: w=0, row-0 L1-hot
            int c0 = __shfl(cw.x, j0);
            float w0 = __int_as_float(__shfl(cw.y, j0));
            int c1 = __shfl(cw.x, j1);
            float w1 = __int_as_float(__shfl(cw.y, j1));
            float4 raw0 = ((const float4*)(t + (size_t)c0 * 64))[gl];
            float4 raw1 = ((const float4*)(t + (size_t)c1 * 64))[gl];
            const __half2* h0 = (const __half2*)&raw0;
            const __half2* h1 = (const __half2*)&raw1;
#pragma unroll
            for (int q = 0; q < 4; ++q) {
                float2 f0 = __half22float2(h0[q]);
                float2 f1 = __half22float2(h1[q]);
                acc[2 * q + 0] += w0 * f0.x + w1 * f1.x;
                acc[2 * q + 1] += w0 * f0.y + w1 * f1.y;
            }
        }
    }
#pragma unroll
    for (int i = 0; i < 8; ++i) {
        acc[i] += __shfl_xor(acc[i], 8);
        acc[i] += __shfl_xor(acc[i], 16);
        acc[i] += __shfl_xor(acc[i], 32);
    }
    if (g == 0) {
        __half2 tmp[4];
        tmp[0] = __floats2half2_rn(acc[0], acc[1]);
        tmp[1] = __floats2half2_rn(acc[2], acc[3]);
        tmp[2] = __floats2half2_rn(acc[4], acc[5]);
        tmp[3] = __floats2half2_rn(acc[6], acc[7]);
        ((float4*)(out + (size_t)node * 64))[gl] = *(float4*)tmp;
    }
}

// ---------- prop32: 4 lanes/edge, unrolled x2; fused add-input; fp16/fp32 out ----------
template <bool F32OUT>
__global__ __launch_bounds__(256) void prop_gather32(const __half* __restrict__ t,
                                                     const int* __restrict__ rowptr,
                                                     const int2* __restrict__ colw,
                                                     const void* __restrict__ addin,
                                                     void* __restrict__ outv, int nnodes) {
    int node = blockIdx.x * 4 + (threadIdx.x >> 6);
    if (node >= nnodes) return;
    int lane = threadIdx.x & 63;
    int g = lane >> 2;    // edge group 0..15
    int gl = lane & 3;    // channel octet
    int s = rowptr[node];
    int e = rowptr[node + 1];
    float acc[8] = {0.f, 0.f, 0.f, 0.f, 0.f, 0.f, 0.f, 0.f};
    for (int base = s; base < e; base += 64) {
        int m = e - base;
        if (m > 64) m = 64;
        int2 cw = (lane < m) ? colw[base + lane] : make_int2(0, 0);
        int iters = (m + 15) >> 4;
        for (int it = 0; it < iters; it += 2) {
            int j0 = (it << 4) | g;
            int j1 = j0 + 16;                       // sentinel-safe
            int c0 = __shfl(cw.x, j0);
            float w0 = __int_as_float(__shfl(cw.y, j0));
            int c1 = __shfl(cw.x, j1);
            float w1 = __int_as_float(__shfl(cw.y, j1));
            float4 raw0 = ((const float4*)(t + (size_t)c0 * 32))[gl];
            float4 raw1 = ((const float4*)(t + (size_t)c1 * 32))[gl];
            const __half2* h0 = (const __half2*)&raw0;
            const __half2* h1 = (const __half2*)&raw1;
#pragma unroll
            for (int q = 0; q < 4; ++q) {
                float2 f0 = __half22float2(h0[q]);
                float2 f1 = __half22float2(h1[q]);
                acc[2 * q + 0] += w0 * f0.x + w1 * f1.x;
                acc[2 * q + 1] += w0 * f0.y + w1 * f1.y;
            }
        }
    }
#pragma unroll
    for (int i = 0; i < 8; ++i) {
        acc[i] += __shfl_xor(acc[i], 4);
        acc[i] += __shfl_xor(acc[i], 8);
        acc[i] += __shfl_xor(acc[i], 16);
        acc[i] += __shfl_xor(acc[i], 32);
    }
    if (g == 0) {
        if (F32OUT) {
            const float* add = (const float*)addin;
            float* out = (float*)outv;
            float4 a0 = ((const float4*)(add + (size_t)node * 32))[gl * 2 + 0];
            float4 a1 = ((const float4*)(add + (size_t)node * 32))[gl * 2 + 1];
            a0.x += acc[0]; a0.y += acc[1]; a0.z += acc[2]; a0.w += acc[3];
            a1.x += acc[4]; a1.y += acc[5]; a1.z += acc[6]; a1.w += acc[7];
            ((float4*)(out + (size_t)node * 32))[gl * 2 + 0] = a0;
            ((float4*)(out + (size_t)node * 32))[gl * 2 + 1] = a1;
        } else {
            const __half* add = (const __half*)addin;
            __half* out = (__half*)outv;
            float4 raw = ((const float4*)(add + (size_t)node * 32))[gl];
            const __half2* hp = (const __half2*)&raw;
            float2 f0 = __half22float2(hp[0]);
            float2 f1 = __half22float2(hp[1]);
            float2 f2 = __half22float2(hp[2]);
            float2 f3 = __half22float2(hp[3]);
            __half2 tmp[4];
            tmp[0] = __floats2half2_rn(acc[0] + f0.x, acc[1] + f0.y);
            tmp[1] = __floats2half2_rn(acc[2] + f1.x, acc[3] + f1.y);
            tmp[2] = __floats2half2_rn(acc[4] + f2.x, acc[5] + f2.y);
            tmp[3] = __floats2half2_rn(acc[6] + f3.x, acc[7] + f3.y);
            ((float4*)(out + (size_t)node * 32))[gl] = *(float4*)tmp;
        }
    }
}

// ---------- layer-1 register-tiled GEMM: Hh = relu([A0|A1|A2] @ Wp + bias), fp16 out ----------
__global__ __launch_bounds__(256) void cheb_gemm_h(const __half* __restrict__ A0,
                                                   const __half* __restrict__ A1,
                                                   const __half* __restrict__ A2,
                                                   const float* __restrict__ Wp,
                                                   const float* __restrict__ bias,
                                                   __half* __restrict__ outh, int nnodes) {
    constexpr int OUTC = 64;
    constexpr int NODES = 64;
    constexpr int NG = 16;
    constexpr int S = NODES + 5;
    constexpr int F8 = NODES * 8 / 256;
    __shared__ float sA[64 * S];

    const int tid = threadIdx.x;
    const int ng = tid % NG;
    const int cg = tid / NG;
    const int node0 = blockIdx.x * NODES;
    const int n_base = node0 + ng * 4;

    float4 bv = *(const float4*)(bias + cg * 4);
    float acc[4][4];
#pragma unroll
    for (int j = 0; j < 4; ++j) {
        acc[j][0] = bv.x; acc[j][1] = bv.y; acc[j][2] = bv.z; acc[j][3] = bv.w;
    }

    const __half* Aptr[3] = {A0, A1, A2};
    for (int term = 0; term < 3; ++term) {
        const __half* A = Aptr[term];
        __syncthreads();
#pragma unroll
        for (int i = 0; i < F8; ++i) {
            int f = tid + i * 256;
            int n = f >> 3;
            int kc = f & 7;
            int gn = node0 + n;
            float4 raw = make_float4(0.f, 0.f, 0.f, 0.f);
            if (gn < nnodes) raw = ((const float4*)(A + (size_t)gn * 64))[kc];
            const __half2* hp = (const __half2*)&raw;
            float2 f0 = __half22float2(hp[0]);
            float2 f1 = __half22float2(hp[1]);
            float2 f2 = __half22float2(hp[2]);
            float2 f3 = __half22float2(hp[3]);
            sA[(kc * 8 + 0) * S + n] = f0.x;
            sA[(kc * 8 + 1) * S + n] = f0.y;
            sA[(kc * 8 + 2) * S + n] = f1.x;
            sA[(kc * 8 + 3) * S + n] = f1.y;
            sA[(kc * 8 + 4) * S + n] = f2.x;
            sA[(kc * 8 + 5) * S + n] = f2.y;
            sA[(kc * 8 + 6) * S + n] = f3.x;
            sA[(kc * 8 + 7) * S + n] = f3.y;
        }
        __syncthreads();
        const float* Wt = Wp + term * 64 * OUTC;
#pragma unroll 8
        for (int k = 0; k < 64; ++k) {
            float4 a = *(const float4*)(sA + k * S + ng * 4);
            float4 b = *(const float4*)(Wt + k * OUTC + cg * 4);
            acc[0][0] += a.x * b.x; acc[0][1] += a.x * b.y; acc[0][2] += a.x * b.z; acc[0][3] += a.x * b.w;
            acc[1][0] += a.y * b.x; acc[1][1] += a.y * b.y; acc[1][2] += a.y * b.z; acc[1][3] += a.y * b.w;
            acc[2][0] += a.z * b.x; acc[2][1] += a.z * b.y; acc[2][2] += a.z * b.z; acc[2][3] += a.z * b.w;
            acc[3][0] += a.w * b.x; acc[3][1] += a.w * b.y; acc[3][2] += a.w * b.z; acc[3][3] += a.w * b.w;
        }
    }
#pragma unroll
    for (int j = 0; j < 4; ++j) {
        int n = n_base + j;
        if (n >= nnodes) continue;
        float4 o = make_float4(fmaxf(acc[j][0], 0.f), fmaxf(acc[j][1], 0.f),
                               fmaxf(acc[j][2], 0.f), fmaxf(acc[j][3], 0.f));
        __half2 tmp[2];
        tmp[0] = __floats2half2_rn(o.x, o.y);
        tmp[1] = __floats2half2_rn(o.z, o.w);
        ((float2*)(outh + (size_t)n * OUTC))[cg] = *(float2*)tmp;
    }
}

// ---------- layer-2 fan-out GEMM: [P0|G1|G2] = Hh @ Wcat (+b2 on P0 cols) ----------
__global__ __launch_bounds__(256) void gemm96(const __half* __restrict__ Hh,
                                              const float* __restrict__ Wcat,
                                              const float* __restrict__ b2,
                                              float* __restrict__ P0,
                                              __half* __restrict__ G1,
                                              __half* __restrict__ G2, int nnodes) {
    constexpr int NODES = 64;
    constexpr int NG = 16;
    constexpr int S = NODES + 5;
    __shared__ float sA[64 * S];

    const int tid = threadIdx.x;
    const int ng = tid % NG;
    const int cg = tid / NG;   // 16 channel-pair groups
    const int c0 = cg * 2;
    const int node0 = blockIdx.x * NODES;
    const int n_base = node0 + ng * 4;

    float2 bp = *(const float2*)(b2 + c0);
    float acc[4][6];
#pragma unroll
    for (int j = 0; j < 4; ++j) {
        acc[j][0] = bp.x; acc[j][1] = bp.y;
        acc[j][2] = 0.f;  acc[j][3] = 0.f;
        acc[j][4] = 0.f;  acc[j][5] = 0.f;
    }

#pragma unroll
    for (int i = 0; i < 2; ++i) {
        int f = tid + i * 256;
        int n = f >> 3;
        int kc = f & 7;
        int gn = node0 + n;
        float4 raw = make_float4(0.f, 0.f, 0.f, 0.f);
        if (gn < nnodes) raw = ((const float4*)(Hh + (size_t)gn * 64))[kc];
        const __half2* hp = (const __half2*)&raw;
        float2 f0 = __half22float2(hp[0]);
        float2 f1 = __half22float2(hp[1]);
        float2 f2 = __half22float2(hp[2]);
        float2 f3 = __half22float2(hp[3]);
        sA[(kc * 8 + 0) * S + n] = f0.x;
        sA[(kc * 8 + 1) * S + n] = f0.y;
        sA[(kc * 8 + 2) * S + n] = f1.x;
        sA[(kc * 8 + 3) * S + n] = f1.y;
        sA[(kc * 8 + 4) * S + n] = f2.x;
        sA[(kc * 8 + 5) * S + n] = f2.y;
        sA[(kc * 8 + 6) * S + n] = f3.x;
        sA[(kc * 8 + 7) * S + n] = f3.y;
    }
    __syncthreads();
#pragma unroll 8
    for (int k = 0; k < 64; ++k) {
        float4 a = *(const float4*)(sA + k * S + ng * 4);
        float2 w0 = *(const float2*)(Wcat + k * 96 + c0);
        float2 w1 = *(const float2*)(Wcat + k * 96 + 32 + c0);
        float2 w2 = *(const float2*)(Wcat + k * 96 + 64 + c0);
        float av[4] = {a.x, a.y, a.z, a.w};
#pragma unroll
        for (int j = 0; j < 4; ++j) {
            acc[j][0] += av[j] * w0.x; acc[j][1] += av[j] * w0.y;
            acc[j][2] += av[j] * w1.x; acc[j][3] += av[j] * w1.y;
            acc[j][4] += av[j] * w2.x; acc[j][5] += av[j] * w2.y;
        }
    }
#pragma unroll
    for (int j = 0; j < 4; ++j) {
        int n = n_base + j;
        if (n >= nnodes) continue;
        *(float2*)(P0 + (size_t)n * 32 + c0) = make_float2(acc[j][0], acc[j][1]);
        *(__half2*)(G1 + (size_t)n * 32 + c0) = __floats2half2_rn(acc[j][2], acc[j][3]);
        *(__half2*)(G2 + (size_t)n * 32 + c0) = __floats2half2_rn(acc[j][4], acc[j][5]);
    }
}

extern "C" void kernel_launch(void* const* d_in, const int* in_sizes, int n_in,
                              void* d_out, int out_size, void* d_ws, size_t ws_size,
                              hipStream_t stream) {
    const float* x  = (const float*)d_in[0];
    const int*   ei = (const int*)d_in[1];
    const float* W1 = (const float*)d_in[2];
    const float* b1 = (const float*)d_in[3];
    const float* W2 = (const float*)d_in[4];
    const float* b2 = (const float*)d_in[5];
    float* out = (float*)d_out;

    const int NN = N_NODES_C;
    const int NE = N_EDGES_C;
    const size_t HFEAT_BYTES = (size_t)NN * 64 * sizeof(__half);
    const size_t H32_BYTES = (size_t)NN * 32 * sizeof(__half);

    char* ws = (char*)d_ws;
    size_t off = 0;
    auto alloc = [&](size_t bytes) -> void* {
        void* p = ws + off;
        off += (bytes + 255) & ~(size_t)255;
        return p;
    };
    int*    cnt         = (int*)alloc((size_t)NN * 4);
    int*    rowptr      = (int*)alloc((size_t)(NN + 1) * 4);
    float*  dis         = (float*)alloc((size_t)NN * 4);
    int*    blocksum    = (int*)alloc(1024);
    int*    bucket_next = (int*)alloc((size_t)NBUK * 4);
    int2*   staged      = (int2*)alloc((size_t)NE * 8);
    int2*   colw        = (int2*)alloc((size_t)NE * 8);
    __half* xh          = (__half*)alloc(HFEAT_BYTES);
    __half* T1h         = (__half*)alloc(HFEAT_BYTES);   // layer1: T1; layer2: G1
    __half* T2h         = (__half*)alloc(HFEAT_BYTES);   // layer1: T2; layer2: G2
    __half* Hh          = (__half*)alloc(HFEAT_BYTES);
    __half* Qh          = (__half*)alloc(H32_BYTES);
    float*  P0          = (float*)alloc((size_t)NN * 32 * 4);
    float*  W1p         = (float*)alloc((size_t)3 * 64 * 64 * 4);
    float*  Wcat        = (float*)alloc((size_t)64 * 96 * 4);

    const int EB = (NE + 255) / 256;
    const int SCAN_BLOCKS = (NN + 1023) / 1024;
    const int PROPB = (NN + 3) / 4;
    const int CONVB = (NN * 64 / 4 + 255) / 256;
    const int STAGEB = (NE + CHUNK - 1) / CHUNK;

    // ---- CSR build (binned) + normalization + weight prep + x->fp16 ----
    hipMemsetAsync(cnt, 0, (size_t)NN * 4, stream);
    hist_kernel<<<EB, 256, 0, stream>>>(ei, cnt, NE);
    scan1<<<SCAN_BLOCKS, 256, 0, stream>>>(cnt, rowptr, blocksum, dis, NN);
    scan2<<<1, 64, 0, stream>>>(blocksum, SCAN_BLOCKS);
    scan3<<<(NN + 256) / 256, 256, 0, stream>>>(rowptr, bucket_next, blocksum, NN, NE);
    bin_stage<<<STAGEB, 256, 0, stream>>>(ei, bucket_next, staged, NE);
    bin_place<<<NBUK, 256, 0, stream>>>(staged, rowptr, dis, colw, NN);
    fold_w<<<(64 * 64 + 255) / 256, 256, 0, stream>>>(W1, W1p, 64 * 64);
    fold_wcat<<<(64 * 96 + 255) / 256, 256, 0, stream>>>(W2, Wcat);
    f2h_kernel<<<CONVB, 256, 0, stream>>>(x, xh, NN * 64 / 4);

    // ---- layer 1: Hh = relu(x@(W0-W2) + T1@W1 + T2@(2W2) + b1), T2 = prop(T1) ----
    prop_gather_h<<<PROPB, 256, 0, stream>>>(xh, rowptr, colw, T1h, NN);
    prop_gather_h<<<PROPB, 256, 0, stream>>>(T1h, rowptr, colw, T2h, NN);
    cheb_gemm_h<<<(NN + 63) / 64, 256, 0, stream>>>(xh, T1h, T2h, W1p, b1, Hh, NN);

    // ---- layer 2 (factored): out = P0 + prop(G1 + prop(G2)) ----
    gemm96<<<(NN + 63) / 64, 256, 0, stream>>>(Hh, Wcat, b2, P0, T1h, T2h, NN);
    prop_gather32<false><<<PROPB, 256, 0, stream>>>(T2h, rowptr, colw, T1h, Qh, NN);
    prop_gather32<true><<<PROPB, 256, 0, stream>>>(Qh, rowptr, colw, P0, out, NN);
}

// Round 9
// 430.399 us; speedup vs baseline: 1.0948x; 1.0041x over previous
//
#include <hip/hip_runtime.h>
#include <hip/hip_fp16.h>

#define N_NODES_C 100000
#define N_EDGES_C 1200000
#define NBUK ((N_NODES_C + 255) >> 8)   // 391 buckets of 256 nodes
#define CHUNK 4096                       // edges per bin_stage block

// ---------- degree histogram (int) over row ----------
__global__ void hist_kernel(const int* __restrict__ ei, int* __restrict__ cnt, int nedges) {
    int e = blockIdx.x * blockDim.x + threadIdx.x;
    if (e >= nedges) return;
    atomicAdd(cnt + ei[e], 1);
}

// ---------- exclusive scan stage 1 + fused deg_inv_sqrt ----------
__global__ __launch_bounds__(256) void scan1(const int* __restrict__ cnt, int* __restrict__ rowptr,
                                             int* __restrict__ blocksum, float* __restrict__ dis,
                                             int n) {
    __shared__ int s[256];
    int base = blockIdx.x * 1024 + threadIdx.x * 4;
    int v[4];
    int sum = 0;
#pragma unroll
    for (int i = 0; i < 4; ++i) {
        int idx = base + i;
        v[i] = (idx < n) ? cnt[idx] : 0;
        sum += v[i];
        if (idx < n) {
            float d = (float)v[i];
            dis[idx] = (d > 0.f) ? (1.0f / sqrtf(fmaxf(d, 1.f))) : 0.f;
        }
    }
    s[threadIdx.x] = sum;
    __syncthreads();
    for (int off = 1; off < 256; off <<= 1) {
        int val = s[threadIdx.x];
        int add = (threadIdx.x >= off) ? s[threadIdx.x - off] : 0;
        __syncthreads();
        s[threadIdx.x] = val + add;
        __syncthreads();
    }
    int run = (threadIdx.x > 0) ? s[threadIdx.x - 1] : 0;
#pragma unroll
    for (int i = 0; i < 4; ++i) {
        int idx = base + i;
        if (idx < n) rowptr[idx] = run;
        run += v[i];
    }
    if (threadIdx.x == 255) blocksum[blockIdx.x] = s[255];
}

// ---------- scan stage 2: serial scan of block sums (~98) ----------
__global__ void scan2(int* __restrict__ blocksum, int nb) {
    if (threadIdx.x == 0 && blockIdx.x == 0) {
        int acc = 0;
        for (int i = 0; i < nb; ++i) {
            int t = blocksum[i];
            blocksum[i] = acc;
            acc += t;
        }
    }
}

// ---------- scan stage 3: finalize rowptr, init per-bucket alloc cursors ----------
__global__ void scan3(int* __restrict__ rowptr, int* __restrict__ bucket_next,
                      const int* __restrict__ blocksum, int n, int nedges) {
    int i = blockIdx.x * blockDim.x + threadIdx.x;
    if (i < n) {
        int v = rowptr[i] + blocksum[i >> 10];
        rowptr[i] = v;
        if ((i & 255) == 0) bucket_next[i >> 8] = v;   // bucket base = rowptr[b*256]
    }
    if (i == n) rowptr[n] = nedges;
}

// ---------- phase B: LDS-binned staging of (r,c) grouped by 256-node bucket ----------
__global__ __launch_bounds__(256) void bin_stage(const int* __restrict__ ei,
                                                 int* __restrict__ bucket_next,
                                                 int2* __restrict__ staged, int nedges) {
    __shared__ int cnt[NBUK];
    __shared__ int ofs[NBUK];
    __shared__ int run[NBUK];
    __shared__ int gbase[NBUK];
    __shared__ int ssum[256];
    __shared__ int2 sedge[CHUNK];
    const int tid = threadIdx.x;
    const int base = blockIdx.x * CHUNK;
    const int nloc = min(CHUNK, nedges - base);

    for (int i = tid; i < NBUK; i += 256) { cnt[i] = 0; run[i] = 0; }
    __syncthreads();

    int r[16], c[16];
#pragma unroll
    for (int k = 0; k < 16; ++k) {
        int loc = tid + k * 256;
        bool ok = loc < nloc;
        int idx = base + loc;
        r[k] = ok ? ei[idx] : -1;
        c[k] = ok ? ei[nedges + idx] : 0;
        if (ok) atomicAdd(&cnt[r[k] >> 8], 1);
    }
    __syncthreads();

    // exclusive scan of cnt[NBUK] -> ofs
    int a0 = (2 * tid < NBUK) ? cnt[2 * tid] : 0;
    int a1 = (2 * tid + 1 < NBUK) ? cnt[2 * tid + 1] : 0;
    ssum[tid] = a0 + a1;
    __syncthreads();
    for (int off = 1; off < 256; off <<= 1) {
        int v = ssum[tid];
        int add = (tid >= off) ? ssum[tid - off] : 0;
        __syncthreads();
        ssum[tid] = v + add;
        __syncthreads();
    }
    int excl = (tid > 0) ? ssum[tid - 1] : 0;
    if (2 * tid < NBUK) ofs[2 * tid] = excl;
    if (2 * tid + 1 < NBUK) ofs[2 * tid + 1] = excl + a0;
    __syncthreads();

    // place edges into LDS grouped by bucket
#pragma unroll
    for (int k = 0; k < 16; ++k) {
        if (r[k] >= 0) {
            int b = r[k] >> 8;
            int p = atomicAdd(&run[b], 1);
            sedge[ofs[b] + p] = make_int2(r[k], c[k]);
        }
    }
    __syncthreads();

    // allocate global runs (one atomic per non-empty bucket)
    for (int b = tid; b < NBUK; b += 256) {
        int n = cnt[b];
        gbase[b] = n ? atomicAdd(&bucket_next[b], n) : 0;
    }
    __syncthreads();

    // coalesced copy-out: consecutive i are bucket-grouped runs
    for (int i = tid; i < nloc; i += 256) {
        int2 e = sedge[i];
        int b = e.x >> 8;
        staged[gbase[b] + (i - ofs[b])] = e;
    }
}

// ---------- phase C: per-bucket exact CSR placement + norm weight ----------
__global__ __launch_bounds__(256) void bin_place(const int2* __restrict__ staged,
                                                 const int* __restrict__ rowptr,
                                                 const float* __restrict__ dis,
                                                 int2* __restrict__ colw, int nnodes) {
    __shared__ int rp[256];
    __shared__ int nx[256];
    __shared__ float dl[256];
    const int b = blockIdx.x;
    const int n0 = b << 8;
    const int nend = min(n0 + 256, nnodes);
    const int nloc = nend - n0;
    const int tid = threadIdx.x;
    if (tid < nloc) {
        rp[tid] = rowptr[n0 + tid];
        dl[tid] = dis[n0 + tid];
    }
    nx[tid] = 0;
    __syncthreads();
    const int ebase = rowptr[n0];
    const int ecount = rowptr[nend] - ebase;
    for (int i = tid; i < ecount; i += 256) {
        int2 e = staged[ebase + i];
        int rrel = e.x - n0;
        int p = atomicAdd(&nx[rrel], 1);
        float w = -dl[rrel] * dis[e.y];
        colw[rp[rrel] + p] = make_int2(e.y, __float_as_int(w));
    }
}

// ---------- fold Chebyshev recurrence into layer-1 weights: [3][64][64] k-major ----------
__global__ void fold_w(const float* __restrict__ W, float* __restrict__ Wp, int total) {
    int i = blockIdx.x * blockDim.x + threadIdx.x;
    if (i >= total) return;
    float w0 = W[i], w1 = W[total + i], w2 = W[2 * total + i];
    Wp[i] = w0 - w2;
    Wp[total + i] = w1;
    Wp[2 * total + i] = 2.0f * w2;
}

// ---------- layer-2 weights concatenated: Wcat[k][0:32]=W0-W2, [32:64]=W1, [64:96]=2W2 ----------
__global__ void fold_wcat(const float* __restrict__ W, float* __restrict__ Wcat) {
    int i = blockIdx.x * blockDim.x + threadIdx.x;
    if (i >= 64 * 96) return;
    int k = i / 96;
    int c = i % 96;
    float v;
    if (c < 32) v = W[k * 32 + c] - W[2 * 2048 + k * 32 + c];
    else if (c < 64) v = W[2048 + k * 32 + (c - 32)];
    else v = 2.0f * W[2 * 2048 + k * 32 + (c - 64)];
    Wcat[i] = v;
}

// ---------- fp32 -> fp16 feature conversion (4 elems/thread) ----------
__global__ void f2h_kernel(const float* __restrict__ in, __half* __restrict__ out, int n4) {
    int i = blockIdx.x * blockDim.x + threadIdx.x;
    if (i >= n4) return;
    float4 v = ((const float4*)in)[i];
    __half2 tmp[2];
    tmp[0] = __floats2half2_rn(v.x, v.y);
    tmp[1] = __floats2half2_rn(v.z, v.w);
    ((float2*)out)[i] = *(float2*)tmp;
}

// ---------- prop64: 8 lanes/edge, chunk loop unrolled x2 (2 gathers in flight) ----------
__global__ __launch_bounds__(256) void prop_gather_h(const __half* __restrict__ t,
                                                     const int* __restrict__ rowptr,
                                                     const int2* __restrict__ colw,
                                                     __half* __restrict__ out, int nnodes) {
    int node = blockIdx.x * 4 + (threadIdx.x >> 6);
    if (node >= nnodes) return;
    int lane = threadIdx.x & 63;
    int g = lane >> 3;    // edge group 0..7
    int gl = lane & 7;    // channel octet
    int s = rowptr[node];
    int e = rowptr[node + 1];
    float acc[8] = {0.f, 0.f, 0.f, 0.f, 0.f, 0.f, 0.f, 0.f};
    for (int base = s; base < e; base += 64) {
        int m = e - base;
        if (m > 64) m = 64;
        int2 cw = (lane < m) ? colw[base + lane] : make_int2(0, 0);
        int iters = (m + 7) >> 3;
        for (int it = 0; it < iters; it += 2) {
            int j0 = (it << 3) | g;
            int j1 = j0 + 8;                        // sentinel (0,0) if >= m: w=0, row-0 L1-hot
            int c0 = __shfl(cw.x, j0);
            float w0 = __int_as_float(__shfl(cw.y, j0));
            int c1 = __shfl(cw.x, j1);
            float w1 = __int_as_float(__shfl(cw.y, j1));
            float4 raw0 = ((const float4*)(t + (size_t)c0 * 64))[gl];
            float4 raw1 = ((const float4*)(t + (size_t)c1 * 64))[gl];
            const __half2* h0 = (const __half2*)&raw0;
            const __half2* h1 = (const __half2*)&raw1;
#pragma unroll
            for (int q = 0; q < 4; ++q) {
                float2 f0 = __half22float2(h0[q]);
                float2 f1 = __half22float2(h1[q]);
                acc[2 * q + 0] += w0 * f0.x + w1 * f1.x;
                acc[2 * q + 1] += w0 * f0.y + w1 * f1.y;
            }
        }
    }
#pragma unroll
    for (int i = 0; i < 8; ++i) {
        acc[i] += __shfl_xor(acc[i], 8);
        acc[i] += __shfl_xor(acc[i], 16);
        acc[i] += __shfl_xor(acc[i], 32);
    }
    if (g == 0) {
        __half2 tmp[4];
        tmp[0] = __floats2half2_rn(acc[0], acc[1]);
        tmp[1] = __floats2half2_rn(acc[2], acc[3]);
        tmp[2] = __floats2half2_rn(acc[4], acc[5]);
        tmp[3] = __floats2half2_rn(acc[6], acc[7]);
        ((float4*)(out + (size_t)node * 64))[gl] = *(float4*)tmp;
    }
}

// ---------- prop32: 4 lanes/edge, unrolled x2; fused add-input; fp16/fp32 out ----------
template <bool F32OUT>
__global__ __launch_bounds__(256) void prop_gather32(const __half* __restrict__ t,
                                                     const int* __restrict__ rowptr,
                                                     const int2* __restrict__ colw,
                                                     const void* __restrict__ addin,
                                                     void* __restrict__ outv, int nnodes) {
    int node = blockIdx.x * 4 + (threadIdx.x >> 6);
    if (node >= nnodes) return;
    int lane = threadIdx.x & 63;
    int g = lane >> 2;    // edge group 0..15
    int gl = lane & 3;    // channel octet
    int s = rowptr[node];
    int e = rowptr[node + 1];
    float acc[8] = {0.f, 0.f, 0.f, 0.f, 0.f, 0.f, 0.f, 0.f};
    for (int base = s; base < e; base += 64) {
        int m = e - base;
        if (m > 64) m = 64;
        int2 cw = (lane < m) ? colw[base + lane] : make_int2(0, 0);
        int iters = (m + 15) >> 4;
        for (int it = 0; it < iters; it += 2) {
            int j0 = (it << 4) | g;
            int j1 = j0 + 16;                       // sentinel-safe
            int c0 = __shfl(cw.x, j0);
            float w0 = __int_as_float(__shfl(cw.y, j0));
            int c1 = __shfl(cw.x, j1);
            float w1 = __int_as_float(__shfl(cw.y, j1));
            float4 raw0 = ((const float4*)(t + (size_t)c0 * 32))[gl];
            float4 raw1 = ((const float4*)(t + (size_t)c1 * 32))[gl];
            const __half2* h0 = (const __half2*)&raw0;
            const __half2* h1 = (const __half2*)&raw1;
#pragma unroll
            for (int q = 0; q < 4; ++q) {
                float2 f0 = __half22float2(h0[q]);
                float2 f1 = __half22float2(h1[q]);
                acc[2 * q + 0] += w0 * f0.x + w1 * f1.x;
                acc[2 * q + 1] += w0 * f0.y + w1 * f1.y;
            }
        }
    }
#pragma unroll
    for (int i = 0; i < 8; ++i) {
        acc[i] += __shfl_xor(acc[i], 4);
        acc[i] += __shfl_xor(acc[i], 8);
        acc[i] += __shfl_xor(acc[i], 16);
        acc[i] += __shfl_xor(acc[i], 32);
    }
    if (g == 0) {
        if (F32OUT) {
            const float* add = (const float*)addin;
            float* out = (float*)outv;
            float4 a0 = ((const float4*)(add + (size_t)node * 32))[gl * 2 + 0];
            float4 a1 = ((const float4*)(add + (size_t)node * 32))[gl * 2 + 1];
            a0.x += acc[0]; a0.y += acc[1]; a0.z += acc[2]; a0.w += acc[3];
            a1.x += acc[4]; a1.y += acc[5]; a1.z += acc[6]; a1.w += acc[7];
            ((float4*)(out + (size_t)node * 32))[gl * 2 + 0] = a0;
            ((float4*)(out + (size_t)node * 32))[gl * 2 + 1] = a1;
        } else {
            const __half* add = (const __half*)addin;
            __half* out = (__half*)outv;
            float4 raw = ((const float4*)(add + (size_t)node * 32))[gl];
            const __half2* hp = (const __half2*)&raw;
            float2 f0 = __half22float2(hp[0]);
            float2 f1 = __half22float2(hp[1]);
            float2 f2 = __half22float2(hp[2]);
            float2 f3 = __half22float2(hp[3]);
            __half2 tmp[4];
            tmp[0] = __floats2half2_rn(acc[0] + f0.x, acc[1] + f0.y);
            tmp[1] = __floats2half2_rn(acc[2] + f1.x, acc[3] + f1.y);
            tmp[2] = __floats2half2_rn(acc[4] + f2.x, acc[5] + f2.y);
            tmp[3] = __floats2half2_rn(acc[6] + f3.x, acc[7] + f3.y);
            ((float4*)(out + (size_t)node * 32))[gl] = *(float4*)tmp;
        }
    }
}

// ---- LDS A-tile: S=64, XOR granule swizzle.
// element (k, n) stored at k*64 + ((n>>2) ^ ((k>>3)&7))*4 + (n&3)
// writes: per-instr lanes span kc(0..7) x g(2) x o(4) -> bank 4*(g^kc)+o: 2-way, free
// reads:  float4 at granule (ng ^ ((k>>3)&7)) -> aligned b128, bijective, conflict-free

// ---------- layer-1 register-tiled GEMM: Hh = relu([A0|A1|A2] @ Wp + bias), fp16 out ----------
__global__ __launch_bounds__(256) void cheb_gemm_h(const __half* __restrict__ A0,
                                                   const __half* __restrict__ A1,
                                                   const __half* __restrict__ A2,
                                                   const float* __restrict__ Wp,
                                                   const float* __restrict__ bias,
                                                   __half* __restrict__ outh, int nnodes) {
    constexpr int OUTC = 64;
    constexpr int NODES = 64;
    constexpr int NG = 16;
    constexpr int F8 = NODES * 8 / 256;
    __shared__ float sA[64 * 64];

    const int tid = threadIdx.x;
    const int ng = tid % NG;
    const int cg = tid / NG;
    const int node0 = blockIdx.x * NODES;
    const int n_base = node0 + ng * 4;

    float4 bv = *(const float4*)(bias + cg * 4);
    float acc[4][4];
#pragma unroll
    for (int j = 0; j < 4; ++j) {
        acc[j][0] = bv.x; acc[j][1] = bv.y; acc[j][2] = bv.z; acc[j][3] = bv.w;
    }

    const __half* Aptr[3] = {A0, A1, A2};
    for (int term = 0; term < 3; ++term) {
        const __half* A = Aptr[term];
        __syncthreads();
#pragma unroll
        for (int i = 0; i < F8; ++i) {
            int f = tid + i * 256;
            int n = f >> 3;
            int kc = f & 7;
            int gn = node0 + n;
            float4 raw = make_float4(0.f, 0.f, 0.f, 0.f);
            if (gn < nnodes) raw = ((const float4*)(A + (size_t)gn * 64))[kc];
            const __half2* hp = (const __half2*)&raw;
            int col = (((n >> 2) ^ kc) << 2) | (n & 3);   // swizzled column
            float* dst = sA + kc * 8 * 64 + col;
            float2 f0 = __half22float2(hp[0]);
            float2 f1 = __half22float2(hp[1]);
            float2 f2 = __half22float2(hp[2]);
            float2 f3 = __half22float2(hp[3]);
            dst[0 * 64] = f0.x;
            dst[1 * 64] = f0.y;
            dst[2 * 64] = f1.x;
            dst[3 * 64] = f1.y;
            dst[4 * 64] = f2.x;
            dst[5 * 64] = f2.y;
            dst[6 * 64] = f3.x;
            dst[7 * 64] = f3.y;
        }
        __syncthreads();
        const float* Wt = Wp + term * 64 * OUTC;
#pragma unroll 8
        for (int k = 0; k < 64; ++k) {
            float4 a = *(const float4*)(sA + k * 64 + ((ng ^ ((k >> 3) & 7)) << 2));
            float4 b = *(const float4*)(Wt + k * OUTC + cg * 4);
            acc[0][0] += a.x * b.x; acc[0][1] += a.x * b.y; acc[0][2] += a.x * b.z; acc[0][3] += a.x * b.w;
            acc[1][0] += a.y * b.x; acc[1][1] += a.y * b.y; acc[1][2] += a.y * b.z; acc[1][3] += a.y * b.w;
            acc[2][0] += a.z * b.x; acc[2][1] += a.z * b.y; acc[2][2] += a.z * b.z; acc[2][3] += a.z * b.w;
            acc[3][0] += a.w * b.x; acc[3][1] += a.w * b.y; acc[3][2] += a.w * b.z; acc[3][3] += a.w * b.w;
        }
    }
#pragma unroll
    for (int j = 0; j < 4; ++j) {
        int n = n_base + j;
        if (n >= nnodes) continue;
        float4 o = make_float4(fmaxf(acc[j][0], 0.f), fmaxf(acc[j][1], 0.f),
                               fmaxf(acc[j][2], 0.f), fmaxf(acc[j][3], 0.f));
        __half2 tmp[2];
        tmp[0] = __floats2half2_rn(o.x, o.y);
        tmp[1] = __floats2half2_rn(o.z, o.w);
        ((float2*)(outh + (size_t)n * OUTC))[cg] = *(float2*)tmp;
    }
}

// ---------- layer-2 fan-out GEMM: [P0|G1|G2] = Hh @ Wcat (+b2 on P0 cols) ----------
__global__ __launch_bounds__(256) void gemm96(const __half* __restrict__ Hh,
                                              const float* __restrict__ Wcat,
                                              const float* __restrict__ b2,
                                              float* __restrict__ P0,
                                              __half* __restrict__ G1,
                                              __half* __restrict__ G2, int nnodes) {
    constexpr int NODES = 64;
    constexpr int NG = 16;
    __shared__ float sA[64 * 64];

    const int tid = threadIdx.x;
    const int ng = tid % NG;
    const int cg = tid / NG;   // 16 channel-pair groups
    const int c0 = cg * 2;
    const int node0 = blockIdx.x * NODES;
    const int n_base = node0 + ng * 4;

    float2 bp = *(const float2*)(b2 + c0);
    float acc[4][6];
#pragma unroll
    for (int j = 0; j < 4; ++j) {
        acc[j][0] = bp.x; acc[j][1] = bp.y;
        acc[j][2] = 0.f;  acc[j][3] = 0.f;
        acc[j][4] = 0.f;  acc[j][5] = 0.f;
    }

#pragma unroll
    for (int i = 0; i < 2; ++i) {
        int f = tid + i * 256;
        int n = f >> 3;
        int kc = f & 7;
        int gn = node0 + n;
        float4 raw = make_float4(0.f, 0.f, 0.f, 0.f);
        if (gn < nnodes) raw = ((const float4*)(Hh + (size_t)gn * 64))[kc];
        const __half2* hp = (const __half2*)&raw;
        int col = (((n >> 2) ^ kc) << 2) | (n & 3);   // swizzled column
        float* dst = sA + kc * 8 * 64 + col;
        float2 f0 = __half22float2(hp[0]);
        float2 f1 = __half22float2(hp[1]);
        float2 f2 = __half22float2(hp[2]);
        float2 f3 = __half22float2(hp[3]);
        dst[0 * 64] = f0.x;
        dst[1 * 64] = f0.y;
        dst[2 * 64] = f1.x;
        dst[3 * 64] = f1.y;
        dst[4 * 64] = f2.x;
        dst[5 * 64] = f2.y;
        dst[6 * 64] = f3.x;
        dst[7 * 64] = f3.y;
    }
    __syncthreads();
#pragma unroll 8
    for (int k = 0; k < 64; ++k) {
        float4 a = *(const float4*)(sA + k * 64 + ((ng ^ ((k >> 3) & 7)) << 2));
        float2 w0 = *(const float2*)(Wcat + k * 96 + c0);
        float2 w1 = *(const float2*)(Wcat + k * 96 + 32 + c0);
        float2 w2 = *(const float2*)(Wcat + k * 96 + 64 + c0);
        float av[4] = {a.x, a.y, a.z, a.w};
#pragma unroll
        for (int j = 0; j < 4; ++j) {
            acc[j][0] += av[j] * w0.x; acc[j][1] += av[j] * w0.y;
            acc[j][2] += av[j] * w1.x; acc[j][3] += av[j] * w1.y;
            acc[j][4] += av[j] * w2.x; acc[j][5] += av[j] * w2.y;
        }
    }
#pragma unroll
    for (int j = 0; j < 4; ++j) {
        int n = n_base + j;
        if (n >= nnodes) continue;
        *(float2*)(P0 + (size_t)n * 32 + c0) = make_float2(acc[j][0], acc[j][1]);
        *(__half2*)(G1 + (size_t)n * 32 + c0) = __floats2half2_rn(acc[j][2], acc[j][3]);
        *(__half2*)(G2 + (size_t)n * 32 + c0) = __floats2half2_rn(acc[j][4], acc[j][5]);
    }
}

extern "C" void kernel_launch(void* const* d_in, const int* in_sizes, int n_in,
                              void* d_out, int out_size, void* d_ws, size_t ws_size,
                              hipStream_t stream) {
    const float* x  = (const float*)d_in[0];
    const int*   ei = (const int*)d_in[1];
    const float* W1 = (const float*)d_in[2];
    const float* b1 = (const float*)d_in[3];
    const float* W2 = (const float*)d_in[4];
    const float* b2 = (const float*)d_in[5];
    float* out = (float*)d_out;

    const int NN = N_NODES_C;
    const int NE = N_EDGES_C;
    const size_t HFEAT_BYTES = (size_t)NN * 64 * sizeof(__half);
    const size_t H32_BYTES = (size_t)NN * 32 * sizeof(__half);

    char* ws = (char*)d_ws;
    size_t off = 0;
    auto alloc = [&](size_t bytes) -> void* {
        void* p = ws + off;
        off += (bytes + 255) & ~(size_t)255;
        return p;
    };
    int*    cnt         = (int*)alloc((size_t)NN * 4);
    int*    rowptr      = (int*)alloc((size_t)(NN + 1) * 4);
    float*  dis         = (float*)alloc((size_t)NN * 4);
    int*    blocksum    = (int*)alloc(1024);
    int*    bucket_next = (int*)alloc((size_t)NBUK * 4);
    int2*   staged      = (int2*)alloc((size_t)NE * 8);
    int2*   colw        = (int2*)alloc((size_t)NE * 8);
    __half* xh          = (__half*)alloc(HFEAT_BYTES);
    __half* T1h         = (__half*)alloc(HFEAT_BYTES);   // layer1: T1; layer2: G1
    __half* T2h         = (__half*)alloc(HFEAT_BYTES);   // layer1: T2; layer2: G2
    __half* Hh          = (__half*)alloc(HFEAT_BYTES);
    __half* Qh          = (__half*)alloc(H32_BYTES);
    float*  P0          = (float*)alloc((size_t)NN * 32 * 4);
    float*  W1p         = (float*)alloc((size_t)3 * 64 * 64 * 4);
    float*  Wcat        = (float*)alloc((size_t)64 * 96 * 4);

    const int EB = (NE + 255) / 256;
    const int SCAN_BLOCKS = (NN + 1023) / 1024;
    const int PROPB = (NN + 3) / 4;
    const int CONVB = (NN * 64 / 4 + 255) / 256;
    const int STAGEB = (NE + CHUNK - 1) / CHUNK;

    // ---- CSR build (binned) + normalization + weight prep + x->fp16 ----
    hipMemsetAsync(cnt, 0, (size_t)NN * 4, stream);
    hist_kernel<<<EB, 256, 0, stream>>>(ei, cnt, NE);
    scan1<<<SCAN_BLOCKS, 256, 0, stream>>>(cnt, rowptr, blocksum, dis, NN);
    scan2<<<1, 64, 0, stream>>>(blocksum, SCAN_BLOCKS);
    scan3<<<(NN + 256) / 256, 256, 0, stream>>>(rowptr, bucket_next, blocksum, NN, NE);
    bin_stage<<<STAGEB, 256, 0, stream>>>(ei, bucket_next, staged, NE);
    bin_place<<<NBUK, 256, 0, stream>>>(staged, rowptr, dis, colw, NN);
    fold_w<<<(64 * 64 + 255) / 256, 256, 0, stream>>>(W1, W1p, 64 * 64);
    fold_wcat<<<(64 * 96 + 255) / 256, 256, 0, stream>>>(W2, Wcat);
    f2h_kernel<<<CONVB, 256, 0, stream>>>(x, xh, NN * 64 / 4);

    // ---- layer 1: Hh = relu(x@(W0-W2) + T1@W1 + T2@(2W2) + b1), T2 = prop(T1) ----
    prop_gather_h<<<PROPB, 256, 0, stream>>>(xh, rowptr, colw, T1h, NN);
    prop_gather_h<<<PROPB, 256, 0, stream>>>(T1h, rowptr, colw, T2h, NN);
    cheb_gemm_h<<<(NN + 63) / 64, 256, 0, stream>>>(xh, T1h, T2h, W1p, b1, Hh, NN);

    // ---- layer 2 (factored): out = P0 + prop(G1 + prop(G2)) ----
    gemm96<<<(NN + 63) / 64, 256, 0, stream>>>(Hh, Wcat, b2, P0, T1h, T2h, NN);
    prop_gather32<false><<<PROPB, 256, 0, stream>>>(T2h, rowptr, colw, T1h, Qh, NN);
    prop_gather32<true><<<PROPB, 256, 0, stream>>>(Qh, rowptr, colw, P0, out, NN);
}

// Round 10
// 359.995 us; speedup vs baseline: 1.3089x; 1.1956x over previous
//
#include <hip/hip_runtime.h>
#include <hip/hip_fp16.h>

#define N_NODES_C 100000
#define N_EDGES_C 1200000
#define NBUK ((N_NODES_C + 255) >> 8)   // 391 buckets of 256 nodes
#define CHUNK 4096                       // edges per bin_stage block

typedef _Float16 f16x8 __attribute__((ext_vector_type(8)));
typedef float f32x4 __attribute__((ext_vector_type(4)));

// ---------- degree histogram (int) over row ----------
__global__ void hist_kernel(const int* __restrict__ ei, int* __restrict__ cnt, int nedges) {
    int e = blockIdx.x * blockDim.x + threadIdx.x;
    if (e >= nedges) return;
    atomicAdd(cnt + ei[e], 1);
}

// ---------- exclusive scan stage 1 + fused deg_inv_sqrt ----------
__global__ __launch_bounds__(256) void scan1(const int* __restrict__ cnt, int* __restrict__ rowptr,
                                             int* __restrict__ blocksum, float* __restrict__ dis,
                                             int n) {
    __shared__ int s[256];
    int base = blockIdx.x * 1024 + threadIdx.x * 4;
    int v[4];
    int sum = 0;
#pragma unroll
    for (int i = 0; i < 4; ++i) {
        int idx = base + i;
        v[i] = (idx < n) ? cnt[idx] : 0;
        sum += v[i];
        if (idx < n) {
            float d = (float)v[i];
            dis[idx] = (d > 0.f) ? (1.0f / sqrtf(fmaxf(d, 1.f))) : 0.f;
        }
    }
    s[threadIdx.x] = sum;
    __syncthreads();
    for (int off = 1; off < 256; off <<= 1) {
        int val = s[threadIdx.x];
        int add = (threadIdx.x >= off) ? s[threadIdx.x - off] : 0;
        __syncthreads();
        s[threadIdx.x] = val + add;
        __syncthreads();
    }
    int run = (threadIdx.x > 0) ? s[threadIdx.x - 1] : 0;
#pragma unroll
    for (int i = 0; i < 4; ++i) {
        int idx = base + i;
        if (idx < n) rowptr[idx] = run;
        run += v[i];
    }
    if (threadIdx.x == 255) blocksum[blockIdx.x] = s[255];
}

// ---------- scan stage 2: serial scan of block sums (~98) ----------
__global__ void scan2(int* __restrict__ blocksum, int nb) {
    if (threadIdx.x == 0 && blockIdx.x == 0) {
        int acc = 0;
        for (int i = 0; i < nb; ++i) {
            int t = blocksum[i];
            blocksum[i] = acc;
            acc += t;
        }
    }
}

// ---------- scan stage 3: finalize rowptr, init per-bucket alloc cursors ----------
__global__ void scan3(int* __restrict__ rowptr, int* __restrict__ bucket_next,
                      const int* __restrict__ blocksum, int n, int nedges) {
    int i = blockIdx.x * blockDim.x + threadIdx.x;
    if (i < n) {
        int v = rowptr[i] + blocksum[i >> 10];
        rowptr[i] = v;
        if ((i & 255) == 0) bucket_next[i >> 8] = v;   // bucket base = rowptr[b*256]
    }
    if (i == n) rowptr[n] = nedges;
}

// ---------- phase B: LDS-binned staging of (r,c) grouped by 256-node bucket ----------
__global__ __launch_bounds__(256) void bin_stage(const int* __restrict__ ei,
                                                 int* __restrict__ bucket_next,
                                                 int2* __restrict__ staged, int nedges) {
    __shared__ int cnt[NBUK];
    __shared__ int ofs[NBUK];
    __shared__ int run[NBUK];
    __shared__ int gbase[NBUK];
    __shared__ int ssum[256];
    __shared__ int2 sedge[CHUNK];
    const int tid = threadIdx.x;
    const int base = blockIdx.x * CHUNK;
    const int nloc = min(CHUNK, nedges - base);

    for (int i = tid; i < NBUK; i += 256) { cnt[i] = 0; run[i] = 0; }
    __syncthreads();

    int r[16], c[16];
#pragma unroll
    for (int k = 0; k < 16; ++k) {
        int loc = tid + k * 256;
        bool ok = loc < nloc;
        int idx = base + loc;
        r[k] = ok ? ei[idx] : -1;
        c[k] = ok ? ei[nedges + idx] : 0;
        if (ok) atomicAdd(&cnt[r[k] >> 8], 1);
    }
    __syncthreads();

    // exclusive scan of cnt[NBUK] -> ofs
    int a0 = (2 * tid < NBUK) ? cnt[2 * tid] : 0;
    int a1 = (2 * tid + 1 < NBUK) ? cnt[2 * tid + 1] : 0;
    ssum[tid] = a0 + a1;
    __syncthreads();
    for (int off = 1; off < 256; off <<= 1) {
        int v = ssum[tid];
        int add = (tid >= off) ? ssum[tid - off] : 0;
        __syncthreads();
        ssum[tid] = v + add;
        __syncthreads();
    }
    int excl = (tid > 0) ? ssum[tid - 1] : 0;
    if (2 * tid < NBUK) ofs[2 * tid] = excl;
    if (2 * tid + 1 < NBUK) ofs[2 * tid + 1] = excl + a0;
    __syncthreads();

    // place edges into LDS grouped by bucket
#pragma unroll
    for (int k = 0; k < 16; ++k) {
        if (r[k] >= 0) {
            int b = r[k] >> 8;
            int p = atomicAdd(&run[b], 1);
            sedge[ofs[b] + p] = make_int2(r[k], c[k]);
        }
    }
    __syncthreads();

    // allocate global runs (one atomic per non-empty bucket)
    for (int b = tid; b < NBUK; b += 256) {
        int n = cnt[b];
        gbase[b] = n ? atomicAdd(&bucket_next[b], n) : 0;
    }
    __syncthreads();

    // coalesced copy-out: consecutive i are bucket-grouped runs
    for (int i = tid; i < nloc; i += 256) {
        int2 e = sedge[i];
        int b = e.x >> 8;
        staged[gbase[b] + (i - ofs[b])] = e;
    }
}

// ---------- phase C: per-bucket exact CSR placement + norm weight ----------
__global__ __launch_bounds__(256) void bin_place(const int2* __restrict__ staged,
                                                 const int* __restrict__ rowptr,
                                                 const float* __restrict__ dis,
                                                 int2* __restrict__ colw, int nnodes) {
    __shared__ int rp[256];
    __shared__ int nx[256];
    __shared__ float dl[256];
    const int b = blockIdx.x;
    const int n0 = b << 8;
    const int nend = min(n0 + 256, nnodes);
    const int nloc = nend - n0;
    const int tid = threadIdx.x;
    if (tid < nloc) {
        rp[tid] = rowptr[n0 + tid];
        dl[tid] = dis[n0 + tid];
    }
    nx[tid] = 0;
    __syncthreads();
    const int ebase = rowptr[n0];
    const int ecount = rowptr[nend] - ebase;
    for (int i = tid; i < ecount; i += 256) {
        int2 e = staged[ebase + i];
        int rrel = e.x - n0;
        int p = atomicAdd(&nx[rrel], 1);
        float w = -dl[rrel] * dis[e.y];
        colw[rp[rrel] + p] = make_int2(e.y, __float_as_int(w));
    }
}

// ---------- pack layer-1 folded weights into MFMA B-fragment layout (fp16) ----------
// Wf[((ct*6 + kh)*64 + lane)*8 + j] = Wfold[term=kh/2][k=(kh&1)*32+(lane>>4)*8+j][c=ct*16+(lane&15)]
// Wfold: term0 = W0-W2, term1 = W1, term2 = 2*W2.  W1 input layout [3][64][64].
__global__ void fold_w1f(const float* __restrict__ W, __half* __restrict__ Wf) {
    int i = blockIdx.x * blockDim.x + threadIdx.x;
    if (i >= 4 * 6 * 64 * 8) return;
    int j = i & 7;
    int lane = (i >> 3) & 63;
    int rest = i >> 9;
    int kh = rest % 6;
    int ct = rest / 6;
    int term = kh >> 1;
    int k = ((kh & 1) << 5) | ((lane >> 4) << 3) | j;
    int c = (ct << 4) | (lane & 15);
    float w0 = W[k * 64 + c];
    float w1 = W[4096 + k * 64 + c];
    float w2 = W[2 * 4096 + k * 64 + c];
    float v = (term == 0) ? (w0 - w2) : ((term == 1) ? w1 : 2.0f * w2);
    Wf[i] = __float2half(v);
}

// ---------- pack layer-2 concat weights into MFMA B-fragment layout (fp16) ----------
// cols 0..95: seg0 = W0-W2, seg1 = W1, seg2 = 2*W2.  W2 input layout [3][64][32].
__global__ void fold_w2f(const float* __restrict__ W, __half* __restrict__ Wf) {
    int i = blockIdx.x * blockDim.x + threadIdx.x;
    if (i >= 6 * 2 * 64 * 8) return;
    int j = i & 7;
    int lane = (i >> 3) & 63;
    int rest = i >> 9;
    int kh = rest & 1;
    int ct = rest >> 1;
    int k = (kh << 5) | ((lane >> 4) << 3) | j;
    int cg = ct * 16 + (lane & 15);
    int seg = cg >> 5;
    int c = cg & 31;
    float w0 = W[k * 32 + c];
    float w1 = W[2048 + k * 32 + c];
    float w2 = W[2 * 2048 + k * 32 + c];
    float v = (seg == 0) ? (w0 - w2) : ((seg == 1) ? w1 : 2.0f * w2);
    Wf[i] = __float2half(v);
}

// ---------- fp32 -> fp16 feature conversion (4 elems/thread) ----------
__global__ void f2h_kernel(const float* __restrict__ in, __half* __restrict__ out, int n4) {
    int i = blockIdx.x * blockDim.x + threadIdx.x;
    if (i >= n4) return;
    float4 v = ((const float4*)in)[i];
    __half2 tmp[2];
    tmp[0] = __floats2half2_rn(v.x, v.y);
    tmp[1] = __floats2half2_rn(v.z, v.w);
    ((float2*)out)[i] = *(float2*)tmp;
}

// ---------- prop64: 8 lanes/edge, chunk loop unrolled x2 (2 gathers in flight) ----------
__global__ __launch_bounds__(256) void prop_gather_h(const __half* __restrict__ t,
                                                     const int* __restrict__ rowptr,
                                                     const int2* __restrict__ colw,
                                                     __half* __restrict__ out, int nnodes) {
    int node = blockIdx.x * 4 + (threadIdx.x >> 6);
    if (node >= nnodes) return;
    int lane = threadIdx.x & 63;
    int g = lane >> 3;    // edge group 0..7
    int gl = lane & 7;    // channel octet
    int s = rowptr[node];
    int e = rowptr[node + 1];
    float acc[8] = {0.f, 0.f, 0.f, 0.f, 0.f, 0.f, 0.f, 0.f};
    for (int base = s; base < e; base += 64) {
        int m = e - base;
        if (m > 64) m = 64;
        int2 cw = (lane < m) ? colw[base + lane] : make_int2(0, 0);
        int iters = (m + 7) >> 3;
        for (int it = 0; it < iters; it += 2) {
            int j0 = (it << 3) | g;
            int j1 = j0 + 8;                        // sentinel (0,0) if >= m: w=0, row-0 L1-hot
            int c0 = __shfl(cw.x, j0);
            float w0 = __int_as_float(__shfl(cw.y, j0));
            int c1 = __shfl(cw.x, j1);
            float w1 = __int_as_float(__shfl(cw.y, j1));
            float4 raw0 = ((const float4*)(t + (size_t)c0 * 64))[gl];
            float4 raw1 = ((const float4*)(t + (size_t)c1 * 64))[gl];
            const __half2* h0 = (const __half2*)&raw0;
            const __half2* h1 = (const __half2*)&raw1;
#pragma unroll
            for (int q = 0; q < 4; ++q) {
                float2 f0 = __half22float2(h0[q]);
                float2 f1 = __half22float2(h1[q]);
                acc[2 * q + 0] += w0 * f0.x + w1 * f1.x;
                acc[2 * q + 1] += w0 * f0.y + w1 * f1.y;
            }
        }
    }
#pragma unroll
    for (int i = 0; i < 8; ++i) {
        acc[i] += __shfl_xor(acc[i], 8);
        acc[i] += __shfl_xor(acc[i], 16);
        acc[i] += __shfl_xor(acc[i], 32);
    }
    if (g == 0) {
        __half2 tmp[4];
        tmp[0] = __floats2half2_rn(acc[0], acc[1]);
        tmp[1] = __floats2half2_rn(acc[2], acc[3]);
        tmp[2] = __floats2half2_rn(acc[4], acc[5]);
        tmp[3] = __floats2half2_rn(acc[6], acc[7]);
        ((float4*)(out + (size_t)node * 64))[gl] = *(float4*)tmp;
    }
}

// ---------- prop32: 4 lanes/edge, unrolled x2; fused add-input; fp16/fp32 out ----------
template <bool F32OUT>
__global__ __launch_bounds__(256) void prop_gather32(const __half* __restrict__ t,
                                                     const int* __restrict__ rowptr,
                                                     const int2* __restrict__ colw,
                                                     const void* __restrict__ addin,
                                                     void* __restrict__ outv, int nnodes) {
    int node = blockIdx.x * 4 + (threadIdx.x >> 6);
    if (node >= nnodes) return;
    int lane = threadIdx.x & 63;
    int g = lane >> 2;    // edge group 0..15
    int gl = lane & 3;    // channel octet
    int s = rowptr[node];
    int e = rowptr[node + 1];
    float acc[8] = {0.f, 0.f, 0.f, 0.f, 0.f, 0.f, 0.f, 0.f};
    for (int base = s; base < e; base += 64) {
        int m = e - base;
        if (m > 64) m = 64;
        int2 cw = (lane < m) ? colw[base + lane] : make_int2(0, 0);
        int iters = (m + 15) >> 4;
        for (int it = 0; it < iters; it += 2) {
            int j0 = (it << 4) | g;
            int j1 = j0 + 16;                       // sentinel-safe
            int c0 = __shfl(cw.x, j0);
            float w0 = __int_as_float(__shfl(cw.y, j0));
            int c1 = __shfl(cw.x, j1);
            float w1 = __int_as_float(__shfl(cw.y, j1));
            float4 raw0 = ((const float4*)(t + (size_t)c0 * 32))[gl];
            float4 raw1 = ((const float4*)(t + (size_t)c1 * 32))[gl];
            const __half2* h0 = (const __half2*)&raw0;
            const __half2* h1 = (const __half2*)&raw1;
#pragma unroll
            for (int q = 0; q < 4; ++q) {
                float2 f0 = __half22float2(h0[q]);
                float2 f1 = __half22float2(h1[q]);
                acc[2 * q + 0] += w0 * f0.x + w1 * f1.x;
                acc[2 * q + 1] += w0 * f0.y + w1 * f1.y;
            }
        }
    }
#pragma unroll
    for (int i = 0; i < 8; ++i) {
        acc[i] += __shfl_xor(acc[i], 4);
        acc[i] += __shfl_xor(acc[i], 8);
        acc[i] += __shfl_xor(acc[i], 16);
        acc[i] += __shfl_xor(acc[i], 32);
    }
    if (g == 0) {
        if (F32OUT) {
            const float* add = (const float*)addin;
            float* out = (float*)outv;
            float4 a0 = ((const float4*)(add + (size_t)node * 32))[gl * 2 + 0];
            float4 a1 = ((const float4*)(add + (size_t)node * 32))[gl * 2 + 1];
            a0.x += acc[0]; a0.y += acc[1]; a0.z += acc[2]; a0.w += acc[3];
            a1.x += acc[4]; a1.y += acc[5]; a1.z += acc[6]; a1.w += acc[7];
            ((float4*)(out + (size_t)node * 32))[gl * 2 + 0] = a0;
            ((float4*)(out + (size_t)node * 32))[gl * 2 + 1] = a1;
        } else {
            const __half* add = (const __half*)addin;
            __half* out = (__half*)outv;
            float4 raw = ((const float4*)(add + (size_t)node * 32))[gl];
            const __half2* hp = (const __half2*)&raw;
            float2 f0 = __half22float2(hp[0]);
            float2 f1 = __half22float2(hp[1]);
            float2 f2 = __half22float2(hp[2]);
            float2 f3 = __half22float2(hp[3]);
            __half2 tmp[4];
            tmp[0] = __floats2half2_rn(acc[0] + f0.x, acc[1] + f0.y);
            tmp[1] = __floats2half2_rn(acc[2] + f1.x, acc[3] + f1.y);
            tmp[2] = __floats2half2_rn(acc[4] + f2.x, acc[5] + f2.y);
            tmp[3] = __floats2half2_rn(acc[6] + f3.x, acc[7] + f3.y);
            ((float4*)(out + (size_t)node * 32))[gl] = *(float4*)tmp;
        }
    }
}

// ---------- layer-1 MFMA GEMM: Hh = relu([xh|T1h|T2h] @ W1f + b1), fp16 out ----------
// One wave = 16 nodes. A-frag (m=lane&15, k=quad*8+j) is 16 contiguous bytes of a
// feature row -> direct global load, no LDS. B-frags pre-packed by fold_w1f.
// C/D: row = quad*4+r, col = lane&15 [measured: learn_hip m89/m91].
__global__ __launch_bounds__(256) void gemm_l1_mfma(const __half* __restrict__ A0,
                                                    const __half* __restrict__ A1,
                                                    const __half* __restrict__ A2,
                                                    const __half* __restrict__ Wf,
                                                    const float* __restrict__ b1,
                                                    __half* __restrict__ Hh, int nnodes) {
    const int wave = threadIdx.x >> 6;
    const int lane = threadIdx.x & 63;
    const int node0 = blockIdx.x * 64 + wave * 16;
    const int m = lane & 15;
    const int quad = lane >> 4;
    int arow = node0 + m;
    if (arow >= nnodes) arow = nnodes - 1;   // clamp: garbage rows never stored
    const __half* Ap[3] = {A0, A1, A2};
    f16x8 a[6];
#pragma unroll
    for (int kh = 0; kh < 6; ++kh) {
        const __half* A = Ap[kh >> 1];
        a[kh] = *(const f16x8*)(A + (size_t)arow * 64 + ((kh & 1) << 5) + (quad << 3));
    }
#pragma unroll
    for (int ct = 0; ct < 4; ++ct) {
        f32x4 acc = {0.f, 0.f, 0.f, 0.f};
#pragma unroll
        for (int kh = 0; kh < 6; ++kh) {
            f16x8 b = *(const f16x8*)(Wf + ((size_t)(ct * 6 + kh) * 64 + lane) * 8);
            acc = __builtin_amdgcn_mfma_f32_16x16x32_f16(a[kh], b, acc, 0, 0, 0);
        }
        int col = (ct << 4) | m;
        float bias = b1[col];
#pragma unroll
        for (int r = 0; r < 4; ++r) {
            int n = node0 + (quad << 2) + r;
            if (n < nnodes) Hh[(size_t)n * 64 + col] = __float2half(fmaxf(acc[r] + bias, 0.f));
        }
    }
}

// ---------- layer-2 MFMA GEMM: [P0|G1|G2] = Hh @ W2f (+b2 on P0) ----------
// seg = ct>>1 is wave-uniform (each 16-col tile lies inside one 32-col segment).
__global__ __launch_bounds__(256) void gemm_l2_mfma(const __half* __restrict__ Hh,
                                                    const __half* __restrict__ Wf,
                                                    const float* __restrict__ b2,
                                                    float* __restrict__ P0,
                                                    __half* __restrict__ G1,
                                                    __half* __restrict__ G2, int nnodes) {
    const int wave = threadIdx.x >> 6;
    const int lane = threadIdx.x & 63;
    const int node0 = blockIdx.x * 64 + wave * 16;
    const int m = lane & 15;
    const int quad = lane >> 4;
    int arow = node0 + m;
    if (arow >= nnodes) arow = nnodes - 1;
    f16x8 a0 = *(const f16x8*)(Hh + (size_t)arow * 64 + (quad << 3));
    f16x8 a1 = *(const f16x8*)(Hh + (size_t)arow * 64 + 32 + (quad << 3));
#pragma unroll
    for (int ct = 0; ct < 6; ++ct) {
        f32x4 acc = {0.f, 0.f, 0.f, 0.f};
        f16x8 b0 = *(const f16x8*)(Wf + ((size_t)(ct * 2 + 0) * 64 + lane) * 8);
        f16x8 b1v = *(const f16x8*)(Wf + ((size_t)(ct * 2 + 1) * 64 + lane) * 8);
        acc = __builtin_amdgcn_mfma_f32_16x16x32_f16(a0, b0, acc, 0, 0, 0);
        acc = __builtin_amdgcn_mfma_f32_16x16x32_f16(a1, b1v, acc, 0, 0, 0);
        int seg = ct >> 1;                      // wave-uniform
        int c = ((ct & 1) << 4) | m;            // col within segment
#pragma unroll
        for (int r = 0; r < 4; ++r) {
            int n = node0 + (quad << 2) + r;
            if (n >= nnodes) continue;
            float v = acc[r];
            if (seg == 0)      P0[(size_t)n * 32 + c] = v + b2[c];
            else if (seg == 1) G1[(size_t)n * 32 + c] = __float2half(v);
            else               G2[(size_t)n * 32 + c] = __float2half(v);
        }
    }
}

extern "C" void kernel_launch(void* const* d_in, const int* in_sizes, int n_in,
                              void* d_out, int out_size, void* d_ws, size_t ws_size,
                              hipStream_t stream) {
    const float* x  = (const float*)d_in[0];
    const int*   ei = (const int*)d_in[1];
    const float* W1 = (const float*)d_in[2];
    const float* b1 = (const float*)d_in[3];
    const float* W2 = (const float*)d_in[4];
    const float* b2 = (const float*)d_in[5];
    float* out = (float*)d_out;

    const int NN = N_NODES_C;
    const int NE = N_EDGES_C;
    const size_t HFEAT_BYTES = (size_t)NN * 64 * sizeof(__half);
    const size_t H32_BYTES = (size_t)NN * 32 * sizeof(__half);

    char* ws = (char*)d_ws;
    size_t off = 0;
    auto alloc = [&](size_t bytes) -> void* {
        void* p = ws + off;
        off += (bytes + 255) & ~(size_t)255;
        return p;
    };
    int*    cnt         = (int*)alloc((size_t)NN * 4);
    int*    rowptr      = (int*)alloc((size_t)(NN + 1) * 4);
    float*  dis         = (float*)alloc((size_t)NN * 4);
    int*    blocksum    = (int*)alloc(1024);
    int*    bucket_next = (int*)alloc((size_t)NBUK * 4);
    int2*   staged      = (int2*)alloc((size_t)NE * 8);
    int2*   colw        = (int2*)alloc((size_t)NE * 8);
    __half* xh          = (__half*)alloc(HFEAT_BYTES);
    __half* T1h         = (__half*)alloc(HFEAT_BYTES);   // layer1: T1; layer2: G1
    __half* T2h         = (__half*)alloc(HFEAT_BYTES);   // layer1: T2; layer2: G2
    __half* Hh          = (__half*)alloc(HFEAT_BYTES);
    __half* Qh          = (__half*)alloc(H32_BYTES);
    float*  P0          = (float*)alloc((size_t)NN * 32 * 4);
    __half* W1f         = (__half*)alloc((size_t)4 * 6 * 64 * 8 * 2);   // 24 KB
    __half* W2f         = (__half*)alloc((size_t)6 * 2 * 64 * 8 * 2);   // 12 KB

    const int EB = (NE + 255) / 256;
    const int SCAN_BLOCKS = (NN + 1023) / 1024;
    const int PROPB = (NN + 3) / 4;
    const int CONVB = (NN * 64 / 4 + 255) / 256;
    const int STAGEB = (NE + CHUNK - 1) / CHUNK;
    const int GEMMB = (NN + 63) / 64;

    // ---- CSR build (binned) + normalization + weight packing + x->fp16 ----
    hipMemsetAsync(cnt, 0, (size_t)NN * 4, stream);
    hist_kernel<<<EB, 256, 0, stream>>>(ei, cnt, NE);
    scan1<<<SCAN_BLOCKS, 256, 0, stream>>>(cnt, rowptr, blocksum, dis, NN);
    scan2<<<1, 64, 0, stream>>>(blocksum, SCAN_BLOCKS);
    scan3<<<(NN + 256) / 256, 256, 0, stream>>>(rowptr, bucket_next, blocksum, NN, NE);
    bin_stage<<<STAGEB, 256, 0, stream>>>(ei, bucket_next, staged, NE);
    bin_place<<<NBUK, 256, 0, stream>>>(staged, rowptr, dis, colw, NN);
    fold_w1f<<<(12288 + 255) / 256, 256, 0, stream>>>(W1, W1f);
    fold_w2f<<<(6144 + 255) / 256, 256, 0, stream>>>(W2, W2f);
    f2h_kernel<<<CONVB, 256, 0, stream>>>(x, xh, NN * 64 / 4);

    // ---- layer 1: Hh = relu(x@(W0-W2) + T1@W1 + T2@(2W2) + b1), T2 = prop(T1) ----
    prop_gather_h<<<PROPB, 256, 0, stream>>>(xh, rowptr, colw, T1h, NN);
    prop_gather_h<<<PROPB, 256, 0, stream>>>(T1h, rowptr, colw, T2h, NN);
    gemm_l1_mfma<<<GEMMB, 256, 0, stream>>>(xh, T1h, T2h, W1f, b1, Hh, NN);

    // ---- layer 2 (factored): out = P0 + prop(G1 + prop(G2)) ----
    gemm_l2_mfma<<<GEMMB, 256, 0, stream>>>(Hh, W2f, b2, P0, T1h, T2h, NN);
    prop_gather32<false><<<PROPB, 256, 0, stream>>>(T2h, rowptr, colw, T1h, Qh, NN);
    prop_gather32<true><<<PROPB, 256, 0, stream>>>(Qh, rowptr, colw, P0, out, NN);
}

// Round 11
// 334.525 us; speedup vs baseline: 1.4085x; 1.0761x over previous
//
#include <hip/hip_runtime.h>
#include <hip/hip_fp16.h>

#define N_NODES_C 100000
#define N_EDGES_C 1200000
#define NBUK ((N_NODES_C + 255) >> 8)   // 391 buckets of 256 nodes
#define CHUNK 4096                       // edges per binning block

typedef _Float16 f16x8 __attribute__((ext_vector_type(8)));
typedef float f32x4 __attribute__((ext_vector_type(4)));

// ---------- bucket-level histogram: LDS aggregate, ~115k global atomics ----------
__global__ __launch_bounds__(256) void bucket_hist(const int* __restrict__ ei,
                                                   int* __restrict__ bucket_cnt, int nedges) {
    __shared__ int cnt[NBUK];
    const int tid = threadIdx.x;
    const int base = blockIdx.x * CHUNK;
    const int nloc = min(CHUNK, nedges - base);
    for (int i = tid; i < NBUK; i += 256) cnt[i] = 0;
    __syncthreads();
    for (int i = tid; i < nloc; i += 256) atomicAdd(&cnt[ei[base + i] >> 8], 1);
    __syncthreads();
    for (int b = tid; b < NBUK; b += 256) {
        int n = cnt[b];
        if (n) atomicAdd(&bucket_cnt[b], n);
    }
}

// ---------- scan 391 bucket counts -> bucket_base / bucket_next ----------
__global__ void bucket_scan(const int* __restrict__ bucket_cnt, int* __restrict__ bucket_base,
                            int* __restrict__ bucket_next, int nb) {
    if (threadIdx.x == 0 && blockIdx.x == 0) {
        int acc = 0;
        for (int i = 0; i < nb; ++i) {
            bucket_base[i] = acc;
            bucket_next[i] = acc;
            acc += bucket_cnt[i];
        }
        bucket_base[nb] = acc;
    }
}

// ---------- phase B: LDS-binned staging of (r,c) grouped by 256-node bucket ----------
__global__ __launch_bounds__(256) void bin_stage(const int* __restrict__ ei,
                                                 int* __restrict__ bucket_next,
                                                 int2* __restrict__ staged, int nedges) {
    __shared__ int cnt[NBUK];
    __shared__ int ofs[NBUK];
    __shared__ int run[NBUK];
    __shared__ int gbase[NBUK];
    __shared__ int ssum[256];
    __shared__ int2 sedge[CHUNK];
    const int tid = threadIdx.x;
    const int base = blockIdx.x * CHUNK;
    const int nloc = min(CHUNK, nedges - base);

    for (int i = tid; i < NBUK; i += 256) { cnt[i] = 0; run[i] = 0; }
    __syncthreads();

    int r[16], c[16];
#pragma unroll
    for (int k = 0; k < 16; ++k) {
        int loc = tid + k * 256;
        bool ok = loc < nloc;
        int idx = base + loc;
        r[k] = ok ? ei[idx] : -1;
        c[k] = ok ? ei[nedges + idx] : 0;
        if (ok) atomicAdd(&cnt[r[k] >> 8], 1);
    }
    __syncthreads();

    // exclusive scan of cnt[NBUK] -> ofs
    int a0 = (2 * tid < NBUK) ? cnt[2 * tid] : 0;
    int a1 = (2 * tid + 1 < NBUK) ? cnt[2 * tid + 1] : 0;
    ssum[tid] = a0 + a1;
    __syncthreads();
    for (int off = 1; off < 256; off <<= 1) {
        int v = ssum[tid];
        int add = (tid >= off) ? ssum[tid - off] : 0;
        __syncthreads();
        ssum[tid] = v + add;
        __syncthreads();
    }
    int excl = (tid > 0) ? ssum[tid - 1] : 0;
    if (2 * tid < NBUK) ofs[2 * tid] = excl;
    if (2 * tid + 1 < NBUK) ofs[2 * tid + 1] = excl + a0;
    __syncthreads();

    // place edges into LDS grouped by bucket
#pragma unroll
    for (int k = 0; k < 16; ++k) {
        if (r[k] >= 0) {
            int b = r[k] >> 8;
            int p = atomicAdd(&run[b], 1);
            sedge[ofs[b] + p] = make_int2(r[k], c[k]);
        }
    }
    __syncthreads();

    // allocate global runs (one atomic per non-empty bucket)
    for (int b = tid; b < NBUK; b += 256) {
        int n = cnt[b];
        gbase[b] = n ? atomicAdd(&bucket_next[b], n) : 0;
    }
    __syncthreads();

    // coalesced copy-out: consecutive i are bucket-grouped runs
    for (int i = tid; i < nloc; i += 256) {
        int2 e = sedge[i];
        int b = e.x >> 8;
        staged[gbase[b] + (i - ofs[b])] = e;
    }
}

// ---------- phase C1: per-bucket degree count -> rowptr slice + deg_inv_sqrt ----------
__global__ __launch_bounds__(256) void bin_count(const int2* __restrict__ staged,
                                                 const int* __restrict__ bucket_base,
                                                 int* __restrict__ rowptr, float* __restrict__ dis,
                                                 int nnodes, int nedges) {
    __shared__ int deg[256];
    __shared__ int ssum[256];
    const int b = blockIdx.x;
    const int n0 = b << 8;
    const int nend = min(n0 + 256, nnodes);
    const int nloc = nend - n0;
    const int tid = threadIdx.x;
    deg[tid] = 0;
    __syncthreads();
    const int ebase = bucket_base[b];
    const int ecount = bucket_base[b + 1] - ebase;
    for (int i = tid; i < ecount; i += 256) {
        atomicAdd(&deg[staged[ebase + i].x - n0], 1);
    }
    __syncthreads();
    int d = deg[tid];
    if (tid < nloc) {
        float df = (float)d;
        dis[n0 + tid] = (d > 0) ? (1.0f / sqrtf(fmaxf(df, 1.f))) : 0.f;
    }
    ssum[tid] = d;
    __syncthreads();
    for (int off = 1; off < 256; off <<= 1) {
        int v = ssum[tid];
        int add = (tid >= off) ? ssum[tid - off] : 0;
        __syncthreads();
        ssum[tid] = v + add;
        __syncthreads();
    }
    int excl = (tid > 0) ? ssum[tid - 1] : 0;
    if (tid < nloc) rowptr[n0 + tid] = ebase + excl;
    if (b == NBUK - 1 && tid == 0) rowptr[nnodes] = nedges;
}

// ---------- phase C2: per-bucket exact CSR placement + norm weight ----------
__global__ __launch_bounds__(256) void bin_place(const int2* __restrict__ staged,
                                                 const int* __restrict__ rowptr,
                                                 const float* __restrict__ dis,
                                                 int2* __restrict__ colw, int nnodes) {
    __shared__ int rp[256];
    __shared__ int nx[256];
    __shared__ float dl[256];
    const int b = blockIdx.x;
    const int n0 = b << 8;
    const int nend = min(n0 + 256, nnodes);
    const int nloc = nend - n0;
    const int tid = threadIdx.x;
    if (tid < nloc) {
        rp[tid] = rowptr[n0 + tid];
        dl[tid] = dis[n0 + tid];
    }
    nx[tid] = 0;
    __syncthreads();
    const int ebase = rowptr[n0];
    const int ecount = rowptr[nend] - ebase;
    for (int i = tid; i < ecount; i += 256) {
        int2 e = staged[ebase + i];
        int rrel = e.x - n0;
        int p = atomicAdd(&nx[rrel], 1);
        float w = -dl[rrel] * dis[e.y];
        colw[rp[rrel] + p] = make_int2(e.y, __float_as_int(w));
    }
}

// ---------- pack layer-1 folded weights into MFMA B-fragment layout (fp16) ----------
__global__ void fold_w1f(const float* __restrict__ W, __half* __restrict__ Wf) {
    int i = blockIdx.x * blockDim.x + threadIdx.x;
    if (i >= 4 * 6 * 64 * 8) return;
    int j = i & 7;
    int lane = (i >> 3) & 63;
    int rest = i >> 9;
    int kh = rest % 6;
    int ct = rest / 6;
    int term = kh >> 1;
    int k = ((kh & 1) << 5) | ((lane >> 4) << 3) | j;
    int c = (ct << 4) | (lane & 15);
    float w0 = W[k * 64 + c];
    float w1 = W[4096 + k * 64 + c];
    float w2 = W[2 * 4096 + k * 64 + c];
    float v = (term == 0) ? (w0 - w2) : ((term == 1) ? w1 : 2.0f * w2);
    Wf[i] = __float2half(v);
}

// ---------- pack layer-2 concat weights into MFMA B-fragment layout (fp16) ----------
__global__ void fold_w2f(const float* __restrict__ W, __half* __restrict__ Wf) {
    int i = blockIdx.x * blockDim.x + threadIdx.x;
    if (i >= 6 * 2 * 64 * 8) return;
    int j = i & 7;
    int lane = (i >> 3) & 63;
    int rest = i >> 9;
    int kh = rest & 1;
    int ct = rest >> 1;
    int k = (kh << 5) | ((lane >> 4) << 3) | j;
    int cg = ct * 16 + (lane & 15);
    int seg = cg >> 5;
    int c = cg & 31;
    float w0 = W[k * 32 + c];
    float w1 = W[2048 + k * 32 + c];
    float w2 = W[2 * 2048 + k * 32 + c];
    float v = (seg == 0) ? (w0 - w2) : ((seg == 1) ? w1 : 2.0f * w2);
    Wf[i] = __float2half(v);
}

// ---------- fp32 -> fp16 feature conversion (4 elems/thread) ----------
__global__ void f2h_kernel(const float* __restrict__ in, __half* __restrict__ out, int n4) {
    int i = blockIdx.x * blockDim.x + threadIdx.x;
    if (i >= n4) return;
    float4 v = ((const float4*)in)[i];
    __half2 tmp[2];
    tmp[0] = __floats2half2_rn(v.x, v.y);
    tmp[1] = __floats2half2_rn(v.z, v.w);
    ((float2*)out)[i] = *(float2*)tmp;
}

// ---------- prop64: 8 lanes/edge, chunk loop unrolled x2 (2 gathers in flight) ----------
__global__ __launch_bounds__(256) void prop_gather_h(const __half* __restrict__ t,
                                                     const int* __restrict__ rowptr,
                                                     const int2* __restrict__ colw,
                                                     __half* __restrict__ out, int nnodes) {
    int node = blockIdx.x * 4 + (threadIdx.x >> 6);
    if (node >= nnodes) return;
    int lane = threadIdx.x & 63;
    int g = lane >> 3;    // edge group 0..7
    int gl = lane & 7;    // channel octet
    int s = rowptr[node];
    int e = rowptr[node + 1];
    float acc[8] = {0.f, 0.f, 0.f, 0.f, 0.f, 0.f, 0.f, 0.f};
    for (int base = s; base < e; base += 64) {
        int m = e - base;
        if (m > 64) m = 64;
        int2 cw = (lane < m) ? colw[base + lane] : make_int2(0, 0);
        int iters = (m + 7) >> 3;
        for (int it = 0; it < iters; it += 2) {
            int j0 = (it << 3) | g;
            int j1 = j0 + 8;                        // sentinel (0,0) if >= m: w=0, row-0 L1-hot
            int c0 = __shfl(cw.x, j0);
            float w0 = __int_as_float(__shfl(cw.y, j0));
            int c1 = __shfl(cw.x, j1);
            float w1 = __int_as_float(__shfl(cw.y, j1));
            float4 raw0 = ((const float4*)(t + (size_t)c0 * 64))[gl];
            float4 raw1 = ((const float4*)(t + (size_t)c1 * 64))[gl];
            const __half2* h0 = (const __half2*)&raw0;
            const __half2* h1 = (const __half2*)&raw1;
#pragma unroll
            for (int q = 0; q < 4; ++q) {
                float2 f0 = __half22float2(h0[q]);
                float2 f1 = __half22float2(h1[q]);
                acc[2 * q + 0] += w0 * f0.x + w1 * f1.x;
                acc[2 * q + 1] += w0 * f0.y + w1 * f1.y;
            }
        }
    }
#pragma unroll
    for (int i = 0; i < 8; ++i) {
        acc[i] += __shfl_xor(acc[i], 8);
        acc[i] += __shfl_xor(acc[i], 16);
        acc[i] += __shfl_xor(acc[i], 32);
    }
    if (g == 0) {
        __half2 tmp[4];
        tmp[0] = __floats2half2_rn(acc[0], acc[1]);
        tmp[1] = __floats2half2_rn(acc[2], acc[3]);
        tmp[2] = __floats2half2_rn(acc[4], acc[5]);
        tmp[3] = __floats2half2_rn(acc[6], acc[7]);
        ((float4*)(out + (size_t)node * 64))[gl] = *(float4*)tmp;
    }
}

// ---------- prop32: 4 lanes/edge, unrolled x2; fused add-input; fp16/fp32 out ----------
template <bool F32OUT>
__global__ __launch_bounds__(256) void prop_gather32(const __half* __restrict__ t,
                                                     const int* __restrict__ rowptr,
                                                     const int2* __restrict__ colw,
                                                     const void* __restrict__ addin,
                                                     void* __restrict__ outv, int nnodes) {
    int node = blockIdx.x * 4 + (threadIdx.x >> 6);
    if (node >= nnodes) return;
    int lane = threadIdx.x & 63;
    int g = lane >> 2;    // edge group 0..15
    int gl = lane & 3;    // channel octet
    int s = rowptr[node];
    int e = rowptr[node + 1];
    float acc[8] = {0.f, 0.f, 0.f, 0.f, 0.f, 0.f, 0.f, 0.f};
    for (int base = s; base < e; base += 64) {
        int m = e - base;
        if (m > 64) m = 64;
        int2 cw = (lane < m) ? colw[base + lane] : make_int2(0, 0);
        int iters = (m + 15) >> 4;
        for (int it = 0; it < iters; it += 2) {
            int j0 = (it << 4) | g;
            int j1 = j0 + 16;                       // sentinel-safe
            int c0 = __shfl(cw.x, j0);
            float w0 = __int_as_float(__shfl(cw.y, j0));
            int c1 = __shfl(cw.x, j1);
            float w1 = __int_as_float(__shfl(cw.y, j1));
            float4 raw0 = ((const float4*)(t + (size_t)c0 * 32))[gl];
            float4 raw1 = ((const float4*)(t + (size_t)c1 * 32))[gl];
            const __half2* h0 = (const __half2*)&raw0;
            const __half2* h1 = (const __half2*)&raw1;
#pragma unroll
            for (int q = 0; q < 4; ++q) {
                float2 f0 = __half22float2(h0[q]);
                float2 f1 = __half22float2(h1[q]);
                acc[2 * q + 0] += w0 * f0.x + w1 * f1.x;
                acc[2 * q + 1] += w0 * f0.y + w1 * f1.y;
            }
        }
    }
#pragma unroll
    for (int i = 0; i < 8; ++i) {
        acc[i] += __shfl_xor(acc[i], 4);
        acc[i] += __shfl_xor(acc[i], 8);
        acc[i] += __shfl_xor(acc[i], 16);
        acc[i] += __shfl_xor(acc[i], 32);
    }
    if (g == 0) {
        if (F32OUT) {
            const float* add = (const float*)addin;
            float* out = (float*)outv;
            float4 a0 = ((const float4*)(add + (size_t)node * 32))[gl * 2 + 0];
            float4 a1 = ((const float4*)(add + (size_t)node * 32))[gl * 2 + 1];
            a0.x += acc[0]; a0.y += acc[1]; a0.z += acc[2]; a0.w += acc[3];
            a1.x += acc[4]; a1.y += acc[5]; a1.z += acc[6]; a1.w += acc[7];
            ((float4*)(out + (size_t)node * 32))[gl * 2 + 0] = a0;
            ((float4*)(out + (size_t)node * 32))[gl * 2 + 1] = a1;
        } else {
            const __half* add = (const __half*)addin;
            __half* out = (__half*)outv;
            float4 raw = ((const float4*)(add + (size_t)node * 32))[gl];
            const __half2* hp = (const __half2*)&raw;
            float2 f0 = __half22float2(hp[0]);
            float2 f1 = __half22float2(hp[1]);
            float2 f2 = __half22float2(hp[2]);
            float2 f3 = __half22float2(hp[3]);
            __half2 tmp[4];
            tmp[0] = __floats2half2_rn(acc[0] + f0.x, acc[1] + f0.y);
            tmp[1] = __floats2half2_rn(acc[2] + f1.x, acc[3] + f1.y);
            tmp[2] = __floats2half2_rn(acc[4] + f2.x, acc[5] + f2.y);
            tmp[3] = __floats2half2_rn(acc[6] + f3.x, acc[7] + f3.y);
            ((float4*)(out + (size_t)node * 32))[gl] = *(float4*)tmp;
        }
    }
}

// ---------- layer-1 MFMA GEMM: Hh = relu([xh|T1h|T2h] @ W1f + b1), fp16 out ----------
__global__ __launch_bounds__(256) void gemm_l1_mfma(const __half* __restrict__ A0,
                                                    const __half* __restrict__ A1,
                                                    const __half* __restrict__ A2,
                                                    const __half* __restrict__ Wf,
                                                    const float* __restrict__ b1,
                                                    __half* __restrict__ Hh, int nnodes) {
    const int wave = threadIdx.x >> 6;
    const int lane = threadIdx.x & 63;
    const int node0 = blockIdx.x * 64 + wave * 16;
    const int m = lane & 15;
    const int quad = lane >> 4;
    int arow = node0 + m;
    if (arow >= nnodes) arow = nnodes - 1;   // clamp: garbage rows never stored
    const __half* Ap[3] = {A0, A1, A2};
    f16x8 a[6];
#pragma unroll
    for (int kh = 0; kh < 6; ++kh) {
        const __half* A = Ap[kh >> 1];
        a[kh] = *(const f16x8*)(A + (size_t)arow * 64 + ((kh & 1) << 5) + (quad << 3));
    }
#pragma unroll
    for (int ct = 0; ct < 4; ++ct) {
        f32x4 acc = {0.f, 0.f, 0.f, 0.f};
#pragma unroll
        for (int kh = 0; kh < 6; ++kh) {
            f16x8 b = *(const f16x8*)(Wf + ((size_t)(ct * 6 + kh) * 64 + lane) * 8);
            acc = __builtin_amdgcn_mfma_f32_16x16x32_f16(a[kh], b, acc, 0, 0, 0);
        }
        int col = (ct << 4) | m;
        float bias = b1[col];
#pragma unroll
        for (int r = 0; r < 4; ++r) {
            int n = node0 + (quad << 2) + r;
            if (n < nnodes) Hh[(size_t)n * 64 + col] = __float2half(fmaxf(acc[r] + bias, 0.f));
        }
    }
}

// ---------- layer-2 MFMA GEMM: [P0|G1|G2] = Hh @ W2f (+b2 on P0) ----------
__global__ __launch_bounds__(256) void gemm_l2_mfma(const __half* __restrict__ Hh,
                                                    const __half* __restrict__ Wf,
                                                    const float* __restrict__ b2,
                                                    float* __restrict__ P0,
                                                    __half* __restrict__ G1,
                                                    __half* __restrict__ G2, int nnodes) {
    const int wave = threadIdx.x >> 6;
    const int lane = threadIdx.x & 63;
    const int node0 = blockIdx.x * 64 + wave * 16;
    const int m = lane & 15;
    const int quad = lane >> 4;
    int arow = node0 + m;
    if (arow >= nnodes) arow = nnodes - 1;
    f16x8 a0 = *(const f16x8*)(Hh + (size_t)arow * 64 + (quad << 3));
    f16x8 a1 = *(const f16x8*)(Hh + (size_t)arow * 64 + 32 + (quad << 3));
#pragma unroll
    for (int ct = 0; ct < 6; ++ct) {
        f32x4 acc = {0.f, 0.f, 0.f, 0.f};
        f16x8 b0 = *(const f16x8*)(Wf + ((size_t)(ct * 2 + 0) * 64 + lane) * 8);
        f16x8 b1v = *(const f16x8*)(Wf + ((size_t)(ct * 2 + 1) * 64 + lane) * 8);
        acc = __builtin_amdgcn_mfma_f32_16x16x32_f16(a0, b0, acc, 0, 0, 0);
        acc = __builtin_amdgcn_mfma_f32_16x16x32_f16(a1, b1v, acc, 0, 0, 0);
        int seg = ct >> 1;                      // wave-uniform
        int c = ((ct & 1) << 4) | m;            // col within segment
#pragma unroll
        for (int r = 0; r < 4; ++r) {
            int n = node0 + (quad << 2) + r;
            if (n >= nnodes) continue;
            float v = acc[r];
            if (seg == 0)      P0[(size_t)n * 32 + c] = v + b2[c];
            else if (seg == 1) G1[(size_t)n * 32 + c] = __float2half(v);
            else               G2[(size_t)n * 32 + c] = __float2half(v);
        }
    }
}

extern "C" void kernel_launch(void* const* d_in, const int* in_sizes, int n_in,
                              void* d_out, int out_size, void* d_ws, size_t ws_size,
                              hipStream_t stream) {
    const float* x  = (const float*)d_in[0];
    const int*   ei = (const int*)d_in[1];
    const float* W1 = (const float*)d_in[2];
    const float* b1 = (const float*)d_in[3];
    const float* W2 = (const float*)d_in[4];
    const float* b2 = (const float*)d_in[5];
    float* out = (float*)d_out;

    const int NN = N_NODES_C;
    const int NE = N_EDGES_C;
    const size_t HFEAT_BYTES = (size_t)NN * 64 * sizeof(__half);
    const size_t H32_BYTES = (size_t)NN * 32 * sizeof(__half);

    char* ws = (char*)d_ws;
    size_t off = 0;
    auto alloc = [&](size_t bytes) -> void* {
        void* p = ws + off;
        off += (bytes + 255) & ~(size_t)255;
        return p;
    };
    int*    bucket_cnt  = (int*)alloc((size_t)NBUK * 4);
    int*    bucket_base = (int*)alloc((size_t)(NBUK + 1) * 4);
    int*    bucket_next = (int*)alloc((size_t)NBUK * 4);
    int*    rowptr      = (int*)alloc((size_t)(NN + 1) * 4);
    float*  dis         = (float*)alloc((size_t)NN * 4);
    int2*   staged      = (int2*)alloc((size_t)NE * 8);
    int2*   colw        = (int2*)alloc((size_t)NE * 8);
    __half* xh          = (__half*)alloc(HFEAT_BYTES);
    __half* T1h         = (__half*)alloc(HFEAT_BYTES);   // layer1: T1; layer2: G1
    __half* T2h         = (__half*)alloc(HFEAT_BYTES);   // layer1: T2; layer2: G2
    __half* Hh          = (__half*)alloc(HFEAT_BYTES);
    __half* Qh          = (__half*)alloc(H32_BYTES);
    float*  P0          = (float*)alloc((size_t)NN * 32 * 4);
    __half* W1f         = (__half*)alloc((size_t)4 * 6 * 64 * 8 * 2);   // 24 KB
    __half* W2f         = (__half*)alloc((size_t)6 * 2 * 64 * 8 * 2);   // 12 KB

    const int PROPB = (NN + 3) / 4;
    const int CONVB = (NN * 64 / 4 + 255) / 256;
    const int BINB = (NE + CHUNK - 1) / CHUNK;
    const int GEMMB = (NN + 63) / 64;

    // ---- CSR build (bucket-atomic) + weight packing + x->fp16 ----
    hipMemsetAsync(bucket_cnt, 0, (size_t)NBUK * 4, stream);
    bucket_hist<<<BINB, 256, 0, stream>>>(ei, bucket_cnt, NE);
    bucket_scan<<<1, 64, 0, stream>>>(bucket_cnt, bucket_base, bucket_next, NBUK);
    bin_stage<<<BINB, 256, 0, stream>>>(ei, bucket_next, staged, NE);
    bin_count<<<NBUK, 256, 0, stream>>>(staged, bucket_base, rowptr, dis, NN, NE);
    bin_place<<<NBUK, 256, 0, stream>>>(staged, rowptr, dis, colw, NN);
    fold_w1f<<<(12288 + 255) / 256, 256, 0, stream>>>(W1, W1f);
    fold_w2f<<<(6144 + 255) / 256, 256, 0, stream>>>(W2, W2f);
    f2h_kernel<<<CONVB, 256, 0, stream>>>(x, xh, NN * 64 / 4);

    // ---- layer 1: Hh = relu(x@(W0-W2) + T1@W1 + T2@(2W2) + b1), T2 = prop(T1) ----
    prop_gather_h<<<PROPB, 256, 0, stream>>>(xh, rowptr, colw, T1h, NN);
    prop_gather_h<<<PROPB, 256, 0, stream>>>(T1h, rowptr, colw, T2h, NN);
    gemm_l1_mfma<<<GEMMB, 256, 0, stream>>>(xh, T1h, T2h, W1f, b1, Hh, NN);

    // ---- layer 2 (factored): out = P0 + prop(G1 + prop(G2)) ----
    gemm_l2_mfma<<<GEMMB, 256, 0, stream>>>(Hh, W2f, b2, P0, T1h, T2h, NN);
    prop_gather32<false><<<PROPB, 256, 0, stream>>>(T2h, rowptr, colw, T1h, Qh, NN);
    prop_gather32<true><<<PROPB, 256, 0, stream>>>(Qh, rowptr, colw, P0, out, NN);
}

// Round 12
// 327.144 us; speedup vs baseline: 1.4403x; 1.0226x over previous
//
#include <hip/hip_runtime.h>
#include <hip/hip_fp16.h>

#define N_NODES_C 100000
#define N_EDGES_C 1200000
#define NBUK ((N_NODES_C + 255) >> 8)   // 391 buckets of 256 nodes
#define CHUNK 4096                       // edges per binning block

typedef _Float16 f16x8 __attribute__((ext_vector_type(8)));
typedef float f32x4 __attribute__((ext_vector_type(4)));

// ---------- bucket-level histogram: LDS aggregate, ~115k global atomics ----------
__global__ __launch_bounds__(256) void bucket_hist(const int* __restrict__ ei,
                                                   int* __restrict__ bucket_cnt, int nedges) {
    __shared__ int cnt[NBUK];
    const int tid = threadIdx.x;
    const int base = blockIdx.x * CHUNK;
    const int nloc = min(CHUNK, nedges - base);
    for (int i = tid; i < NBUK; i += 256) cnt[i] = 0;
    __syncthreads();
    for (int i = tid; i < nloc; i += 256) atomicAdd(&cnt[ei[base + i] >> 8], 1);
    __syncthreads();
    for (int b = tid; b < NBUK; b += 256) {
        int n = cnt[b];
        if (n) atomicAdd(&bucket_cnt[b], n);
    }
}

// ---------- scan 391 bucket counts -> bucket_base / bucket_next ----------
__global__ void bucket_scan(const int* __restrict__ bucket_cnt, int* __restrict__ bucket_base,
                            int* __restrict__ bucket_next, int nb) {
    if (threadIdx.x == 0 && blockIdx.x == 0) {
        int acc = 0;
        for (int i = 0; i < nb; ++i) {
            bucket_base[i] = acc;
            bucket_next[i] = acc;
            acc += bucket_cnt[i];
        }
        bucket_base[nb] = acc;
    }
}

// ---------- phase B: LDS-binned staging of (r,c) grouped by 256-node bucket ----------
__global__ __launch_bounds__(256) void bin_stage(const int* __restrict__ ei,
                                                 int* __restrict__ bucket_next,
                                                 int2* __restrict__ staged, int nedges) {
    __shared__ int cnt[NBUK];
    __shared__ int ofs[NBUK];
    __shared__ int run[NBUK];
    __shared__ int gbase[NBUK];
    __shared__ int ssum[256];
    __shared__ int2 sedge[CHUNK];
    const int tid = threadIdx.x;
    const int base = blockIdx.x * CHUNK;
    const int nloc = min(CHUNK, nedges - base);

    for (int i = tid; i < NBUK; i += 256) { cnt[i] = 0; run[i] = 0; }
    __syncthreads();

    int r[16], c[16];
#pragma unroll
    for (int k = 0; k < 16; ++k) {
        int loc = tid + k * 256;
        bool ok = loc < nloc;
        int idx = base + loc;
        r[k] = ok ? ei[idx] : -1;
        c[k] = ok ? ei[nedges + idx] : 0;
        if (ok) atomicAdd(&cnt[r[k] >> 8], 1);
    }
    __syncthreads();

    // exclusive scan of cnt[NBUK] -> ofs
    int a0 = (2 * tid < NBUK) ? cnt[2 * tid] : 0;
    int a1 = (2 * tid + 1 < NBUK) ? cnt[2 * tid + 1] : 0;
    ssum[tid] = a0 + a1;
    __syncthreads();
    for (int off = 1; off < 256; off <<= 1) {
        int v = ssum[tid];
        int add = (tid >= off) ? ssum[tid - off] : 0;
        __syncthreads();
        ssum[tid] = v + add;
        __syncthreads();
    }
    int excl = (tid > 0) ? ssum[tid - 1] : 0;
    if (2 * tid < NBUK) ofs[2 * tid] = excl;
    if (2 * tid + 1 < NBUK) ofs[2 * tid + 1] = excl + a0;
    __syncthreads();

    // place edges into LDS grouped by bucket
#pragma unroll
    for (int k = 0; k < 16; ++k) {
        if (r[k] >= 0) {
            int b = r[k] >> 8;
            int p = atomicAdd(&run[b], 1);
            sedge[ofs[b] + p] = make_int2(r[k], c[k]);
        }
    }
    __syncthreads();

    // allocate global runs (one atomic per non-empty bucket)
    for (int b = tid; b < NBUK; b += 256) {
        int n = cnt[b];
        gbase[b] = n ? atomicAdd(&bucket_next[b], n) : 0;
    }
    __syncthreads();

    // coalesced copy-out: consecutive i are bucket-grouped runs
    for (int i = tid; i < nloc; i += 256) {
        int2 e = sedge[i];
        int b = e.x >> 8;
        staged[gbase[b] + (i - ofs[b])] = e;
    }
}

// ---------- phase C1: per-bucket degree count -> rowptr slice + deg_inv_sqrt ----------
__global__ __launch_bounds__(256) void bin_count(const int2* __restrict__ staged,
                                                 const int* __restrict__ bucket_base,
                                                 int* __restrict__ rowptr, float* __restrict__ dis,
                                                 int nnodes, int nedges) {
    __shared__ int deg[256];
    __shared__ int ssum[256];
    const int b = blockIdx.x;
    const int n0 = b << 8;
    const int nend = min(n0 + 256, nnodes);
    const int nloc = nend - n0;
    const int tid = threadIdx.x;
    deg[tid] = 0;
    __syncthreads();
    const int ebase = bucket_base[b];
    const int ecount = bucket_base[b + 1] - ebase;
    for (int i = tid; i < ecount; i += 256) {
        atomicAdd(&deg[staged[ebase + i].x - n0], 1);
    }
    __syncthreads();
    int d = deg[tid];
    if (tid < nloc) {
        float df = (float)d;
        dis[n0 + tid] = (d > 0) ? (1.0f / sqrtf(fmaxf(df, 1.f))) : 0.f;
    }
    ssum[tid] = d;
    __syncthreads();
    for (int off = 1; off < 256; off <<= 1) {
        int v = ssum[tid];
        int add = (tid >= off) ? ssum[tid - off] : 0;
        __syncthreads();
        ssum[tid] = v + add;
        __syncthreads();
    }
    int excl = (tid > 0) ? ssum[tid - 1] : 0;
    if (tid < nloc) rowptr[n0 + tid] = ebase + excl;
    if (b == NBUK - 1 && tid == 0) rowptr[nnodes] = nedges;
}

// ---------- phase C2: per-bucket exact CSR placement + norm weight ----------
__global__ __launch_bounds__(256) void bin_place(const int2* __restrict__ staged,
                                                 const int* __restrict__ rowptr,
                                                 const float* __restrict__ dis,
                                                 int2* __restrict__ colw, int nnodes) {
    __shared__ int rp[256];
    __shared__ int nx[256];
    __shared__ float dl[256];
    const int b = blockIdx.x;
    const int n0 = b << 8;
    const int nend = min(n0 + 256, nnodes);
    const int nloc = nend - n0;
    const int tid = threadIdx.x;
    if (tid < nloc) {
        rp[tid] = rowptr[n0 + tid];
        dl[tid] = dis[n0 + tid];
    }
    nx[tid] = 0;
    __syncthreads();
    const int ebase = rowptr[n0];
    const int ecount = rowptr[nend] - ebase;
    for (int i = tid; i < ecount; i += 256) {
        int2 e = staged[ebase + i];
        int rrel = e.x - n0;
        int p = atomicAdd(&nx[rrel], 1);
        float w = -dl[rrel] * dis[e.y];
        colw[rp[rrel] + p] = make_int2(e.y, __float_as_int(w));
    }
}

// ---------- pack layer-1 folded weights into MFMA B-fragment layout (fp16) ----------
__global__ void fold_w1f(const float* __restrict__ W, __half* __restrict__ Wf) {
    int i = blockIdx.x * blockDim.x + threadIdx.x;
    if (i >= 4 * 6 * 64 * 8) return;
    int j = i & 7;
    int lane = (i >> 3) & 63;
    int rest = i >> 9;
    int kh = rest % 6;
    int ct = rest / 6;
    int term = kh >> 1;
    int k = ((kh & 1) << 5) | ((lane >> 4) << 3) | j;
    int c = (ct << 4) | (lane & 15);
    float w0 = W[k * 64 + c];
    float w1 = W[4096 + k * 64 + c];
    float w2 = W[2 * 4096 + k * 64 + c];
    float v = (term == 0) ? (w0 - w2) : ((term == 1) ? w1 : 2.0f * w2);
    Wf[i] = __float2half(v);
}

// ---------- pack layer-2 concat weights into MFMA B-fragment layout (fp16) ----------
__global__ void fold_w2f(const float* __restrict__ W, __half* __restrict__ Wf) {
    int i = blockIdx.x * blockDim.x + threadIdx.x;
    if (i >= 6 * 2 * 64 * 8) return;
    int j = i & 7;
    int lane = (i >> 3) & 63;
    int rest = i >> 9;
    int kh = rest & 1;
    int ct = rest >> 1;
    int k = (kh << 5) | ((lane >> 4) << 3) | j;
    int cg = ct * 16 + (lane & 15);
    int seg = cg >> 5;
    int c = cg & 31;
    float w0 = W[k * 32 + c];
    float w1 = W[2048 + k * 32 + c];
    float w2 = W[2 * 2048 + k * 32 + c];
    float v = (seg == 0) ? (w0 - w2) : ((seg == 1) ? w1 : 2.0f * w2);
    Wf[i] = __float2half(v);
}

// ---------- fp32 -> fp16 feature conversion (4 elems/thread) ----------
__global__ void f2h_kernel(const float* __restrict__ in, __half* __restrict__ out, int n4) {
    int i = blockIdx.x * blockDim.x + threadIdx.x;
    if (i >= n4) return;
    float4 v = ((const float4*)in)[i];
    __half2 tmp[2];
    tmp[0] = __floats2half2_rn(v.x, v.y);
    tmp[1] = __floats2half2_rn(v.z, v.w);
    ((float2*)out)[i] = *(float2*)tmp;
}

// ---------- prop64: 8 lanes/edge; dual-gather main loop + uniform single tail ----------
// m / iters are wave-uniform (one node per wave) -> tail branch is divergence-free.
__global__ __launch_bounds__(256) void prop_gather_h(const __half* __restrict__ t,
                                                     const int* __restrict__ rowptr,
                                                     const int2* __restrict__ colw,
                                                     __half* __restrict__ out, int nnodes) {
    int node = blockIdx.x * 4 + (threadIdx.x >> 6);
    if (node >= nnodes) return;
    int lane = threadIdx.x & 63;
    int g = lane >> 3;    // edge group 0..7
    int gl = lane & 7;    // channel octet
    int s = rowptr[node];
    int e = rowptr[node + 1];
    float acc[8] = {0.f, 0.f, 0.f, 0.f, 0.f, 0.f, 0.f, 0.f};
    for (int base = s; base < e; base += 64) {
        int m = e - base;
        if (m > 64) m = 64;
        int2 cw = (lane < m) ? colw[base + lane] : make_int2(0, 0);
        int iters = (m + 7) >> 3;
        int it = 0;
        for (; it + 1 < iters; it += 2) {
            int j0 = (it << 3) | g;
            int j1 = j0 + 8;
            int c0 = __shfl(cw.x, j0);
            float w0 = __int_as_float(__shfl(cw.y, j0));
            int c1 = __shfl(cw.x, j1);
            float w1 = __int_as_float(__shfl(cw.y, j1));
            float4 raw0 = ((const float4*)(t + (size_t)c0 * 64))[gl];
            float4 raw1 = ((const float4*)(t + (size_t)c1 * 64))[gl];
            const __half2* h0 = (const __half2*)&raw0;
            const __half2* h1 = (const __half2*)&raw1;
#pragma unroll
            for (int q = 0; q < 4; ++q) {
                float2 f0 = __half22float2(h0[q]);
                float2 f1 = __half22float2(h1[q]);
                acc[2 * q + 0] += w0 * f0.x + w1 * f1.x;
                acc[2 * q + 1] += w0 * f0.y + w1 * f1.y;
            }
        }
        if (it < iters) {   // wave-uniform tail: single gather (sentinel-safe)
            int j0 = (it << 3) | g;
            int c0 = __shfl(cw.x, j0);
            float w0 = __int_as_float(__shfl(cw.y, j0));
            float4 raw0 = ((const float4*)(t + (size_t)c0 * 64))[gl];
            const __half2* h0 = (const __half2*)&raw0;
#pragma unroll
            for (int q = 0; q < 4; ++q) {
                float2 f0 = __half22float2(h0[q]);
                acc[2 * q + 0] += w0 * f0.x;
                acc[2 * q + 1] += w0 * f0.y;
            }
        }
    }
#pragma unroll
    for (int i = 0; i < 8; ++i) {
        acc[i] += __shfl_xor(acc[i], 8);
        acc[i] += __shfl_xor(acc[i], 16);
        acc[i] += __shfl_xor(acc[i], 32);
    }
    if (g == 0) {
        __half2 tmp[4];
        tmp[0] = __floats2half2_rn(acc[0], acc[1]);
        tmp[1] = __floats2half2_rn(acc[2], acc[3]);
        tmp[2] = __floats2half2_rn(acc[4], acc[5]);
        tmp[3] = __floats2half2_rn(acc[6], acc[7]);
        ((float4*)(out + (size_t)node * 64))[gl] = *(float4*)tmp;
    }
}

// ---------- prop32: 4 lanes/edge; dual main + uniform single tail; fused add-input ----------
template <bool F32OUT>
__global__ __launch_bounds__(256) void prop_gather32(const __half* __restrict__ t,
                                                     const int* __restrict__ rowptr,
                                                     const int2* __restrict__ colw,
                                                     const void* __restrict__ addin,
                                                     void* __restrict__ outv, int nnodes) {
    int node = blockIdx.x * 4 + (threadIdx.x >> 6);
    if (node >= nnodes) return;
    int lane = threadIdx.x & 63;
    int g = lane >> 2;    // edge group 0..15
    int gl = lane & 3;    // channel octet
    int s = rowptr[node];
    int e = rowptr[node + 1];
    float acc[8] = {0.f, 0.f, 0.f, 0.f, 0.f, 0.f, 0.f, 0.f};
    for (int base = s; base < e; base += 64) {
        int m = e - base;
        if (m > 64) m = 64;
        int2 cw = (lane < m) ? colw[base + lane] : make_int2(0, 0);
        int iters = (m + 15) >> 4;   // == 1 for deg <= 16 (~90% of nodes)
        int it = 0;
        for (; it + 1 < iters; it += 2) {
            int j0 = (it << 4) | g;
            int j1 = j0 + 16;
            int c0 = __shfl(cw.x, j0);
            float w0 = __int_as_float(__shfl(cw.y, j0));
            int c1 = __shfl(cw.x, j1);
            float w1 = __int_as_float(__shfl(cw.y, j1));
            float4 raw0 = ((const float4*)(t + (size_t)c0 * 32))[gl];
            float4 raw1 = ((const float4*)(t + (size_t)c1 * 32))[gl];
            const __half2* h0 = (const __half2*)&raw0;
            const __half2* h1 = (const __half2*)&raw1;
#pragma unroll
            for (int q = 0; q < 4; ++q) {
                float2 f0 = __half22float2(h0[q]);
                float2 f1 = __half22float2(h1[q]);
                acc[2 * q + 0] += w0 * f0.x + w1 * f1.x;
                acc[2 * q + 1] += w0 * f0.y + w1 * f1.y;
            }
        }
        if (it < iters) {   // wave-uniform tail: single gather (sentinel-safe)
            int j0 = (it << 4) | g;
            int c0 = __shfl(cw.x, j0);
            float w0 = __int_as_float(__shfl(cw.y, j0));
            float4 raw0 = ((const float4*)(t + (size_t)c0 * 32))[gl];
            const __half2* h0 = (const __half2*)&raw0;
#pragma unroll
            for (int q = 0; q < 4; ++q) {
                float2 f0 = __half22float2(h0[q]);
                acc[2 * q + 0] += w0 * f0.x;
                acc[2 * q + 1] += w0 * f0.y;
            }
        }
    }
#pragma unroll
    for (int i = 0; i < 8; ++i) {
        acc[i] += __shfl_xor(acc[i], 4);
        acc[i] += __shfl_xor(acc[i], 8);
        acc[i] += __shfl_xor(acc[i], 16);
        acc[i] += __shfl_xor(acc[i], 32);
    }
    if (g == 0) {
        if (F32OUT) {
            const float* add = (const float*)addin;
            float* out = (float*)outv;
            float4 a0 = ((const float4*)(add + (size_t)node * 32))[gl * 2 + 0];
            float4 a1 = ((const float4*)(add + (size_t)node * 32))[gl * 2 + 1];
            a0.x += acc[0]; a0.y += acc[1]; a0.z += acc[2]; a0.w += acc[3];
            a1.x += acc[4]; a1.y += acc[5]; a1.z += acc[6]; a1.w += acc[7];
            ((float4*)(out + (size_t)node * 32))[gl * 2 + 0] = a0;
            ((float4*)(out + (size_t)node * 32))[gl * 2 + 1] = a1;
        } else {
            const __half* add = (const __half*)addin;
            __half* out = (__half*)outv;
            float4 raw = ((const float4*)(add + (size_t)node * 32))[gl];
            const __half2* hp = (const __half2*)&raw;
            float2 f0 = __half22float2(hp[0]);
            float2 f1 = __half22float2(hp[1]);
            float2 f2 = __half22float2(hp[2]);
            float2 f3 = __half22float2(hp[3]);
            __half2 tmp[4];
            tmp[0] = __floats2half2_rn(acc[0] + f0.x, acc[1] + f0.y);
            tmp[1] = __floats2half2_rn(acc[2] + f1.x, acc[3] + f1.y);
            tmp[2] = __floats2half2_rn(acc[4] + f2.x, acc[5] + f2.y);
            tmp[3] = __floats2half2_rn(acc[6] + f3.x, acc[7] + f3.y);
            ((float4*)(out + (size_t)node * 32))[gl] = *(float4*)tmp;
        }
    }
}

// ---------- layer-1 MFMA GEMM: Hh = relu([xh|T1h|T2h] @ W1f + b1), fp16 out ----------
__global__ __launch_bounds__(256) void gemm_l1_mfma(const __half* __restrict__ A0,
                                                    const __half* __restrict__ A1,
                                                    const __half* __restrict__ A2,
                                                    const __half* __restrict__ Wf,
                                                    const float* __restrict__ b1,
                                                    __half* __restrict__ Hh, int nnodes) {
    const int wave = threadIdx.x >> 6;
    const int lane = threadIdx.x & 63;
    const int node0 = blockIdx.x * 64 + wave * 16;
    const int m = lane & 15;
    const int quad = lane >> 4;
    int arow = node0 + m;
    if (arow >= nnodes) arow = nnodes - 1;   // clamp: garbage rows never stored
    const __half* Ap[3] = {A0, A1, A2};
    f16x8 a[6];
#pragma unroll
    for (int kh = 0; kh < 6; ++kh) {
        const __half* A = Ap[kh >> 1];
        a[kh] = *(const f16x8*)(A + (size_t)arow * 64 + ((kh & 1) << 5) + (quad << 3));
    }
#pragma unroll
    for (int ct = 0; ct < 4; ++ct) {
        f32x4 acc = {0.f, 0.f, 0.f, 0.f};
#pragma unroll
        for (int kh = 0; kh < 6; ++kh) {
            f16x8 b = *(const f16x8*)(Wf + ((size_t)(ct * 6 + kh) * 64 + lane) * 8);
            acc = __builtin_amdgcn_mfma_f32_16x16x32_f16(a[kh], b, acc, 0, 0, 0);
        }
        int col = (ct << 4) | m;
        float bias = b1[col];
#pragma unroll
        for (int r = 0; r < 4; ++r) {
            int n = node0 + (quad << 2) + r;
            if (n < nnodes) Hh[(size_t)n * 64 + col] = __float2half(fmaxf(acc[r] + bias, 0.f));
        }
    }
}

// ---------- layer-2 MFMA GEMM: [P0|G1|G2] = Hh @ W2f (+b2 on P0) ----------
__global__ __launch_bounds__(256) void gemm_l2_mfma(const __half* __restrict__ Hh,
                                                    const __half* __restrict__ Wf,
                                                    const float* __restrict__ b2,
                                                    float* __restrict__ P0,
                                                    __half* __restrict__ G1,
                                                    __half* __restrict__ G2, int nnodes) {
    const int wave = threadIdx.x >> 6;
    const int lane = threadIdx.x & 63;
    const int node0 = blockIdx.x * 64 + wave * 16;
    const int m = lane & 15;
    const int quad = lane >> 4;
    int arow = node0 + m;
    if (arow >= nnodes) arow = nnodes - 1;
    f16x8 a0 = *(const f16x8*)(Hh + (size_t)arow * 64 + (quad << 3));
    f16x8 a1 = *(const f16x8*)(Hh + (size_t)arow * 64 + 32 + (quad << 3));
#pragma unroll
    for (int ct = 0; ct < 6; ++ct) {
        f32x4 acc = {0.f, 0.f, 0.f, 0.f};
        f16x8 b0 = *(const f16x8*)(Wf + ((size_t)(ct * 2 + 0) * 64 + lane) * 8);
        f16x8 b1v = *(const f16x8*)(Wf + ((size_t)(ct * 2 + 1) * 64 + lane) * 8);
        acc = __builtin_amdgcn_mfma_f32_16x16x32_f16(a0, b0, acc, 0, 0, 0);
        acc = __builtin_amdgcn_mfma_f32_16x16x32_f16(a1, b1v, acc, 0, 0, 0);
        int seg = ct >> 1;                      // wave-uniform
        int c = ((ct & 1) << 4) | m;            // col within segment
#pragma unroll
        for (int r = 0; r < 4; ++r) {
            int n = node0 + (quad << 2) + r;
            if (n >= nnodes) continue;
            float v = acc[r];
            if (seg == 0)      P0[(size_t)n * 32 + c] = v + b2[c];
            else if (seg == 1) G1[(size_t)n * 32 + c] = __float2half(v);
            else               G2[(size_t)n * 32 + c] = __float2half(v);
        }
    }
}

extern "C" void kernel_launch(void* const* d_in, const int* in_sizes, int n_in,
                              void* d_out, int out_size, void* d_ws, size_t ws_size,
                              hipStream_t stream) {
    const float* x  = (const float*)d_in[0];
    const int*   ei = (const int*)d_in[1];
    const float* W1 = (const float*)d_in[2];
    const float* b1 = (const float*)d_in[3];
    const float* W2 = (const float*)d_in[4];
    const float* b2 = (const float*)d_in[5];
    float* out = (float*)d_out;

    const int NN = N_NODES_C;
    const int NE = N_EDGES_C;
    const size_t HFEAT_BYTES = (size_t)NN * 64 * sizeof(__half);
    const size_t H32_BYTES = (size_t)NN * 32 * sizeof(__half);

    char* ws = (char*)d_ws;
    size_t off = 0;
    auto alloc = [&](size_t bytes) -> void* {
        void* p = ws + off;
        off += (bytes + 255) & ~(size_t)255;
        return p;
    };
    int*    bucket_cnt  = (int*)alloc((size_t)NBUK * 4);
    int*    bucket_base = (int*)alloc((size_t)(NBUK + 1) * 4);
    int*    bucket_next = (int*)alloc((size_t)NBUK * 4);
    int*    rowptr      = (int*)alloc((size_t)(NN + 1) * 4);
    float*  dis         = (float*)alloc((size_t)NN * 4);
    int2*   staged      = (int2*)alloc((size_t)NE * 8);
    int2*   colw        = (int2*)alloc((size_t)NE * 8);
    __half* xh          = (__half*)alloc(HFEAT_BYTES);
    __half* T1h         = (__half*)alloc(HFEAT_BYTES);   // layer1: T1; layer2: G1
    __half* T2h         = (__half*)alloc(HFEAT_BYTES);   // layer1: T2; layer2: G2
    __half* Hh          = (__half*)alloc(HFEAT_BYTES);
    __half* Qh          = (__half*)alloc(H32_BYTES);
    float*  P0          = (float*)alloc((size_t)NN * 32 * 4);
    __half* W1f         = (__half*)alloc((size_t)4 * 6 * 64 * 8 * 2);   // 24 KB
    __half* W2f         = (__half*)alloc((size_t)6 * 2 * 64 * 8 * 2);   // 12 KB

    const int PROPB = (NN + 3) / 4;
    const int CONVB = (NN * 64 / 4 + 255) / 256;
    const int BINB = (NE + CHUNK - 1) / CHUNK;
    const int GEMMB = (NN + 63) / 64;

    // ---- CSR build (bucket-atomic) + weight packing + x->fp16 ----
    hipMemsetAsync(bucket_cnt, 0, (size_t)NBUK * 4, stream);
    bucket_hist<<<BINB, 256, 0, stream>>>(ei, bucket_cnt, NE);
    bucket_scan<<<1, 64, 0, stream>>>(bucket_cnt, bucket_base, bucket_next, NBUK);
    bin_stage<<<BINB, 256, 0, stream>>>(ei, bucket_next, staged, NE);
    bin_count<<<NBUK, 256, 0, stream>>>(staged, bucket_base, rowptr, dis, NN, NE);
    bin_place<<<NBUK, 256, 0, stream>>>(staged, rowptr, dis, colw, NN);
    fold_w1f<<<(12288 + 255) / 256, 256, 0, stream>>>(W1, W1f);
    fold_w2f<<<(6144 + 255) / 256, 256, 0, stream>>>(W2, W2f);
    f2h_kernel<<<CONVB, 256, 0, stream>>>(x, xh, NN * 64 / 4);

    // ---- layer 1: Hh = relu(x@(W0-W2) + T1@W1 + T2@(2W2) + b1), T2 = prop(T1) ----
    prop_gather_h<<<PROPB, 256, 0, stream>>>(xh, rowptr, colw, T1h, NN);
    prop_gather_h<<<PROPB, 256, 0, stream>>>(T1h, rowptr, colw, T2h, NN);
    gemm_l1_mfma<<<GEMMB, 256, 0, stream>>>(xh, T1h, T2h, W1f, b1, Hh, NN);

    // ---- layer 2 (factored): out = P0 + prop(G1 + prop(G2)) ----
    gemm_l2_mfma<<<GEMMB, 256, 0, stream>>>(Hh, W2f, b2, P0, T1h, T2h, NN);
    prop_gather32<false><<<PROPB, 256, 0, stream>>>(T2h, rowptr, colw, T1h, Qh, NN);
    prop_gather32<true><<<PROPB, 256, 0, stream>>>(Qh, rowptr, colw, P0, out, NN);
}

// Round 13
// 318.629 us; speedup vs baseline: 1.4788x; 1.0267x over previous
//
#include <hip/hip_runtime.h>
#include <hip/hip_fp16.h>

#define N_NODES_C 100000
#define N_EDGES_C 1200000
#define NBUK ((N_NODES_C + 255) >> 8)   // 391 buckets of 256 nodes
#define CHUNK 4096                       // edges per binning block

typedef _Float16 f16x8 __attribute__((ext_vector_type(8)));
typedef float f32x4 __attribute__((ext_vector_type(4)));

// ---------- bucket-level histogram: LDS aggregate, ~115k global atomics ----------
__global__ __launch_bounds__(256) void bucket_hist(const int* __restrict__ ei,
                                                   int* __restrict__ bucket_cnt, int nedges) {
    __shared__ int cnt[NBUK];
    const int tid = threadIdx.x;
    const int base = blockIdx.x * CHUNK;
    const int nloc = min(CHUNK, nedges - base);
    for (int i = tid; i < NBUK; i += 256) cnt[i] = 0;
    __syncthreads();
    for (int i = tid; i < nloc; i += 256) atomicAdd(&cnt[ei[base + i] >> 8], 1);
    __syncthreads();
    for (int b = tid; b < NBUK; b += 256) {
        int n = cnt[b];
        if (n) atomicAdd(&bucket_cnt[b], n);
    }
}

// ---------- scan 391 bucket counts -> bucket_base / bucket_next ----------
__global__ void bucket_scan(const int* __restrict__ bucket_cnt, int* __restrict__ bucket_base,
                            int* __restrict__ bucket_next, int nb) {
    if (threadIdx.x == 0 && blockIdx.x == 0) {
        int acc = 0;
        for (int i = 0; i < nb; ++i) {
            bucket_base[i] = acc;
            bucket_next[i] = acc;
            acc += bucket_cnt[i];
        }
        bucket_base[nb] = acc;
    }
}

// ---------- phase B: LDS-binned staging of (r,c) grouped by 256-node bucket ----------
__global__ __launch_bounds__(256) void bin_stage(const int* __restrict__ ei,
                                                 int* __restrict__ bucket_next,
                                                 int2* __restrict__ staged, int nedges) {
    __shared__ int cnt[NBUK];
    __shared__ int ofs[NBUK];
    __shared__ int run[NBUK];
    __shared__ int gbase[NBUK];
    __shared__ int ssum[256];
    __shared__ int2 sedge[CHUNK];
    const int tid = threadIdx.x;
    const int base = blockIdx.x * CHUNK;
    const int nloc = min(CHUNK, nedges - base);

    for (int i = tid; i < NBUK; i += 256) { cnt[i] = 0; run[i] = 0; }
    __syncthreads();

    int r[16], c[16];
#pragma unroll
    for (int k = 0; k < 16; ++k) {
        int loc = tid + k * 256;
        bool ok = loc < nloc;
        int idx = base + loc;
        r[k] = ok ? ei[idx] : -1;
        c[k] = ok ? ei[nedges + idx] : 0;
        if (ok) atomicAdd(&cnt[r[k] >> 8], 1);
    }
    __syncthreads();

    // exclusive scan of cnt[NBUK] -> ofs
    int a0 = (2 * tid < NBUK) ? cnt[2 * tid] : 0;
    int a1 = (2 * tid + 1 < NBUK) ? cnt[2 * tid + 1] : 0;
    ssum[tid] = a0 + a1;
    __syncthreads();
    for (int off = 1; off < 256; off <<= 1) {
        int v = ssum[tid];
        int add = (tid >= off) ? ssum[tid - off] : 0;
        __syncthreads();
        ssum[tid] = v + add;
        __syncthreads();
    }
    int excl = (tid > 0) ? ssum[tid - 1] : 0;
    if (2 * tid < NBUK) ofs[2 * tid] = excl;
    if (2 * tid + 1 < NBUK) ofs[2 * tid + 1] = excl + a0;
    __syncthreads();

    // place edges into LDS grouped by bucket
#pragma unroll
    for (int k = 0; k < 16; ++k) {
        if (r[k] >= 0) {
            int b = r[k] >> 8;
            int p = atomicAdd(&run[b], 1);
            sedge[ofs[b] + p] = make_int2(r[k], c[k]);
        }
    }
    __syncthreads();

    // allocate global runs (one atomic per non-empty bucket)
    for (int b = tid; b < NBUK; b += 256) {
        int n = cnt[b];
        gbase[b] = n ? atomicAdd(&bucket_next[b], n) : 0;
    }
    __syncthreads();

    // coalesced copy-out: consecutive i are bucket-grouped runs
    for (int i = tid; i < nloc; i += 256) {
        int2 e = sedge[i];
        int b = e.x >> 8;
        staged[gbase[b] + (i - ofs[b])] = e;
    }
}

// ---------- phase C1: per-bucket degree count -> rowptr slice + deg_inv_sqrt ----------
__global__ __launch_bounds__(256) void bin_count(const int2* __restrict__ staged,
                                                 const int* __restrict__ bucket_base,
                                                 int* __restrict__ rowptr, float* __restrict__ dis,
                                                 int nnodes, int nedges) {
    __shared__ int deg[256];
    __shared__ int ssum[256];
    const int b = blockIdx.x;
    const int n0 = b << 8;
    const int nend = min(n0 + 256, nnodes);
    const int nloc = nend - n0;
    const int tid = threadIdx.x;
    deg[tid] = 0;
    __syncthreads();
    const int ebase = bucket_base[b];
    const int ecount = bucket_base[b + 1] - ebase;
    for (int i = tid; i < ecount; i += 256) {
        atomicAdd(&deg[staged[ebase + i].x - n0], 1);
    }
    __syncthreads();
    int d = deg[tid];
    if (tid < nloc) {
        float df = (float)d;
        dis[n0 + tid] = (d > 0) ? (1.0f / sqrtf(fmaxf(df, 1.f))) : 0.f;
    }
    ssum[tid] = d;
    __syncthreads();
    for (int off = 1; off < 256; off <<= 1) {
        int v = ssum[tid];
        int add = (tid >= off) ? ssum[tid - off] : 0;
        __syncthreads();
        ssum[tid] = v + add;
        __syncthreads();
    }
    int excl = (tid > 0) ? ssum[tid - 1] : 0;
    if (tid < nloc) rowptr[n0 + tid] = ebase + excl;
    if (b == NBUK - 1 && tid == 0) rowptr[nnodes] = nedges;
}

// ---------- phase C2: per-bucket exact CSR placement + norm weight ----------
__global__ __launch_bounds__(256) void bin_place(const int2* __restrict__ staged,
                                                 const int* __restrict__ rowptr,
                                                 const float* __restrict__ dis,
                                                 int2* __restrict__ colw, int nnodes) {
    __shared__ int rp[256];
    __shared__ int nx[256];
    __shared__ float dl[256];
    const int b = blockIdx.x;
    const int n0 = b << 8;
    const int nend = min(n0 + 256, nnodes);
    const int nloc = nend - n0;
    const int tid = threadIdx.x;
    if (tid < nloc) {
        rp[tid] = rowptr[n0 + tid];
        dl[tid] = dis[n0 + tid];
    }
    nx[tid] = 0;
    __syncthreads();
    const int ebase = rowptr[n0];
    const int ecount = rowptr[nend] - ebase;
    for (int i = tid; i < ecount; i += 256) {
        int2 e = staged[ebase + i];
        int rrel = e.x - n0;
        int p = atomicAdd(&nx[rrel], 1);
        float w = -dl[rrel] * dis[e.y];
        colw[rp[rrel] + p] = make_int2(e.y, __float_as_int(w));
    }
}

// ---------- pack layer-1 folded weights into MFMA B-fragment layout (fp16) ----------
__global__ void fold_w1f(const float* __restrict__ W, __half* __restrict__ Wf) {
    int i = blockIdx.x * blockDim.x + threadIdx.x;
    if (i >= 4 * 6 * 64 * 8) return;
    int j = i & 7;
    int lane = (i >> 3) & 63;
    int rest = i >> 9;
    int kh = rest % 6;
    int ct = rest / 6;
    int term = kh >> 1;
    int k = ((kh & 1) << 5) | ((lane >> 4) << 3) | j;
    int c = (ct << 4) | (lane & 15);
    float w0 = W[k * 64 + c];
    float w1 = W[4096 + k * 64 + c];
    float w2 = W[2 * 4096 + k * 64 + c];
    float v = (term == 0) ? (w0 - w2) : ((term == 1) ? w1 : 2.0f * w2);
    Wf[i] = __float2half(v);
}

// ---------- pack layer-2 concat weights into MFMA B-fragment layout (fp16) ----------
__global__ void fold_w2f(const float* __restrict__ W, __half* __restrict__ Wf) {
    int i = blockIdx.x * blockDim.x + threadIdx.x;
    if (i >= 6 * 2 * 64 * 8) return;
    int j = i & 7;
    int lane = (i >> 3) & 63;
    int rest = i >> 9;
    int kh = rest & 1;
    int ct = rest >> 1;
    int k = (kh << 5) | ((lane >> 4) << 3) | j;
    int cg = ct * 16 + (lane & 15);
    int seg = cg >> 5;
    int c = cg & 31;
    float w0 = W[k * 32 + c];
    float w1 = W[2048 + k * 32 + c];
    float w2 = W[2 * 2048 + k * 32 + c];
    float v = (seg == 0) ? (w0 - w2) : ((seg == 1) ? w1 : 2.0f * w2);
    Wf[i] = __float2half(v);
}

// ---------- fp32 -> fp16 feature conversion (4 elems/thread) ----------
__global__ void f2h_kernel(const float* __restrict__ in, __half* __restrict__ out, int n4) {
    int i = blockIdx.x * blockDim.x + threadIdx.x;
    if (i >= n4) return;
    float4 v = ((const float4*)in)[i];
    __half2 tmp[2];
    tmp[0] = __floats2half2_rn(v.x, v.y);
    tmp[1] = __floats2half2_rn(v.z, v.w);
    ((float2*)out)[i] = *(float2*)tmp;
}

// ---------- prop64: 16 lanes/edge (4 ch, 8B loads), 4 edges/instr ----------
// accs=4, reduce = 2 shfl rounds; dual-gather main + wave-uniform single tail.
__global__ __launch_bounds__(256) void prop_gather_h(const __half* __restrict__ t,
                                                     const int* __restrict__ rowptr,
                                                     const int2* __restrict__ colw,
                                                     __half* __restrict__ out, int nnodes) {
    int node = blockIdx.x * 4 + (threadIdx.x >> 6);
    if (node >= nnodes) return;
    int lane = threadIdx.x & 63;
    int g = lane >> 4;     // edge group 0..3
    int cq = lane & 15;    // channel quad: ch 4*cq .. 4*cq+3
    int s = rowptr[node];
    int e = rowptr[node + 1];
    float acc[4] = {0.f, 0.f, 0.f, 0.f};
    for (int base = s; base < e; base += 64) {
        int m = e - base;
        if (m > 64) m = 64;
        int2 cw = (lane < m) ? colw[base + lane] : make_int2(0, 0);
        int iters = (m + 3) >> 2;
        int it = 0;
        for (; it + 1 < iters; it += 2) {
            int j0 = (it << 2) | g;
            int j1 = j0 + 4;
            int c0 = __shfl(cw.x, j0);
            float w0 = __int_as_float(__shfl(cw.y, j0));
            int c1 = __shfl(cw.x, j1);
            float w1 = __int_as_float(__shfl(cw.y, j1));
            float2 raw0 = ((const float2*)(t + (size_t)c0 * 64))[cq];
            float2 raw1 = ((const float2*)(t + (size_t)c1 * 64))[cq];
            const __half2* h0 = (const __half2*)&raw0;
            const __half2* h1 = (const __half2*)&raw1;
            float2 f00 = __half22float2(h0[0]);
            float2 f01 = __half22float2(h0[1]);
            float2 f10 = __half22float2(h1[0]);
            float2 f11 = __half22float2(h1[1]);
            acc[0] += w0 * f00.x + w1 * f10.x;
            acc[1] += w0 * f00.y + w1 * f10.y;
            acc[2] += w0 * f01.x + w1 * f11.x;
            acc[3] += w0 * f01.y + w1 * f11.y;
        }
        if (it < iters) {   // wave-uniform tail (sentinel-safe)
            int j0 = (it << 2) | g;
            int c0 = __shfl(cw.x, j0);
            float w0 = __int_as_float(__shfl(cw.y, j0));
            float2 raw0 = ((const float2*)(t + (size_t)c0 * 64))[cq];
            const __half2* h0 = (const __half2*)&raw0;
            float2 f00 = __half22float2(h0[0]);
            float2 f01 = __half22float2(h0[1]);
            acc[0] += w0 * f00.x;
            acc[1] += w0 * f00.y;
            acc[2] += w0 * f01.x;
            acc[3] += w0 * f01.y;
        }
    }
#pragma unroll
    for (int i = 0; i < 4; ++i) {
        acc[i] += __shfl_xor(acc[i], 16);
        acc[i] += __shfl_xor(acc[i], 32);
    }
    if (g == 0) {
        __half2 tmp[2];
        tmp[0] = __floats2half2_rn(acc[0], acc[1]);
        tmp[1] = __floats2half2_rn(acc[2], acc[3]);
        ((float2*)(out + (size_t)node * 64))[cq] = *(float2*)tmp;
    }
}

// ---------- prop32: 16 lanes/edge (2 ch, 4B loads), 4 edges/instr ----------
// accs=2, reduce = 2 shfl rounds x 2; fused add-input; fp16/fp32 out.
template <bool F32OUT>
__global__ __launch_bounds__(256) void prop_gather32(const __half* __restrict__ t,
                                                     const int* __restrict__ rowptr,
                                                     const int2* __restrict__ colw,
                                                     const void* __restrict__ addin,
                                                     void* __restrict__ outv, int nnodes) {
    int node = blockIdx.x * 4 + (threadIdx.x >> 6);
    if (node >= nnodes) return;
    int lane = threadIdx.x & 63;
    int g = lane >> 4;     // edge group 0..3
    int cq = lane & 15;    // channel pair: ch 2*cq, 2*cq+1
    int s = rowptr[node];
    int e = rowptr[node + 1];
    float acc0 = 0.f, acc1 = 0.f;
    for (int base = s; base < e; base += 64) {
        int m = e - base;
        if (m > 64) m = 64;
        int2 cw = (lane < m) ? colw[base + lane] : make_int2(0, 0);
        int iters = (m + 3) >> 2;
        int it = 0;
        for (; it + 1 < iters; it += 2) {
            int j0 = (it << 2) | g;
            int j1 = j0 + 4;
            int c0 = __shfl(cw.x, j0);
            float w0 = __int_as_float(__shfl(cw.y, j0));
            int c1 = __shfl(cw.x, j1);
            float w1 = __int_as_float(__shfl(cw.y, j1));
            __half2 r0 = ((const __half2*)(t + (size_t)c0 * 32))[cq];
            __half2 r1 = ((const __half2*)(t + (size_t)c1 * 32))[cq];
            float2 f0 = __half22float2(r0);
            float2 f1 = __half22float2(r1);
            acc0 += w0 * f0.x + w1 * f1.x;
            acc1 += w0 * f0.y + w1 * f1.y;
        }
        if (it < iters) {   // wave-uniform tail (sentinel-safe)
            int j0 = (it << 2) | g;
            int c0 = __shfl(cw.x, j0);
            float w0 = __int_as_float(__shfl(cw.y, j0));
            __half2 r0 = ((const __half2*)(t + (size_t)c0 * 32))[cq];
            float2 f0 = __half22float2(r0);
            acc0 += w0 * f0.x;
            acc1 += w0 * f0.y;
        }
    }
    acc0 += __shfl_xor(acc0, 16); acc1 += __shfl_xor(acc1, 16);
    acc0 += __shfl_xor(acc0, 32); acc1 += __shfl_xor(acc1, 32);
    if (g == 0) {
        if (F32OUT) {
            const float* add = (const float*)addin;
            float* out = (float*)outv;
            float2 a = ((const float2*)(add + (size_t)node * 32))[cq];
            a.x += acc0;
            a.y += acc1;
            ((float2*)(out + (size_t)node * 32))[cq] = a;
        } else {
            const __half* add = (const __half*)addin;
            __half* out = (__half*)outv;
            float2 af = __half22float2(((const __half2*)(add + (size_t)node * 32))[cq]);
            ((__half2*)(out + (size_t)node * 32))[cq] = __floats2half2_rn(acc0 + af.x, acc1 + af.y);
        }
    }
}

// ---------- layer-1 MFMA GEMM: Hh = relu([xh|T1h|T2h] @ W1f + b1), fp16 out ----------
__global__ __launch_bounds__(256) void gemm_l1_mfma(const __half* __restrict__ A0,
                                                    const __half* __restrict__ A1,
                                                    const __half* __restrict__ A2,
                                                    const __half* __restrict__ Wf,
                                                    const float* __restrict__ b1,
                                                    __half* __restrict__ Hh, int nnodes) {
    const int wave = threadIdx.x >> 6;
    const int lane = threadIdx.x & 63;
    const int node0 = blockIdx.x * 64 + wave * 16;
    const int m = lane & 15;
    const int quad = lane >> 4;
    int arow = node0 + m;
    if (arow >= nnodes) arow = nnodes - 1;   // clamp: garbage rows never stored
    const __half* Ap[3] = {A0, A1, A2};
    f16x8 a[6];
#pragma unroll
    for (int kh = 0; kh < 6; ++kh) {
        const __half* A = Ap[kh >> 1];
        a[kh] = *(const f16x8*)(A + (size_t)arow * 64 + ((kh & 1) << 5) + (quad << 3));
    }
#pragma unroll
    for (int ct = 0; ct < 4; ++ct) {
        f32x4 acc = {0.f, 0.f, 0.f, 0.f};
#pragma unroll
        for (int kh = 0; kh < 6; ++kh) {
            f16x8 b = *(const f16x8*)(Wf + ((size_t)(ct * 6 + kh) * 64 + lane) * 8);
            acc = __builtin_amdgcn_mfma_f32_16x16x32_f16(a[kh], b, acc, 0, 0, 0);
        }
        int col = (ct << 4) | m;
        float bias = b1[col];
#pragma unroll
        for (int r = 0; r < 4; ++r) {
            int n = node0 + (quad << 2) + r;
            if (n < nnodes) Hh[(size_t)n * 64 + col] = __float2half(fmaxf(acc[r] + bias, 0.f));
        }
    }
}

// ---------- layer-2 MFMA GEMM: [P0|G1|G2] = Hh @ W2f (+b2 on P0) ----------
__global__ __launch_bounds__(256) void gemm_l2_mfma(const __half* __restrict__ Hh,
                                                    const __half* __restrict__ Wf,
                                                    const float* __restrict__ b2,
                                                    float* __restrict__ P0,
                                                    __half* __restrict__ G1,
                                                    __half* __restrict__ G2, int nnodes) {
    const int wave = threadIdx.x >> 6;
    const int lane = threadIdx.x & 63;
    const int node0 = blockIdx.x * 64 + wave * 16;
    const int m = lane & 15;
    const int quad = lane >> 4;
    int arow = node0 + m;
    if (arow >= nnodes) arow = nnodes - 1;
    f16x8 a0 = *(const f16x8*)(Hh + (size_t)arow * 64 + (quad << 3));
    f16x8 a1 = *(const f16x8*)(Hh + (size_t)arow * 64 + 32 + (quad << 3));
#pragma unroll
    for (int ct = 0; ct < 6; ++ct) {
        f32x4 acc = {0.f, 0.f, 0.f, 0.f};
        f16x8 b0 = *(const f16x8*)(Wf + ((size_t)(ct * 2 + 0) * 64 + lane) * 8);
        f16x8 b1v = *(const f16x8*)(Wf + ((size_t)(ct * 2 + 1) * 64 + lane) * 8);
        acc = __builtin_amdgcn_mfma_f32_16x16x32_f16(a0, b0, acc, 0, 0, 0);
        acc = __builtin_amdgcn_mfma_f32_16x16x32_f16(a1, b1v, acc, 0, 0, 0);
        int seg = ct >> 1;                      // wave-uniform
        int c = ((ct & 1) << 4) | m;            // col within segment
#pragma unroll
        for (int r = 0; r < 4; ++r) {
            int n = node0 + (quad << 2) + r;
            if (n >= nnodes) continue;
            float v = acc[r];
            if (seg == 0)      P0[(size_t)n * 32 + c] = v + b2[c];
            else if (seg == 1) G1[(size_t)n * 32 + c] = __float2half(v);
            else               G2[(size_t)n * 32 + c] = __float2half(v);
        }
    }
}

extern "C" void kernel_launch(void* const* d_in, const int* in_sizes, int n_in,
                              void* d_out, int out_size, void* d_ws, size_t ws_size,
                              hipStream_t stream) {
    const float* x  = (const float*)d_in[0];
    const int*   ei = (const int*)d_in[1];
    const float* W1 = (const float*)d_in[2];
    const float* b1 = (const float*)d_in[3];
    const float* W2 = (const float*)d_in[4];
    const float* b2 = (const float*)d_in[5];
    float* out = (float*)d_out;

    const int NN = N_NODES_C;
    const int NE = N_EDGES_C;
    const size_t HFEAT_BYTES = (size_t)NN * 64 * sizeof(__half);
    const size_t H32_BYTES = (size_t)NN * 32 * sizeof(__half);

    char* ws = (char*)d_ws;
    size_t off = 0;
    auto alloc = [&](size_t bytes) -> void* {
        void* p = ws + off;
        off += (bytes + 255) & ~(size_t)255;
        return p;
    };
    int*    bucket_cnt  = (int*)alloc((size_t)NBUK * 4);
    int*    bucket_base = (int*)alloc((size_t)(NBUK + 1) * 4);
    int*    bucket_next = (int*)alloc((size_t)NBUK * 4);
    int*    rowptr      = (int*)alloc((size_t)(NN + 1) * 4);
    float*  dis         = (float*)alloc((size_t)NN * 4);
    int2*   staged      = (int2*)alloc((size_t)NE * 8);
    int2*   colw        = (int2*)alloc((size_t)NE * 8);
    __half* xh          = (__half*)alloc(HFEAT_BYTES);
    __half* T1h         = (__half*)alloc(HFEAT_BYTES);   // layer1: T1; layer2: G1
    __half* T2h         = (__half*)alloc(HFEAT_BYTES);   // layer1: T2; layer2: G2
    __half* Hh          = (__half*)alloc(HFEAT_BYTES);
    __half* Qh          = (__half*)alloc(H32_BYTES);
    float*  P0          = (float*)alloc((size_t)NN * 32 * 4);
    __half* W1f         = (__half*)alloc((size_t)4 * 6 * 64 * 8 * 2);   // 24 KB
    __half* W2f         = (__half*)alloc((size_t)6 * 2 * 64 * 8 * 2);   // 12 KB

    const int PROPB = (NN + 3) / 4;
    const int CONVB = (NN * 64 / 4 + 255) / 256;
    const int BINB = (NE + CHUNK - 1) / CHUNK;
    const int GEMMB = (NN + 63) / 64;

    // ---- CSR build (bucket-atomic) + weight packing + x->fp16 ----
    hipMemsetAsync(bucket_cnt, 0, (size_t)NBUK * 4, stream);
    bucket_hist<<<BINB, 256, 0, stream>>>(ei, bucket_cnt, NE);
    bucket_scan<<<1, 64, 0, stream>>>(bucket_cnt, bucket_base, bucket_next, NBUK);
    bin_stage<<<BINB, 256, 0, stream>>>(ei, bucket_next, staged, NE);
    bin_count<<<NBUK, 256, 0, stream>>>(staged, bucket_base, rowptr, dis, NN, NE);
    bin_place<<<NBUK, 256, 0, stream>>>(staged, rowptr, dis, colw, NN);
    fold_w1f<<<(12288 + 255) / 256, 256, 0, stream>>>(W1, W1f);
    fold_w2f<<<(6144 + 255) / 256, 256, 0, stream>>>(W2, W2f);
    f2h_kernel<<<CONVB, 256, 0, stream>>>(x, xh, NN * 64 / 4);

    // ---- layer 1: Hh = relu(x@(W0-W2) + T1@W1 + T2@(2W2) + b1), T2 = prop(T1) ----
    prop_gather_h<<<PROPB, 256, 0, stream>>>(xh, rowptr, colw, T1h, NN);
    prop_gather_h<<<PROPB, 256, 0, stream>>>(T1h, rowptr, colw, T2h, NN);
    gemm_l1_mfma<<<GEMMB, 256, 0, stream>>>(xh, T1h, T2h, W1f, b1, Hh, NN);

    // ---- layer 2 (factored): out = P0 + prop(G1 + prop(G2)) ----
    gemm_l2_mfma<<<GEMMB, 256, 0, stream>>>(Hh, W2f, b2, P0, T1h, T2h, NN);
    prop_gather32<false><<<PROPB, 256, 0, stream>>>(T2h, rowptr, colw, T1h, Qh, NN);
    prop_gather32<true><<<PROPB, 256, 0, stream>>>(Qh, rowptr, colw, P0, out, NN);
}